// Round 4
// baseline (7453.213 us; speedup 1.0000x reference)
//
#include <hip/hip_runtime.h>
#include <math.h>

#define SLOPE 0.2f
#define EPSV 1e-12f
#define NEGINF (-3.0e38f)

static __device__ __forceinline__ float lrelu_combine(float xv, float dvv, float dot, float dsq) {
  float xneg = xv - dot / (dsq + EPSV) * dvv;
  float w = (dot >= 0.f) ? xv : xneg;
  return SLOPE * xv + (1.f - SLOPE) * w;
}

// ---------------- squared norms per point ----------------
__global__ void k_xx(const float* __restrict__ x, float* __restrict__ xx, int D, int N) {
  int b = blockIdx.y;
  int m = blockIdx.x * 256 + threadIdx.x;
  if (m >= N) return;
  const float* xp = x + (size_t)b * D * N + m;
  float s = 0.f;
  for (int d = 0; d < D; ++d) { float v = xp[(size_t)d * N]; s = fmaf(v, v, s); }
  xx[b * N + m] = s;
}

// ---------------- knn top-16, 4 queries per block (exact lax.top_k order & ties) ----------------
// dist arithmetic identical to prior passing version: ascending-d fmaf chain, 2*dot - xxn - xxm.
template <int D>
__global__ void __launch_bounds__(256) k_knn2(const float* __restrict__ x,
                                              const float* __restrict__ xx,
                                              int* __restrict__ idx, int N) {
  __shared__ float qt[D * 4];        // qt[d*4+qi]
  __shared__ float dist[4][2048];
  __shared__ float xxq[4];
  int b = blockIdx.y, tid = threadIdx.x;
  int q0 = blockIdx.x * 4;
  const float* xb = x + (size_t)b * D * N;
  for (int i = tid; i < D * 4; i += 256) qt[i] = xb[(size_t)(i >> 2) * N + q0 + (i & 3)];
  if (tid < 4) xxq[tid] = xx[b * N + q0 + tid];
  __syncthreads();
  int kmax = N >> 8;
  for (int k = 0; k < kmax; ++k) {
    int m = tid + 256 * k;
    float a0 = 0.f, a1 = 0.f, a2 = 0.f, a3 = 0.f;
#pragma unroll 8
    for (int d = 0; d < D; ++d) {
      float xv = xb[(size_t)d * N + m];
      const float4 q4 = *(const float4*)&qt[d * 4];
      a0 = fmaf(q4.x, xv, a0);
      a1 = fmaf(q4.y, xv, a1);
      a2 = fmaf(q4.z, xv, a2);
      a3 = fmaf(q4.w, xv, a3);
    }
    float xxm = xx[b * N + m];
    dist[0][m] = 2.f * a0 - xxq[0] - xxm;
    dist[1][m] = 2.f * a1 - xxq[1] - xxm;
    dist[2][m] = 2.f * a2 - xxq[2] - xxm;
    dist[3][m] = 2.f * a3 - xxq[3] - xxm;
  }
  __syncthreads();
  // selection: wave g handles query q0+g; no barriers (wave-private row)
  int g = tid >> 6, lane = tid & 63;
  float* dr = dist[g];
  int n = q0 + g;
  int imax = N >> 8;
  int* op = idx + ((size_t)b * N + n) * 16;
  for (int r = 0; r < 16; ++r) {
    float bv = NEGINF;
    int bi = N;
    for (int i = 0; i < imax; ++i) {
      int mb = i * 256 + lane * 4;
      float4 v = *(const float4*)&dr[mb];
      if (v.x > bv) { bv = v.x; bi = mb; }
      if (v.y > bv) { bv = v.y; bi = mb + 1; }
      if (v.z > bv) { bv = v.z; bi = mb + 2; }
      if (v.w > bv) { bv = v.w; bi = mb + 3; }
    }
#pragma unroll
    for (int s = 1; s < 64; s <<= 1) {
      float ov = __shfl_xor(bv, s, 64);
      int oi = __shfl_xor(bi, s, 64);
      if (ov > bv || (ov == bv && oi < bi)) { bv = ov; bi = oi; }
    }
    if (lane == 0) { op[r] = bi; dr[bi] = NEGINF; }
  }
}

// ---------------- fused linear pipeline ----------------
// PAIR=1: O1a = A1*X, O1b = (A2-A1)*X, O2a = Wd*O1a, O2b = Wd*O1b  (A row = [A1 | A2], stride SA)
// PAIR=0: O1a = A*X (+bias), O2a = Wd*O1a
// Accumulation order ascending k -> bit-identical to the prior k_lin chain.
template <int KT, int PAIR>
__global__ void __launch_bounds__(256) k_fuse(const float* __restrict__ A, int SA,
                                              const float* __restrict__ Wd,
                                              const float* __restrict__ X,
                                              const float* __restrict__ bias,
                                              float* __restrict__ O1a, float* __restrict__ O1b,
                                              float* __restrict__ O2a, float* __restrict__ O2b,
                                              int N) {
  constexpr int NW = PAIR ? 2 : 1;
  __shared__ float s_wa[NW][64][KT];
  __shared__ float s_xl[64 * 64];
  int tid = threadIdx.x;
  int col = tid & 63, g = tid >> 6;
  int b = blockIdx.y;
  int M3 = 3 * N;
  int j = blockIdx.x * 64 + col;
  for (int i = tid; i < 64 * KT; i += 256) {
    int o = i / KT, k = i - o * KT;
    float a1 = A[o * SA + k];
    s_wa[0][o][k] = a1;
    if (PAIR) s_wa[1][o][k] = A[o * SA + KT + k] - a1;
  }
  __syncthreads();
  const float* Xb = X + (size_t)b * KT * M3;
  float xr[KT];
#pragma unroll
  for (int k = 0; k < KT; ++k) xr[k] = Xb[(size_t)k * M3 + j];
  int d = j / N;
  float binit = 0.f;
  if (!PAIR && bias) { /* per-thread bias depends on o; handled below */ }
#pragma unroll
  for (int mat = 0; mat < NW; ++mat) {
    float acc[16];
#pragma unroll
    for (int oo = 0; oo < 16; ++oo) {
      int o = g * 16 + oo;
      acc[oo] = (!PAIR && bias) ? bias[b * 192 + o * 3 + d] : 0.f;
    }
#pragma unroll
    for (int oo = 0; oo < 16; ++oo) {
      int o = g * 16 + oo;
      float s = acc[oo];
      if constexpr (KT >= 4) {
        const float4* wr = (const float4*)&s_wa[mat][o][0];
#pragma unroll
        for (int k4 = 0; k4 < KT / 4; ++k4) {
          float4 w = wr[k4];
          s = fmaf(w.x, xr[4 * k4 + 0], s);
          s = fmaf(w.y, xr[4 * k4 + 1], s);
          s = fmaf(w.z, xr[4 * k4 + 2], s);
          s = fmaf(w.w, xr[4 * k4 + 3], s);
        }
      } else {
#pragma unroll
        for (int k = 0; k < KT; ++k) s = fmaf(s_wa[mat][o][k], xr[k], s);
      }
      acc[oo] = s;
    }
    float* O1 = (mat == 0) ? O1a : O1b;
    float* o1b = O1 + (size_t)b * 64 * M3;
#pragma unroll
    for (int oo = 0; oo < 16; ++oo) {
      int o = g * 16 + oo;
      o1b[(size_t)o * M3 + j] = acc[oo];
      s_xl[o * 64 + col] = acc[oo];
    }
    __syncthreads();
    float xr2[64];
#pragma unroll
    for (int k = 0; k < 64; ++k) xr2[k] = s_xl[k * 64 + col];
    float acc2[16];
#pragma unroll
    for (int oo = 0; oo < 16; ++oo) acc2[oo] = 0.f;
#pragma unroll
    for (int oo = 0; oo < 16; ++oo) {
      int o = g * 16 + oo;
      const float4* wd4 = (const float4*)(Wd + o * 64);
      float s = 0.f;
#pragma unroll
      for (int k4 = 0; k4 < 16; ++k4) {
        float4 w = wd4[k4];
        s = fmaf(w.x, xr2[4 * k4 + 0], s);
        s = fmaf(w.y, xr2[4 * k4 + 1], s);
        s = fmaf(w.z, xr2[4 * k4 + 2], s);
        s = fmaf(w.w, xr2[4 * k4 + 3], s);
      }
      acc2[oo] = s;
    }
    float* O2 = (mat == 0) ? O2a : O2b;
    float* o2b = O2 + (size_t)b * 64 * M3;
#pragma unroll
    for (int oo = 0; oo < 16; ++oo) {
      int o = g * 16 + oo;
      o2b[(size_t)o * M3 + j] = acc2[oo];
    }
    if (PAIR && mat == 0) __syncthreads();
  }
  (void)binit;
}

// ---------------- edge conv via precomputed P1,P2,D1,D2: out = mean_j lrelu ----------------
__global__ void __launch_bounds__(256) k_edge2(const float* __restrict__ P1, const float* __restrict__ P2,
                                               const float* __restrict__ D1, const float* __restrict__ D2,
                                               const int* __restrict__ idx,
                                               float* __restrict__ out, int N) {
  int gi = blockIdx.x * 256 + threadIdx.x;
  int total = 2 * 64 * N;
  if (gi >= total) return;
  int n = gi % N;
  int t = gi / N;
  int o = t & 63, b = t >> 6;
  size_t r0 = (size_t)((b * 64 + o) * 3) * N;
  float p2[3], d2[3];
#pragma unroll
  for (int d = 0; d < 3; ++d) { p2[d] = P2[r0 + (size_t)d * N + n]; d2[d] = D2[r0 + (size_t)d * N + n]; }
  const int* ip = idx + ((size_t)b * N + n) * 16;
  float acc0 = 0.f, acc1 = 0.f, acc2 = 0.f;
  for (int j = 0; j < 16; ++j) {
    int m = ip[j];
    float xl[3], dv[3];
#pragma unroll
    for (int d = 0; d < 3; ++d) {
      xl[d] = P1[r0 + (size_t)d * N + m] + p2[d];
      dv[d] = D1[r0 + (size_t)d * N + m] + d2[d];
    }
    float dot = xl[0] * dv[0] + xl[1] * dv[1] + xl[2] * dv[2];
    float dsq = dv[0] * dv[0] + dv[1] * dv[1] + dv[2] * dv[2];
    acc0 += lrelu_combine(xl[0], dv[0], dot, dsq);
    acc1 += lrelu_combine(xl[1], dv[1], dot, dsq);
    acc2 += lrelu_combine(xl[2], dv[2], dot, dsq);
  }
  out[r0 + n] = acc0 * (1.f / 16.f);
  out[r0 + N + n] = acc1 * (1.f / 16.f);
  out[r0 + 2 * (size_t)N + n] = acc2 * (1.f / 16.f);
}

// ---------------- Qx finisher: lrelu + chnorm (wave per point, lane = channel) ----------------
__global__ void __launch_bounds__(256) k_qfin(const float* __restrict__ XL, const float* __restrict__ DV,
                                              float* __restrict__ out, int N) {
  int tid = threadIdx.x;
  int p = blockIdx.x * 4 + (tid >> 6);
  int c = tid & 63;
  int b = p / N, n = p - b * N;
  size_t r0 = (size_t)((b * 64 + c) * 3) * N;
  float xl[3], dv[3];
#pragma unroll
  for (int d = 0; d < 3; ++d) { xl[d] = XL[r0 + (size_t)d * N + n]; dv[d] = DV[r0 + (size_t)d * N + n]; }
  float dot = xl[0] * dv[0] + xl[1] * dv[1] + xl[2] * dv[2];
  float dsq = dv[0] * dv[0] + dv[1] * dv[1] + dv[2] * dv[2];
  float z[3];
#pragma unroll
  for (int d = 0; d < 3; ++d) z[d] = lrelu_combine(xl[d], dv[d], dot, dsq);
  float n2 = z[0] * z[0] + z[1] * z[1] + z[2] * z[2];
  float cn2 = n2;
#pragma unroll
  for (int s = 1; s < 64; s <<= 1) cn2 += __shfl_xor(cn2, s, 64);
  float n_o = sqrtf(n2), cn = sqrtf(cn2);
  float scl = (n_o / fmaxf(cn, EPSV)) / fmaxf(n_o, EPSV);
#pragma unroll
  for (int d = 0; d < 3; ++d) out[r0 + (size_t)d * N + n] = z[d] * scl;
}

// ---------------- K path: wave per edge -> logits (lane = channel) ----------------
__global__ void __launch_bounds__(256) k_klog2(const float* __restrict__ qx,
                                               const float* __restrict__ P1, const float* __restrict__ P2,
                                               const float* __restrict__ D1, const float* __restrict__ D2,
                                               const int* __restrict__ idx,
                                               float* __restrict__ logits, int N) {
  int tid = threadIdx.x;
  int e = blockIdx.x * 4 + (tid >> 6);
  int c = tid & 63;
  int b = e / (N * 16);
  int r = e - b * N * 16;
  int n = r >> 4, j = r & 15;
  int m = idx[((size_t)b * N + n) * 16 + j];
  size_t r0 = (size_t)((b * 64 + c) * 3) * N;
  float xl[3], dv[3], qv[3];
#pragma unroll
  for (int d = 0; d < 3; ++d) {
    size_t rd = r0 + (size_t)d * N;
    xl[d] = P1[rd + m] + P2[rd + n];
    dv[d] = D1[rd + m] + D2[rd + n];
    qv[d] = qx[rd + n];
  }
  float dot = xl[0] * dv[0] + xl[1] * dv[1] + xl[2] * dv[2];
  float dsq = dv[0] * dv[0] + dv[1] * dv[1] + dv[2] * dv[2];
  float z[3];
#pragma unroll
  for (int d = 0; d < 3; ++d) z[d] = lrelu_combine(xl[d], dv[d], dot, dsq);
  float n2 = z[0] * z[0] + z[1] * z[1] + z[2] * z[2];
  float cn2 = n2;
#pragma unroll
  for (int s = 1; s < 64; s <<= 1) cn2 += __shfl_xor(cn2, s, 64);
  float n_o = sqrtf(n2), cn = sqrtf(cn2);
  float scl = (n_o / fmaxf(cn, EPSV)) / fmaxf(n_o, EPSV);
  float part = (z[0] * qv[0] + z[1] * qv[1] + z[2] * qv[2]) * scl;
#pragma unroll
  for (int s = 1; s < 32; s <<= 1) part += __shfl_xor(part, s, 32);
  if ((c & 31) == 0) {
    int h = c >> 5;
    logits[(((size_t)b * 2 + h) * N + n) * 16 + j] = part * 0.102062072615966f; // 1/sqrt(96)
  }
}

// ---------------- softmax over 16 neighbors ----------------
__global__ void k_soft(const float* __restrict__ logits, float* __restrict__ att, int N) {
  int gi = blockIdx.x * 256 + threadIdx.x;
  if (gi >= 2 * 2 * N) return;
  const float* lp = logits + (size_t)gi * 16;
  float* ap = att + (size_t)gi * 16;
  float mx = lp[0];
  for (int j = 1; j < 16; ++j) mx = fmaxf(mx, lp[j]);
  float e[16]; float sum = 0.f;
  for (int j = 0; j < 16; ++j) { e[j] = expf(lp[j] - mx); sum += e[j]; }
  float inv = 1.f / sum;
  for (int j = 0; j < 16; ++j) ap[j] = e[j] * inv;
}

// ---------------- V path + attention-weighted sum + residual ----------------
__global__ void __launch_bounds__(256) k_attout2(const float* __restrict__ xres,
                                                 const float* __restrict__ P1, const float* __restrict__ P2,
                                                 const float* __restrict__ D1, const float* __restrict__ D2,
                                                 const float* __restrict__ att,
                                                 const int* __restrict__ idx,
                                                 float* __restrict__ out, int N) {
  int gi = blockIdx.x * 256 + threadIdx.x;
  int total = 2 * 64 * N;
  if (gi >= total) return;
  int n = gi % N;
  int t = gi / N;
  int o = t & 63, b = t >> 6;
  int h = o >> 5;
  size_t r0 = (size_t)((b * 64 + o) * 3) * N;
  float p2[3], d2[3];
#pragma unroll
  for (int d = 0; d < 3; ++d) { p2[d] = P2[r0 + (size_t)d * N + n]; d2[d] = D2[r0 + (size_t)d * N + n]; }
  const int* ip = idx + ((size_t)b * N + n) * 16;
  const float* ap = att + (((size_t)b * 2 + h) * N + n) * 16;
  float acc0 = 0.f, acc1 = 0.f, acc2 = 0.f;
  for (int j = 0; j < 16; ++j) {
    int m = ip[j];
    float av = ap[j];
    float xl[3], dv[3];
#pragma unroll
    for (int d = 0; d < 3; ++d) {
      xl[d] = P1[r0 + (size_t)d * N + m] + p2[d];
      dv[d] = D1[r0 + (size_t)d * N + m] + d2[d];
    }
    float dot = xl[0] * dv[0] + xl[1] * dv[1] + xl[2] * dv[2];
    float dsq = dv[0] * dv[0] + dv[1] * dv[1] + dv[2] * dv[2];
    acc0 = fmaf(av, lrelu_combine(xl[0], dv[0], dot, dsq), acc0);
    acc1 = fmaf(av, lrelu_combine(xl[1], dv[1], dot, dsq), acc1);
    acc2 = fmaf(av, lrelu_combine(xl[2], dv[2], dot, dsq), acc2);
  }
  out[r0 + n] = xres[r0 + n] + acc0;
  out[r0 + N + n] = xres[r0 + N + n] + acc1;
  out[r0 + 2 * (size_t)N + n] = xres[r0 + 2 * (size_t)N + n] + acc2;
}

// ---------------- g-fuse finisher: elementwise lrelu ----------------
__global__ void __launch_bounds__(256) k_gfin(const float* __restrict__ XL, const float* __restrict__ DV,
                                              float* __restrict__ out, int N) {
  int gi = blockIdx.x * 256 + threadIdx.x;
  int total = 2 * 64 * N;
  if (gi >= total) return;
  int n = gi % N;
  int t = gi / N;
  int o = t & 63, b = t >> 6;
  size_t r0 = (size_t)((b * 64 + o) * 3) * N;
  float xl[3], dv[3];
#pragma unroll
  for (int d = 0; d < 3; ++d) { xl[d] = XL[r0 + (size_t)d * N + n]; dv[d] = DV[r0 + (size_t)d * N + n]; }
  float dot = xl[0] * dv[0] + xl[1] * dv[1] + xl[2] * dv[2];
  float dsq = dv[0] * dv[0] + dv[1] * dv[1] + dv[2] * dv[2];
#pragma unroll
  for (int d = 0; d < 3; ++d) out[r0 + (size_t)d * N + n] = lrelu_combine(xl[d], dv[d], dot, dsq);
}

// ---------------- bias for g-fuse, both sides in one launch ----------------
__global__ void k_gbias2(const float* __restrict__ gw, const float* __restrict__ meanX,
                         const float* __restrict__ meanY,
                         float* __restrict__ cbX, float* __restrict__ cbY) {
  int b = blockIdx.x, which = blockIdx.y, tid = threadIdx.x;  // 192 threads
  int o = tid / 3, d = tid - o * 3;
  const float* mb = (which ? meanY : meanX) + b * 192;
  float* cb = (which ? cbY : cbX);
  float s = 0.f;
  for (int c = 0; c < 64; ++c) s = fmaf(gw[o * 128 + 64 + c], mb[c * 3 + d], s);
  cb[b * 192 + tid] = s;
}

// ---------------- column mean over N for both arrays in one launch ----------------
__global__ void k_cmean2(const float* __restrict__ x1, const float* __restrict__ x2,
                         float* __restrict__ o1, float* __restrict__ o2,
                         int N, int ostride, int obase, float inv) {
  __shared__ float red[256];
  int b = blockIdx.y, cd = blockIdx.x, which = blockIdx.z, tid = threadIdx.x;
  const float* x = which ? x2 : x1;
  float* out = which ? o2 : o1;
  const float* p = x + ((size_t)b * 192 + cd) * N;
  float s = 0.f;
  for (int i = tid; i < N; i += 256) s += p[i];
  red[tid] = s;
  __syncthreads();
  for (int st = 128; st > 0; st >>= 1) {
    if (tid < st) red[tid] += red[tid + st];
    __syncthreads();
  }
  if (tid == 0) out[(size_t)b * ostride + obase + cd] = red[0] * inv;
}

// ---------------- channel-mean (fx_par pre-normalization) for both arrays ----------------
__global__ void k_parmean(const float* __restrict__ fx, const float* __restrict__ fy,
                          float* __restrict__ px, float* __restrict__ py, int N, int B) {
  int gi = blockIdx.x * 256 + threadIdx.x;
  int total = B * 3 * N;
  if (gi >= total) return;
  int b = gi / (3 * N);
  int r = gi - b * 3 * N;
  const float* fxb = fx + (size_t)b * 192 * N + r;
  const float* fyb = fy + (size_t)b * 192 * N + r;
  float sx = 0.f, sy = 0.f;
  for (int c = 0; c < 64; ++c) { sx += fxb[(size_t)c * 3 * N]; sy += fyb[(size_t)c * 3 * N]; }
  px[gi] = sx * (1.f / 64.f);
  py[gi] = sy * (1.f / 64.f);
}

// ---------------- score logits: sum_c (fx.px)(fy.py) (softmax+norm skipped: monotone) ----------------
__global__ void k_dotphi(const float* __restrict__ fx, const float* __restrict__ fy,
                         const float* __restrict__ px, const float* __restrict__ py,
                         float* __restrict__ dps, int N, int B) {
  int gi = blockIdx.x * 256 + threadIdx.x;
  if (gi >= B * N) return;
  int b = gi / N, n = gi - b * N;
  const float* fxb = fx + (size_t)b * 192 * N + n;
  const float* fyb = fy + (size_t)b * 192 * N + n;
  const float* pxb = px + (size_t)b * 3 * N + n;
  const float* pyb = py + (size_t)b * 3 * N + n;
  float acc = 0.f;
  for (int c = 0; c < 64; ++c) {
    float ax = 0.f, ay = 0.f;
    for (int d = 0; d < 3; ++d) {
      ax = fmaf(fxb[(size_t)(c * 3 + d) * N], pxb[(size_t)d * N], ax);
      ay = fmaf(fyb[(size_t)(c * 3 + d) * N], pyb[(size_t)d * N], ay);
    }
    acc = fmaf(ax, ay, acc);
  }
  dps[gi] = acc;
}

// ---------------- top-N/2 selection: bitonic sort (desc value, asc index) ----------------
__global__ void __launch_bounds__(1024) k_topsel(const float* __restrict__ dps,
                                                 int* __restrict__ sel, int N, int Nh) {
  __shared__ float kv[2048];
  __shared__ int ki[2048];
  int b = blockIdx.x, tid = threadIdx.x;
  for (int i = tid; i < N; i += 1024) { kv[i] = dps[b * N + i]; ki[i] = i; }
  __syncthreads();
  for (int kk = 2; kk <= N; kk <<= 1) {
    for (int jj = kk >> 1; jj > 0; jj >>= 1) {
      for (int i = tid; i < N; i += 1024) {
        int ixj = i ^ jj;
        if (ixj > i) {
          float va = kv[i], vb = kv[ixj];
          int ia = ki[i], ib = ki[ixj];
          bool aFirst = (va > vb) || (va == vb && ia < ib);
          bool up = ((i & kk) == 0);
          bool doswap = up ? (!aFirst) : aFirst;
          if (doswap) { kv[i] = vb; kv[ixj] = va; ki[i] = ib; ki[ixj] = ia; }
        }
      }
      __syncthreads();
    }
  }
  for (int i = tid; i < Nh; i += 1024) sel[b * Nh + i] = ki[i];
}

// ---------------- gather selected points for both arrays ----------------
__global__ void k_gather(const float* __restrict__ sx, const float* __restrict__ sy,
                         const int* __restrict__ sel,
                         float* __restrict__ dx, float* __restrict__ dy,
                         int N, int Nh, int B) {
  int gi = blockIdx.x * 256 + threadIdx.x;
  int total = B * 192 * Nh;
  if (gi >= total) return;
  int i = gi % Nh;
  int t = gi / Nh;
  int cd = t % 192;
  int b = t / 192;
  int s = sel[b * Nh + i];
  dx[gi] = sx[((size_t)b * 192 + cd) * N + s];
  dy[gi] = sy[((size_t)b * 192 + cd) * N + s];
}

// ---------------- final head: vn_lin_lrelu(concat blocks, h_w, h_d) ----------------
__global__ void k_head(const float* __restrict__ blkX, const float* __restrict__ blkY,
                       const float* __restrict__ hw, const float* __restrict__ hd,
                       float* __restrict__ Fx, float* __restrict__ Fy) {
  __shared__ float f[3][128];
  __shared__ float xl[3][32];
  __shared__ float dv[3][32];
  int which = blockIdx.x, b = blockIdx.y, tid = threadIdx.x;
  const float* blk = which ? blkY : blkX;
  float* F = which ? Fy : Fx;
  int o = tid & 31, dd = tid >> 5;
  for (int i = tid; i < 384; i += 96) f[i % 3][i / 3] = blk[(size_t)b * 384 + i];
  __syncthreads();
  float s = 0.f;
  for (int c = 0; c < 128; ++c) s = fmaf(hw[o * 128 + c], f[dd][c], s);
  xl[dd][o] = s;
  __syncthreads();
  float s2 = 0.f;
  for (int p = 0; p < 32; ++p) s2 = fmaf(hd[o * 32 + p], xl[dd][p], s2);
  dv[dd][o] = s2;
  __syncthreads();
  float dot = xl[0][o] * dv[0][o] + xl[1][o] * dv[1][o] + xl[2][o] * dv[2][o];
  float dsq = dv[0][o] * dv[0][o] + dv[1][o] * dv[1][o] + dv[2][o] * dv[2][o];
  F[((size_t)b * 32 + o) * 3 + dd] = lrelu_combine(xl[dd][o], dv[dd][o], dot, dsq);
}

// ================== LAPACK-faithful 3x3 SVD (dgesdd path: dgebrd + dbdsqr) ==================
#define DEPS 2.220446049250313e-16
#define DUNFL 2.2250738585072014e-308

static __device__ void dlartg_(double f, double g, double* cs, double* sn, double* r) {
  if (g == 0.0) { *cs = 1.0; *sn = 0.0; *r = f; }
  else if (f == 0.0) { *cs = 0.0; *sn = copysign(1.0, g); *r = fabs(g); }
  else {
    double d = sqrt(f * f + g * g);
    double c = fabs(f) / d;
    double rr = copysign(d, f);
    *cs = c; *r = rr; *sn = g / rr;
  }
}

static __device__ void dlas2_(double f, double g, double h, double* ssmin, double* ssmax) {
  double fa = fabs(f), ga = fabs(g), ha = fabs(h);
  double fhmn = fmin(fa, ha), fhmx = fmax(fa, ha);
  if (fhmn == 0.0) {
    *ssmin = 0.0;
    if (fhmx == 0.0) *ssmax = ga;
    else { double mx = fmax(fhmx, ga), mn = fmin(fhmx, ga); double q = mn / mx; *ssmax = mx * sqrt(1.0 + q * q); }
  } else {
    if (ga < fhmx) {
      double as_ = 1.0 + fhmn / fhmx;
      double at = (fhmx - fhmn) / fhmx;
      double au = ga / fhmx; au = au * au;
      double c = 2.0 / (sqrt(as_ * as_ + au) + sqrt(at * at + au));
      *ssmin = fhmn * c; *ssmax = fhmx / c;
    } else {
      double au = fhmx / ga;
      if (au == 0.0) { *ssmin = (fhmn * fhmx) / ga; *ssmax = ga; }
      else {
        double as_ = 1.0 + fhmn / fhmx;
        double at = (fhmx - fhmn) / fhmx;
        double t1 = as_ * au, t2 = at * au;
        double c = 1.0 / (sqrt(1.0 + t1 * t1) + sqrt(1.0 + t2 * t2));
        double sm = (fhmn * c) * au; *ssmin = sm + sm;
        *ssmax = ga / (c + c);
      }
    }
  }
}

static __device__ void dlasv2_(double f, double g, double h,
                               double* ssmin, double* ssmax,
                               double* snr, double* csr, double* snl, double* csl) {
  double ft = f, fa = fabs(f), ht = h, ha = fabs(h);
  int pmax = 1;
  bool swp = (ha > fa);
  if (swp) { pmax = 3; double t = ft; ft = ht; ht = t; t = fa; fa = ha; ha = t; }
  double gt = g, ga = fabs(g);
  double clt = 0, crt = 0, slt = 0, srt = 0;
  if (ga == 0.0) {
    *ssmin = ha; *ssmax = fa; clt = 1.0; crt = 1.0; slt = 0.0; srt = 0.0;
  } else {
    bool gasmal = true;
    if (ga > fa) {
      pmax = 2;
      if ((fa / ga) < DEPS) {
        gasmal = false;
        *ssmax = ga;
        *ssmin = (ha > 1.0) ? (fa / (ga / ha)) : ((fa / ga) * ha);
        clt = 1.0; slt = ht / gt; srt = 1.0; crt = ft / gt;
      }
    }
    if (gasmal) {
      double dd = fa - ha;
      double l = (dd == fa) ? 1.0 : (dd / fa);
      double mq = gt / ft;
      double t = 2.0 - l;
      double mm = mq * mq, tt = t * t;
      double s = sqrt(tt + mm);
      double r = (l == 0.0) ? fabs(mq) : sqrt(l * l + mm);
      double a = 0.5 * (s + r);
      *ssmin = ha / a;
      *ssmax = fa * a;
      if (mm == 0.0) {
        if (l == 0.0) t = copysign(2.0, ft) * copysign(1.0, gt);
        else t = gt / copysign(dd, ft) + mq / t;
      } else {
        t = (mq / (s + t) + mq / (r + l)) * (1.0 + a);
      }
      double l2 = sqrt(t * t + 4.0);
      crt = 2.0 / l2;
      srt = t / l2;
      clt = (crt + srt * mq) / a;
      slt = (ht / ft) * srt / a;
    }
  }
  if (swp) { *csl = srt; *snl = crt; *csr = slt; *snr = clt; }
  else { *csl = clt; *snl = slt; *csr = crt; *snr = srt; }
  double tsign = 0.0;
  if (pmax == 1) tsign = copysign(1.0, *csr) * copysign(1.0, *csl) * copysign(1.0, f);
  if (pmax == 2) tsign = copysign(1.0, *snr) * copysign(1.0, *csl) * copysign(1.0, g);
  if (pmax == 3) tsign = copysign(1.0, *snr) * copysign(1.0, *snl) * copysign(1.0, h);
  *ssmax = copysign(*ssmax, tsign);
  *ssmin = copysign(*ssmin, tsign * copysign(1.0, f) * copysign(1.0, h));
}

static __device__ void dbdsqr3(double d[3], double e[2], double VT[3][3], double U[3][3]) {
  const int n = 3;
  double tolmul = fmax(10.0, fmin(100.0, pow(DEPS, -0.125)));
  double tol = tolmul * DEPS;
  double thresh;
  {
    double sminoa = fabs(d[0]);
    if (sminoa != 0.0) {
      double mu = sminoa;
      for (int i = 1; i < n; ++i) {
        mu = fabs(d[i]) * (mu / (mu + fabs(e[i - 1])));
        sminoa = fmin(sminoa, mu);
        if (sminoa == 0.0) break;
      }
    }
    sminoa = sminoa / sqrt((double)n);
    thresh = fmax(tol * sminoa, 6.0 * n * n * DUNFL);
  }
  int maxit = 6 * n * n;
  int iter = 0, oldll = -1, oldm = -1, idir = 0;
  int m = n;
  double sminl = 0.0;
  int guard = 0;
  while (true) {
    if (m <= 1) break;
    if (iter > maxit) break;
    if (++guard > 500) break;
    double smaxb = fabs(d[m - 1]);
    int ll = 0; bool found = false;
    for (int lll = 1; lll <= m - 1; ++lll) {
      int l = m - lll;
      double abss = fabs(d[l - 1]);
      double abse = fabs(e[l - 1]);
      if (abse <= thresh) { ll = l; found = true; break; }
      smaxb = fmax(smaxb, fmax(abss, abse));
    }
    if (found) {
      e[ll - 1] = 0.0;
      if (ll == m - 1) { m = m - 1; continue; }
      ll = ll + 1;
    } else ll = 1;
    if (ll == m - 1) {
      double sigmn, sigmx, sinr, cosr, sinl2, cosl2;
      dlasv2_(d[m - 2], e[m - 2], d[m - 1], &sigmn, &sigmx, &sinr, &cosr, &sinl2, &cosl2);
      d[m - 2] = sigmx; d[m - 1] = sigmn; e[m - 2] = 0.0;
      for (int j = 0; j < 3; ++j) {
        double t1 = VT[m - 2][j], t2 = VT[m - 1][j];
        VT[m - 2][j] = cosr * t1 + sinr * t2;
        VT[m - 1][j] = cosr * t2 - sinr * t1;
      }
      for (int i2 = 0; i2 < 3; ++i2) {
        double t1 = U[i2][m - 2], t2 = U[i2][m - 1];
        U[i2][m - 2] = cosl2 * t1 + sinl2 * t2;
        U[i2][m - 1] = cosl2 * t2 - sinl2 * t1;
      }
      m -= 2;
      continue;
    }
    if (ll > oldm || m < oldll)
      idir = (fabs(d[ll - 1]) >= fabs(d[m - 1])) ? 1 : 2;
    if (idir == 1) {
      if (fabs(e[m - 2]) <= tol * fabs(d[m - 1])) { e[m - 2] = 0.0; continue; }
      double mu = fabs(d[ll - 1]); sminl = mu;
      bool conv = true;
      for (int lll = ll; lll <= m - 1; ++lll) {
        if (fabs(e[lll - 1]) > tol * mu) { conv = false; break; }
        mu = fabs(d[lll]) * (mu / (mu + fabs(e[lll - 1])));
        sminl = fmin(sminl, mu);
      }
      if (conv) { e[m - 2] = 0.0; continue; }
    } else {
      if (fabs(e[ll - 1]) <= tol * fabs(d[ll - 1])) { e[ll - 1] = 0.0; continue; }
      double mu = fabs(d[m - 1]); sminl = mu;
      bool conv = true;
      for (int lll = m - 1; lll >= ll; --lll) {
        if (fabs(e[lll - 1]) > tol * mu) { conv = false; break; }
        mu = fabs(d[lll - 1]) * (mu / (mu + fabs(e[lll - 1])));
        sminl = fmin(sminl, mu);
      }
      if (conv) { e[ll - 1] = 0.0; continue; }
    }
    oldll = ll; oldm = m;
    double shift = 0.0, rr;
    if (!(n * tol * (sminl / smaxb) <= fmax(DEPS, 0.01 * tol))) {
      double sll;
      if (idir == 1) { sll = fabs(d[ll - 1]); dlas2_(d[m - 2], e[m - 2], d[m - 1], &shift, &rr); }
      else { sll = fabs(d[m - 1]); dlas2_(d[ll - 1], e[ll - 1], d[ll], &shift, &rr); }
      if (sll > 0.0) { double q = shift / sll; if (q * q < DEPS) shift = 0.0; }
    }
    iter += m - ll;
    double csv[2], snv[2], ocsv[2], osnv[2];
    int cnt = 0;
    if (shift == 0.0) {
      if (idir == 1) {
        double cs = 1.0, oldcs = 1.0, sn = 0.0, oldsn = 0.0, r;
        for (int i = ll; i <= m - 1; ++i) {
          dlartg_(d[i - 1] * cs, e[i - 1], &cs, &sn, &r);
          if (i > ll) e[i - 2] = oldsn * r;
          dlartg_(oldcs * r, d[i] * sn, &oldcs, &oldsn, &d[i - 1]);
          csv[cnt] = cs; snv[cnt] = sn; ocsv[cnt] = oldcs; osnv[cnt] = oldsn; cnt++;
        }
        double hh = d[m - 1] * cs;
        d[m - 1] = hh * oldcs;
        e[m - 2] = hh * oldsn;
        for (int k = 0; k < cnt; ++k) {
          int r0 = ll - 1 + k, r1 = r0 + 1;
          for (int j = 0; j < 3; ++j) {
            double t1 = VT[r0][j], t2 = VT[r1][j];
            VT[r0][j] = snv[k] * t2 + csv[k] * t1;
            VT[r1][j] = csv[k] * t2 - snv[k] * t1;
          }
        }
        for (int k = 0; k < cnt; ++k) {
          int c0 = ll - 1 + k, c1 = c0 + 1;
          for (int i2 = 0; i2 < 3; ++i2) {
            double t1 = U[i2][c0], t2 = U[i2][c1];
            U[i2][c0] = osnv[k] * t2 + ocsv[k] * t1;
            U[i2][c1] = ocsv[k] * t2 - osnv[k] * t1;
          }
        }
        if (fabs(e[m - 2]) <= thresh) e[m - 2] = 0.0;
      } else {
        double cs = 1.0, oldcs = 1.0, sn = 0.0, oldsn = 0.0, r;
        for (int i = m; i >= ll + 1; --i) {
          dlartg_(d[i - 1] * cs, e[i - 2], &cs, &sn, &r);
          if (i < m) e[i - 1] = oldsn * r;
          dlartg_(oldcs * r, d[i - 2] * sn, &oldcs, &oldsn, &d[i - 1]);
          int k = i - ll - 1;
          csv[k] = cs; snv[k] = -sn; ocsv[k] = oldcs; osnv[k] = -oldsn; cnt++;
        }
        double hh = d[ll - 1] * cs;
        d[ll - 1] = hh * oldcs;
        e[ll - 1] = hh * oldsn;
        for (int k = cnt - 1; k >= 0; --k) {
          int r0 = ll - 1 + k, r1 = r0 + 1;
          for (int j = 0; j < 3; ++j) {
            double t1 = VT[r0][j], t2 = VT[r1][j];
            VT[r0][j] = osnv[k] * t2 + ocsv[k] * t1;
            VT[r1][j] = ocsv[k] * t2 - osnv[k] * t1;
          }
        }
        for (int k = cnt - 1; k >= 0; --k) {
          int c0 = ll - 1 + k, c1 = c0 + 1;
          for (int i2 = 0; i2 < 3; ++i2) {
            double t1 = U[i2][c0], t2 = U[i2][c1];
            U[i2][c0] = snv[k] * t2 + csv[k] * t1;
            U[i2][c1] = csv[k] * t2 - snv[k] * t1;
          }
        }
        if (fabs(e[ll - 1]) <= thresh) e[ll - 1] = 0.0;
      }
    } else {
      if (idir == 1) {
        double f = (fabs(d[ll - 1]) - shift) * (copysign(1.0, d[ll - 1]) + shift / d[ll - 1]);
        double g = e[ll - 1];
        double cosr, sinr, cosl2, sinl2, r;
        for (int i = ll; i <= m - 1; ++i) {
          dlartg_(f, g, &cosr, &sinr, &r);
          if (i > ll) e[i - 2] = r;
          f = cosr * d[i - 1] + sinr * e[i - 1];
          e[i - 1] = cosr * e[i - 1] - sinr * d[i - 1];
          g = sinr * d[i];
          d[i] = cosr * d[i];
          dlartg_(f, g, &cosl2, &sinl2, &r);
          d[i - 1] = r;
          f = cosl2 * e[i - 1] + sinl2 * d[i];
          d[i] = cosl2 * d[i] - sinl2 * e[i - 1];
          if (i < m - 1) {
            g = sinl2 * e[i];
            e[i] = cosl2 * e[i];
          }
          csv[cnt] = cosr; snv[cnt] = sinr; ocsv[cnt] = cosl2; osnv[cnt] = sinl2; cnt++;
        }
        e[m - 2] = f;
        for (int k = 0; k < cnt; ++k) {
          int r0 = ll - 1 + k, r1 = r0 + 1;
          for (int j = 0; j < 3; ++j) {
            double t1 = VT[r0][j], t2 = VT[r1][j];
            VT[r0][j] = snv[k] * t2 + csv[k] * t1;
            VT[r1][j] = csv[k] * t2 - snv[k] * t1;
          }
        }
        for (int k = 0; k < cnt; ++k) {
          int c0 = ll - 1 + k, c1 = c0 + 1;
          for (int i2 = 0; i2 < 3; ++i2) {
            double t1 = U[i2][c0], t2 = U[i2][c1];
            U[i2][c0] = osnv[k] * t2 + ocsv[k] * t1;
            U[i2][c1] = ocsv[k] * t2 - osnv[k] * t1;
          }
        }
        if (fabs(e[m - 2]) <= thresh) e[m - 2] = 0.0;
      } else {
        double f = (fabs(d[m - 1]) - shift) * (copysign(1.0, d[m - 1]) + shift / d[m - 1]);
        double g = e[m - 2];
        for (int i = m; i >= ll + 1; --i) {
          double cosr, sinr, cosl2, sinl2, r;
          dlartg_(f, g, &cosr, &sinr, &r);
          if (i < m) e[i - 1] = r;
          f = cosr * d[i - 1] + sinr * e[i - 2];
          e[i - 2] = cosr * e[i - 2] - sinr * d[i - 1];
          g = sinr * d[i - 2];
          d[i - 2] = cosr * d[i - 2];
          dlartg_(f, g, &cosl2, &sinl2, &r);
          d[i - 1] = r;
          f = cosl2 * e[i - 2] + sinl2 * d[i - 2];
          d[i - 2] = cosl2 * d[i - 2] - sinl2 * e[i - 2];
          if (i > ll + 1) {
            g = sinl2 * e[i - 3];
            e[i - 3] = cosl2 * e[i - 3];
          }
          int k = i - ll - 1;
          ocsv[k] = cosl2; osnv[k] = -sinl2; csv[k] = cosr; snv[k] = -sinr; cnt++;
        }
        e[ll - 1] = f;
        for (int k = cnt - 1; k >= 0; --k) {
          int r0 = ll - 1 + k, r1 = r0 + 1;
          for (int j = 0; j < 3; ++j) {
            double t1 = VT[r0][j], t2 = VT[r1][j];
            VT[r0][j] = snv[k] * t2 + csv[k] * t1;
            VT[r1][j] = csv[k] * t2 - snv[k] * t1;
          }
        }
        for (int k = cnt - 1; k >= 0; --k) {
          int c0 = ll - 1 + k, c1 = c0 + 1;
          for (int i2 = 0; i2 < 3; ++i2) {
            double t1 = U[i2][c0], t2 = U[i2][c1];
            U[i2][c0] = osnv[k] * t2 + ocsv[k] * t1;
            U[i2][c1] = ocsv[k] * t2 - osnv[k] * t1;
          }
        }
        if (fabs(e[ll - 1]) <= thresh) e[ll - 1] = 0.0;
      }
    }
  }
  for (int i = 0; i < n; ++i)
    if (d[i] < 0.0) { d[i] = -d[i]; for (int j = 0; j < 3; ++j) VT[i][j] = -VT[i][j]; }
  for (int i = 1; i <= n - 1; ++i) {
    int isub = 1; double smn = d[0];
    for (int j = 2; j <= n + 1 - i; ++j)
      if (d[j - 1] <= smn) { isub = j; smn = d[j - 1]; }
    if (isub != n + 1 - i) {
      int a = isub - 1, b2 = n - i;
      double t = d[a]; d[a] = d[b2]; d[b2] = t;
      for (int j = 0; j < 3; ++j) { t = VT[a][j]; VT[a][j] = VT[b2][j]; VT[b2][j] = t; }
      for (int j = 0; j < 3; ++j) { t = U[j][a]; U[j][a] = U[j][b2]; U[j][b2] = t; }
    }
  }
}

__global__ void k_svd(const float* __restrict__ Fx, const float* __restrict__ Fy,
                      float* __restrict__ out, int B) {
  int b = blockIdx.x;
  if (threadIdx.x != 0) return;
  double A[3][3];
  for (int d = 0; d < 3; ++d)
    for (int e = 0; e < 3; ++e) {
      double s = 0.0;
      for (int c = 0; c < 32; ++c)
        s += (double)Fx[((size_t)b * 32 + c) * 3 + d] * (double)Fy[((size_t)b * 32 + c) * 3 + e];
      A[d][e] = s;
    }
  double dg[3], eg[2], tauq0, tauq1, taup0;
  double v1_1 = 0, v1_2 = 0, v2_1 = 0, w1 = 0;
  {
    double alpha = A[0][0];
    double xn = sqrt(A[1][0] * A[1][0] + A[2][0] * A[2][0]);
    if (xn == 0.0) { tauq0 = 0.0; dg[0] = alpha; }
    else {
      double beta = -copysign(sqrt(alpha * alpha + xn * xn), alpha);
      tauq0 = (beta - alpha) / beta;
      double scal = 1.0 / (alpha - beta);
      v1_1 = A[1][0] * scal; v1_2 = A[2][0] * scal;
      dg[0] = beta;
    }
    for (int j = 1; j < 3; ++j) {
      double w = A[0][j] + v1_1 * A[1][j] + v1_2 * A[2][j];
      w *= tauq0;
      A[0][j] -= w; A[1][j] -= w * v1_1; A[2][j] -= w * v1_2;
    }
  }
  {
    double alpha = A[0][1];
    double xn = fabs(A[0][2]);
    if (xn == 0.0) { taup0 = 0.0; eg[0] = alpha; }
    else {
      double beta = -copysign(sqrt(alpha * alpha + xn * xn), alpha);
      taup0 = (beta - alpha) / beta;
      w1 = A[0][2] / (alpha - beta);
      eg[0] = beta;
    }
    for (int i = 1; i < 3; ++i) {
      double t = A[i][1] + w1 * A[i][2];
      t *= taup0;
      A[i][1] -= t; A[i][2] -= t * w1;
    }
  }
  {
    double alpha = A[1][1];
    double xn = fabs(A[2][1]);
    if (xn == 0.0) { tauq1 = 0.0; dg[1] = alpha; }
    else {
      double beta = -copysign(sqrt(alpha * alpha + xn * xn), alpha);
      tauq1 = (beta - alpha) / beta;
      v2_1 = A[2][1] / (alpha - beta);
      dg[1] = beta;
    }
    double w = A[1][2] + v2_1 * A[2][2];
    w *= tauq1;
    A[1][2] -= w; A[2][2] -= w * v2_1;
  }
  eg[1] = A[1][2];
  dg[2] = A[2][2];
  double U[3][3] = {{1, 0, 0}, {0, 1, 0}, {0, 0, 1}};
  double VT[3][3] = {{1, 0, 0}, {0, 1, 0}, {0, 0, 1}};
  dbdsqr3(dg, eg, VT, U);
  for (int j = 0; j < 3; ++j) {
    double w = U[1][j] + v2_1 * U[2][j];
    w *= tauq1;
    U[1][j] -= w; U[2][j] -= w * v2_1;
  }
  for (int j = 0; j < 3; ++j) {
    double w = U[0][j] + v1_1 * U[1][j] + v1_2 * U[2][j];
    w *= tauq0;
    U[0][j] -= w; U[1][j] -= w * v1_1; U[2][j] -= w * v1_2;
  }
  for (int r = 0; r < 3; ++r) {
    double t = VT[r][1] + w1 * VT[r][2];
    t *= taup0;
    VT[r][1] -= t; VT[r][2] -= t * w1;
  }
  for (int i = 0; i < 3; ++i)
    for (int j = 0; j < 3; ++j) {
      double r = 0;
      for (int k = 0; k < 3; ++k) r += U[i][k] * VT[j][k];
      out[b * 9 + i * 3 + j] = (float)r;
    }
  for (int dd = 0; dd < 3; ++dd) {
    float sx = 0.f, sy = 0.f;
    for (int c = 0; c < 32; ++c) {
      float vx = Fx[((size_t)b * 32 + c) * 3 + dd];
      float vy = Fy[((size_t)b * 32 + c) * 3 + dd];
      sx = fmaf(vx, vx, sx);
      sy = fmaf(vy, vy, sy);
    }
    out[B * 9 + b * 3 + dd] = sqrtf(sy) / sqrtf(sx);
  }
}

extern "C" void kernel_launch(void* const* d_in, const int* in_sizes, int n_in,
                              void* d_out, int out_size, void* d_ws, size_t ws_size,
                              hipStream_t stream) {
  (void)in_sizes; (void)n_in; (void)out_size; (void)ws_size;
  const int B = 2, N0 = 2048;
  const float* W[24];
  for (int i = 0; i < 24; ++i) W[i] = (const float*)d_in[i];

  float* ws = (float*)d_ws;
  const size_t P = (size_t)B * 64 * 3 * 2048;  // 786432
  float* bufA = ws;
  float* bufB = bufA + P;
  float* bufC = bufB + P;
  float* bufD = bufC + P;
  float* bufQ = bufD + P;
  float* G1 = bufQ + P;
  float* G2 = G1 + P;
  float* G3 = G2 + P;
  float* G4 = G3 + P;
  float* logits = G4 + P;            // B*2*2048*16 = 131072
  float* att = logits + 131072;      // 131072
  float* px = att + 131072;          // B*3*2048 = 12288
  float* py = px + 12288;
  float* dps = py + 12288;           // 4096
  float* xxb = dps + 4096;           // 4096
  float* meanX = xxb + 4096;         // 384
  float* meanY = meanX + 384;
  float* cbX = meanY + 384;          // 384
  float* cbY = cbX + 384;
  float* blkX = cbY + 384;           // 768
  float* blkY = blkX + 768;
  float* Fxb = blkY + 768;           // 192
  float* Fyb = Fxb + 192;
  int* idxA = (int*)(Fyb + 192);     // 65536
  int* idxB = idxA + 65536;
  int* sel = idxB + 65536;           // 2048

  auto knn = [&](const float* x, int D, int N, int* idx) {
    dim3 g1((N + 255) / 256, B);
    k_xx<<<g1, 256, 0, stream>>>(x, xxb, D, N);
    dim3 g2(N / 4, B);
    if (D == 192) k_knn2<192><<<g2, 256, 0, stream>>>(x, xxb, idx, N);
    else          k_knn2<3><<<g2, 256, 0, stream>>>(x, xxb, idx, N);
  };

  const float* fx = W[0];
  const float* fy = W[1];
  int N = N0;
  for (int blk = 0; blk < 2; ++blk) {
    int D = (blk == 0) ? 3 : 192;
    const float* dgw = W[blk ? 12 : 2]; const float* dgd = W[blk ? 13 : 3];
    const float* qw  = W[blk ? 14 : 4]; const float* qd  = W[blk ? 15 : 5];
    const float* kw  = W[blk ? 16 : 6]; const float* kd  = W[blk ? 17 : 7];
    const float* vw  = W[blk ? 18 : 8]; const float* vd  = W[blk ? 19 : 9];
    const float* gw  = W[blk ? 20 : 10]; const float* gd = W[blk ? 21 : 11];
    int nEl = B * 64 * N;
    dim3 gE((nEl + 255) / 256);
    dim3 gW(B * N / 4);              // wave-per-point kernels
    dim3 gK(B * N * 16 / 4);         // wave-per-edge kernels
    dim3 gS((B * 2 * N + 255) / 256);
    dim3 gF(3 * N / 64, B);          // fused linear kernels

    // ---- dgcnn fx -> bufA
    knn(fx, D, N, idxA);
    if (blk == 0) k_fuse<1, 1><<<gF, 256, 0, stream>>>(dgw, 2, dgd, fx, nullptr, G1, G2, G3, G4, N);
    else          k_fuse<64, 1><<<gF, 256, 0, stream>>>(dgw, 128, dgd, fx, nullptr, G1, G2, G3, G4, N);
    k_edge2<<<gE, 256, 0, stream>>>(G1, G2, G3, G4, idxA, bufA, N);
    // ---- dgcnn fy -> bufB
    knn(fy, D, N, idxB);
    if (blk == 0) k_fuse<1, 1><<<gF, 256, 0, stream>>>(dgw, 2, dgd, fy, nullptr, G1, G2, G3, G4, N);
    else          k_fuse<64, 1><<<gF, 256, 0, stream>>>(dgw, 128, dgd, fy, nullptr, G1, G2, G3, G4, N);
    k_edge2<<<gE, 256, 0, stream>>>(G1, G2, G3, G4, idxB, bufB, N);

    // ---- cross_context #1: x=bufA, y=bufB -> bufC
    knn(bufB, 192, N, idxB);
    k_fuse<64, 0><<<gF, 256, 0, stream>>>(qw, 64, qd, bufA, nullptr, G1, nullptr, G2, nullptr, N);
    k_qfin<<<gW, 256, 0, stream>>>(G1, G2, bufQ, N);
    k_fuse<64, 1><<<gF, 256, 0, stream>>>(kw, 128, kd, bufB, nullptr, G1, G2, G3, G4, N);
    k_klog2<<<gK, 256, 0, stream>>>(bufQ, G1, G2, G3, G4, idxB, logits, N);
    k_soft<<<gS, 256, 0, stream>>>(logits, att, N);
    k_fuse<64, 1><<<gF, 256, 0, stream>>>(vw, 128, vd, bufB, nullptr, G1, G2, G3, G4, N);
    k_attout2<<<gE, 256, 0, stream>>>(bufA, G1, G2, G3, G4, att, idxB, bufC, N);

    // ---- cross_context #2: x=bufB, y=bufC -> bufD
    knn(bufC, 192, N, idxA);
    k_fuse<64, 0><<<gF, 256, 0, stream>>>(qw, 64, qd, bufB, nullptr, G1, nullptr, G2, nullptr, N);
    k_qfin<<<gW, 256, 0, stream>>>(G1, G2, bufQ, N);
    k_fuse<64, 1><<<gF, 256, 0, stream>>>(kw, 128, kd, bufC, nullptr, G1, G2, G3, G4, N);
    k_klog2<<<gK, 256, 0, stream>>>(bufQ, G1, G2, G3, G4, idxA, logits, N);
    k_soft<<<gS, 256, 0, stream>>>(logits, att, N);
    k_fuse<64, 1><<<gF, 256, 0, stream>>>(vw, 128, vd, bufC, nullptr, G1, G2, G3, G4, N);
    k_attout2<<<gE, 256, 0, stream>>>(bufB, G1, G2, G3, G4, att, idxA, bufD, N);

    // ---- global fuse
    k_cmean2<<<dim3(192, B, 2), 256, 0, stream>>>(bufC, bufD, meanX, meanY, N, 192, 0, 1.f / (float)N);
    k_gbias2<<<dim3(B, 2), 192, 0, stream>>>(gw, meanX, meanY, cbX, cbY);
    k_fuse<64, 0><<<gF, 256, 0, stream>>>(gw, 128, gd, bufC, cbX, G1, nullptr, G2, nullptr, N);
    k_gfin<<<gE, 256, 0, stream>>>(G1, G2, bufA, N);
    k_fuse<64, 0><<<gF, 256, 0, stream>>>(gw, 128, gd, bufD, cbY, G1, nullptr, G2, nullptr, N);
    k_gfin<<<gE, 256, 0, stream>>>(G1, G2, bufB, N);

    // ---- score + top-half selection
    int Nh = N / 2;
    k_parmean<<<dim3((B * 3 * N + 255) / 256), 256, 0, stream>>>(bufA, bufB, px, py, N, B);
    k_dotphi<<<dim3((B * N + 255) / 256), 256, 0, stream>>>(bufA, bufB, px, py, dps, N, B);
    k_topsel<<<dim3(B), 1024, 0, stream>>>(dps, sel, N, Nh);
    k_gather<<<dim3((B * 192 * Nh + 255) / 256), 256, 0, stream>>>(bufA, bufB, sel, bufC, bufD, N, Nh, B);
    k_cmean2<<<dim3(192, B, 2), 256, 0, stream>>>(bufC, bufD, blkX, blkY, Nh, 384, blk * 192, 1.f / (float)Nh);
    fx = bufC; fy = bufD;
    N = Nh;
  }
  k_head<<<dim3(2, B), 96, 0, stream>>>(blkX, blkY, W[22], W[23], Fxb, Fyb);
  k_svd<<<dim3(B), 64, 0, stream>>>(Fxb, Fyb, (float*)d_out, B);
}

// Round 5
// 2626.041 us; speedup vs baseline: 2.8382x; 2.8382x over previous
//
#include <hip/hip_runtime.h>
#include <math.h>

#define SLOPE 0.2f
#define EPSV 1e-12f
#define NEGINF (-3.0e38f)

static __device__ __forceinline__ float lrelu_combine(float xv, float dvv, float dot, float dsq) {
  float xneg = xv - dot / (dsq + EPSV) * dvv;
  float w = (dot >= 0.f) ? xv : xneg;
  return SLOPE * xv + (1.f - SLOPE) * w;
}

// ---------------- squared norms per point ----------------
__global__ void k_xx(const float* __restrict__ x, float* __restrict__ xx, int D, int N) {
  int b = blockIdx.y;
  int m = blockIdx.x * 256 + threadIdx.x;
  if (m >= N) return;
  const float* xp = x + (size_t)b * D * N + m;
  float s = 0.f;
  for (int d = 0; d < D; ++d) { float v = xp[(size_t)d * N]; s = fmaf(v, v, s); }
  xx[b * N + m] = s;
}

// ---------------- knn top-16, 4 queries per block (exact lax.top_k order & ties) ----------------
// dist arithmetic identical to round-2/3 passing versions: ascending-d fmaf chain, 2*dot - xxn - xxm.
template <int D>
__global__ void __launch_bounds__(256) k_knn2(const float* __restrict__ x,
                                              const float* __restrict__ xx,
                                              int* __restrict__ idx, int N) {
  __shared__ float qt[D * 4];        // qt[d*4+qi]
  __shared__ float dist[4][2048];
  __shared__ float xxq[4];
  int b = blockIdx.y, tid = threadIdx.x;
  int q0 = blockIdx.x * 4;
  const float* xb = x + (size_t)b * D * N;
  for (int i = tid; i < D * 4; i += 256) qt[i] = xb[(size_t)(i >> 2) * N + q0 + (i & 3)];
  if (tid < 4) xxq[tid] = xx[b * N + q0 + tid];
  __syncthreads();
  int kmax = N >> 8;
  for (int k = 0; k < kmax; ++k) {
    int m = tid + 256 * k;
    float a0 = 0.f, a1 = 0.f, a2 = 0.f, a3 = 0.f;
#pragma unroll 8
    for (int d = 0; d < D; ++d) {
      float xv = xb[(size_t)d * N + m];
      const float4 q4 = *(const float4*)&qt[d * 4];
      a0 = fmaf(q4.x, xv, a0);
      a1 = fmaf(q4.y, xv, a1);
      a2 = fmaf(q4.z, xv, a2);
      a3 = fmaf(q4.w, xv, a3);
    }
    float xxm = xx[b * N + m];
    dist[0][m] = 2.f * a0 - xxq[0] - xxm;
    dist[1][m] = 2.f * a1 - xxq[1] - xxm;
    dist[2][m] = 2.f * a2 - xxq[2] - xxm;
    dist[3][m] = 2.f * a3 - xxq[3] - xxm;
  }
  __syncthreads();
  // selection: wave g handles query q0+g; no barriers (wave-private row)
  int g = tid >> 6, lane = tid & 63;
  float* dr = dist[g];
  int n = q0 + g;
  int imax = N >> 8;
  int* op = idx + ((size_t)b * N + n) * 16;
  for (int r = 0; r < 16; ++r) {
    float bv = NEGINF;
    int bi = N;
    for (int i = 0; i < imax; ++i) {
      int mb = i * 256 + lane * 4;
      float4 v = *(const float4*)&dr[mb];
      if (v.x > bv) { bv = v.x; bi = mb; }
      if (v.y > bv) { bv = v.y; bi = mb + 1; }
      if (v.z > bv) { bv = v.z; bi = mb + 2; }
      if (v.w > bv) { bv = v.w; bi = mb + 3; }
    }
#pragma unroll
    for (int s = 1; s < 64; s <<= 1) {
      float ov = __shfl_xor(bv, s, 64);
      int oi = __shfl_xor(bi, s, 64);
      if (ov > bv || (ov == bv && oi < bi)) { bv = ov; bi = oi; }
    }
    if (lane == 0) { op[r] = bi; dr[bi] = NEGINF; }
  }
}

// ---------------- generic 64-out linear: out[b][o][d][n] = sum_k Wl[o][k]*X[b][k][d][n] + bias ----
// Wl[o][k] = W[o*ws + woff + k] - (sub ? W[o*ws + k] : 0)
// Round-3-proven: ~100 live VGPRs (xv[64]+acc[16]), no spill.
template <int KT>
__global__ void __launch_bounds__(256) k_lin(const float* __restrict__ W, int ws, int woff, int sub,
                                             const float* __restrict__ X,
                                             const float* __restrict__ bias,
                                             float* __restrict__ out, int N) {
  __shared__ float wl[64 * ((KT + 3) & ~3)];
  const int KP = (KT + 3) & ~3;
  int tid = threadIdx.x;
  for (int i = tid; i < 64 * KT; i += 256) {
    int o = i / KT, k = i - o * KT;
    float v = W[o * ws + woff + k];
    if (sub) v -= W[o * ws + k];
    wl[o * KP + k] = v;
  }
  __syncthreads();
  int b = blockIdx.y;
  int oc = blockIdx.z * 16;
  int j = blockIdx.x * 256 + tid;  // column in [0, 3N)
  int M3 = 3 * N;
  if (j >= M3) return;
  const float* Xb = X + (size_t)b * KT * M3;
  float xv[KT];
#pragma unroll
  for (int k = 0; k < KT; ++k) xv[k] = Xb[(size_t)k * M3 + j];
  int d = j / N;
  float acc[16];
  if (bias) {
#pragma unroll
    for (int oo = 0; oo < 16; ++oo) acc[oo] = bias[b * 192 + (oc + oo) * 3 + d];
  } else {
#pragma unroll
    for (int oo = 0; oo < 16; ++oo) acc[oo] = 0.f;
  }
#pragma unroll
  for (int oo = 0; oo < 16; ++oo) {
    const float* wr = &wl[(oc + oo) * KP];
    float s = acc[oo];
#pragma unroll
    for (int k = 0; k < KT; ++k) s = fmaf(wr[k], xv[k], s);
    acc[oo] = s;
  }
  float* ob = out + (size_t)b * 64 * M3;
#pragma unroll
  for (int oo = 0; oo < 16; ++oo) ob[(size_t)(oc + oo) * M3 + j] = acc[oo];
}

// ---------------- edge conv via precomputed P1,P2,D1,D2: out = mean_j lrelu ----------------
__global__ void __launch_bounds__(256) k_edge2(const float* __restrict__ P1, const float* __restrict__ P2,
                                               const float* __restrict__ D1, const float* __restrict__ D2,
                                               const int* __restrict__ idx,
                                               float* __restrict__ out, int N) {
  int gi = blockIdx.x * 256 + threadIdx.x;
  int total = 2 * 64 * N;
  if (gi >= total) return;
  int n = gi % N;
  int t = gi / N;
  int o = t & 63, b = t >> 6;
  size_t r0 = (size_t)((b * 64 + o) * 3) * N;
  float p2[3], d2[3];
#pragma unroll
  for (int d = 0; d < 3; ++d) { p2[d] = P2[r0 + (size_t)d * N + n]; d2[d] = D2[r0 + (size_t)d * N + n]; }
  const int* ip = idx + ((size_t)b * N + n) * 16;
  float acc0 = 0.f, acc1 = 0.f, acc2 = 0.f;
  for (int j = 0; j < 16; ++j) {
    int m = ip[j];
    float xl[3], dv[3];
#pragma unroll
    for (int d = 0; d < 3; ++d) {
      xl[d] = P1[r0 + (size_t)d * N + m] + p2[d];
      dv[d] = D1[r0 + (size_t)d * N + m] + d2[d];
    }
    float dot = xl[0] * dv[0] + xl[1] * dv[1] + xl[2] * dv[2];
    float dsq = dv[0] * dv[0] + dv[1] * dv[1] + dv[2] * dv[2];
    acc0 += lrelu_combine(xl[0], dv[0], dot, dsq);
    acc1 += lrelu_combine(xl[1], dv[1], dot, dsq);
    acc2 += lrelu_combine(xl[2], dv[2], dot, dsq);
  }
  out[r0 + n] = acc0 * (1.f / 16.f);
  out[r0 + N + n] = acc1 * (1.f / 16.f);
  out[r0 + 2 * (size_t)N + n] = acc2 * (1.f / 16.f);
}

// ---------------- Qx finisher: lrelu + chnorm (wave per point, lane = channel) ----------------
__global__ void __launch_bounds__(256) k_qfin(const float* __restrict__ XL, const float* __restrict__ DV,
                                              float* __restrict__ out, int N) {
  int tid = threadIdx.x;
  int p = blockIdx.x * 4 + (tid >> 6);
  int c = tid & 63;
  int b = p / N, n = p - b * N;
  size_t r0 = (size_t)((b * 64 + c) * 3) * N;
  float xl[3], dv[3];
#pragma unroll
  for (int d = 0; d < 3; ++d) { xl[d] = XL[r0 + (size_t)d * N + n]; dv[d] = DV[r0 + (size_t)d * N + n]; }
  float dot = xl[0] * dv[0] + xl[1] * dv[1] + xl[2] * dv[2];
  float dsq = dv[0] * dv[0] + dv[1] * dv[1] + dv[2] * dv[2];
  float z[3];
#pragma unroll
  for (int d = 0; d < 3; ++d) z[d] = lrelu_combine(xl[d], dv[d], dot, dsq);
  float n2 = z[0] * z[0] + z[1] * z[1] + z[2] * z[2];
  float cn2 = n2;
#pragma unroll
  for (int s = 1; s < 64; s <<= 1) cn2 += __shfl_xor(cn2, s, 64);
  float n_o = sqrtf(n2), cn = sqrtf(cn2);
  float scl = (n_o / fmaxf(cn, EPSV)) / fmaxf(n_o, EPSV);
#pragma unroll
  for (int d = 0; d < 3; ++d) out[r0 + (size_t)d * N + n] = z[d] * scl;
}

// ---------------- K path: wave per edge -> logits (lane = channel) ----------------
__global__ void __launch_bounds__(256) k_klog2(const float* __restrict__ qx,
                                               const float* __restrict__ P1, const float* __restrict__ P2,
                                               const float* __restrict__ D1, const float* __restrict__ D2,
                                               const int* __restrict__ idx,
                                               float* __restrict__ logits, int N) {
  int tid = threadIdx.x;
  int e = blockIdx.x * 4 + (tid >> 6);
  int c = tid & 63;
  int b = e / (N * 16);
  int r = e - b * N * 16;
  int n = r >> 4, j = r & 15;
  int m = idx[((size_t)b * N + n) * 16 + j];
  size_t r0 = (size_t)((b * 64 + c) * 3) * N;
  float xl[3], dv[3], qv[3];
#pragma unroll
  for (int d = 0; d < 3; ++d) {
    size_t rd = r0 + (size_t)d * N;
    xl[d] = P1[rd + m] + P2[rd + n];
    dv[d] = D1[rd + m] + D2[rd + n];
    qv[d] = qx[rd + n];
  }
  float dot = xl[0] * dv[0] + xl[1] * dv[1] + xl[2] * dv[2];
  float dsq = dv[0] * dv[0] + dv[1] * dv[1] + dv[2] * dv[2];
  float z[3];
#pragma unroll
  for (int d = 0; d < 3; ++d) z[d] = lrelu_combine(xl[d], dv[d], dot, dsq);
  float n2 = z[0] * z[0] + z[1] * z[1] + z[2] * z[2];
  float cn2 = n2;
#pragma unroll
  for (int s = 1; s < 64; s <<= 1) cn2 += __shfl_xor(cn2, s, 64);
  float n_o = sqrtf(n2), cn = sqrtf(cn2);
  float scl = (n_o / fmaxf(cn, EPSV)) / fmaxf(n_o, EPSV);
  float part = (z[0] * qv[0] + z[1] * qv[1] + z[2] * qv[2]) * scl;
#pragma unroll
  for (int s = 1; s < 32; s <<= 1) part += __shfl_xor(part, s, 32);
  if ((c & 31) == 0) {
    int h = c >> 5;
    logits[(((size_t)b * 2 + h) * N + n) * 16 + j] = part * 0.102062072615966f; // 1/sqrt(96)
  }
}

// ---------------- softmax over 16 neighbors ----------------
__global__ void k_soft(const float* __restrict__ logits, float* __restrict__ att, int N) {
  int gi = blockIdx.x * 256 + threadIdx.x;
  if (gi >= 2 * 2 * N) return;
  const float* lp = logits + (size_t)gi * 16;
  float* ap = att + (size_t)gi * 16;
  float mx = lp[0];
  for (int j = 1; j < 16; ++j) mx = fmaxf(mx, lp[j]);
  float e[16]; float sum = 0.f;
  for (int j = 0; j < 16; ++j) { e[j] = expf(lp[j] - mx); sum += e[j]; }
  float inv = 1.f / sum;
  for (int j = 0; j < 16; ++j) ap[j] = e[j] * inv;
}

// ---------------- V path + attention-weighted sum + residual ----------------
__global__ void __launch_bounds__(256) k_attout2(const float* __restrict__ xres,
                                                 const float* __restrict__ P1, const float* __restrict__ P2,
                                                 const float* __restrict__ D1, const float* __restrict__ D2,
                                                 const float* __restrict__ att,
                                                 const int* __restrict__ idx,
                                                 float* __restrict__ out, int N) {
  int gi = blockIdx.x * 256 + threadIdx.x;
  int total = 2 * 64 * N;
  if (gi >= total) return;
  int n = gi % N;
  int t = gi / N;
  int o = t & 63, b = t >> 6;
  int h = o >> 5;
  size_t r0 = (size_t)((b * 64 + o) * 3) * N;
  float p2[3], d2[3];
#pragma unroll
  for (int d = 0; d < 3; ++d) { p2[d] = P2[r0 + (size_t)d * N + n]; d2[d] = D2[r0 + (size_t)d * N + n]; }
  const int* ip = idx + ((size_t)b * N + n) * 16;
  const float* ap = att + (((size_t)b * 2 + h) * N + n) * 16;
  float acc0 = 0.f, acc1 = 0.f, acc2 = 0.f;
  for (int j = 0; j < 16; ++j) {
    int m = ip[j];
    float av = ap[j];
    float xl[3], dv[3];
#pragma unroll
    for (int d = 0; d < 3; ++d) {
      xl[d] = P1[r0 + (size_t)d * N + m] + p2[d];
      dv[d] = D1[r0 + (size_t)d * N + m] + d2[d];
    }
    float dot = xl[0] * dv[0] + xl[1] * dv[1] + xl[2] * dv[2];
    float dsq = dv[0] * dv[0] + dv[1] * dv[1] + dv[2] * dv[2];
    acc0 = fmaf(av, lrelu_combine(xl[0], dv[0], dot, dsq), acc0);
    acc1 = fmaf(av, lrelu_combine(xl[1], dv[1], dot, dsq), acc1);
    acc2 = fmaf(av, lrelu_combine(xl[2], dv[2], dot, dsq), acc2);
  }
  out[r0 + n] = xres[r0 + n] + acc0;
  out[r0 + N + n] = xres[r0 + N + n] + acc1;
  out[r0 + 2 * (size_t)N + n] = xres[r0 + 2 * (size_t)N + n] + acc2;
}

// ---------------- g-fuse finisher: elementwise lrelu ----------------
__global__ void __launch_bounds__(256) k_gfin(const float* __restrict__ XL, const float* __restrict__ DV,
                                              float* __restrict__ out, int N) {
  int gi = blockIdx.x * 256 + threadIdx.x;
  int total = 2 * 64 * N;
  if (gi >= total) return;
  int n = gi % N;
  int t = gi / N;
  int o = t & 63, b = t >> 6;
  size_t r0 = (size_t)((b * 64 + o) * 3) * N;
  float xl[3], dv[3];
#pragma unroll
  for (int d = 0; d < 3; ++d) { xl[d] = XL[r0 + (size_t)d * N + n]; dv[d] = DV[r0 + (size_t)d * N + n]; }
  float dot = xl[0] * dv[0] + xl[1] * dv[1] + xl[2] * dv[2];
  float dsq = dv[0] * dv[0] + dv[1] * dv[1] + dv[2] * dv[2];
#pragma unroll
  for (int d = 0; d < 3; ++d) out[r0 + (size_t)d * N + n] = lrelu_combine(xl[d], dv[d], dot, dsq);
}

// ---------------- bias for g-fuse, both sides in one launch ----------------
__global__ void k_gbias2(const float* __restrict__ gw, const float* __restrict__ meanX,
                         const float* __restrict__ meanY,
                         float* __restrict__ cbX, float* __restrict__ cbY) {
  int b = blockIdx.x, which = blockIdx.y, tid = threadIdx.x;  // 192 threads
  int o = tid / 3, d = tid - o * 3;
  const float* mb = (which ? meanY : meanX) + b * 192;
  float* cb = (which ? cbY : cbX);
  float s = 0.f;
  for (int c = 0; c < 64; ++c) s = fmaf(gw[o * 128 + 64 + c], mb[c * 3 + d], s);
  cb[b * 192 + tid] = s;
}

// ---------------- column mean over N for both arrays in one launch ----------------
__global__ void k_cmean2(const float* __restrict__ x1, const float* __restrict__ x2,
                         float* __restrict__ o1, float* __restrict__ o2,
                         int N, int ostride, int obase, float inv) {
  __shared__ float red[256];
  int b = blockIdx.y, cd = blockIdx.x, which = blockIdx.z, tid = threadIdx.x;
  const float* x = which ? x2 : x1;
  float* out = which ? o2 : o1;
  const float* p = x + ((size_t)b * 192 + cd) * N;
  float s = 0.f;
  for (int i = tid; i < N; i += 256) s += p[i];
  red[tid] = s;
  __syncthreads();
  for (int st = 128; st > 0; st >>= 1) {
    if (tid < st) red[tid] += red[tid + st];
    __syncthreads();
  }
  if (tid == 0) out[(size_t)b * ostride + obase + cd] = red[0] * inv;
}

// ---------------- channel-mean (fx_par pre-normalization) for both arrays ----------------
__global__ void k_parmean(const float* __restrict__ fx, const float* __restrict__ fy,
                          float* __restrict__ px, float* __restrict__ py, int N, int B) {
  int gi = blockIdx.x * 256 + threadIdx.x;
  int total = B * 3 * N;
  if (gi >= total) return;
  int b = gi / (3 * N);
  int r = gi - b * 3 * N;
  const float* fxb = fx + (size_t)b * 192 * N + r;
  const float* fyb = fy + (size_t)b * 192 * N + r;
  float sx = 0.f, sy = 0.f;
  for (int c = 0; c < 64; ++c) { sx += fxb[(size_t)c * 3 * N]; sy += fyb[(size_t)c * 3 * N]; }
  px[gi] = sx * (1.f / 64.f);
  py[gi] = sy * (1.f / 64.f);
}

// ---------------- score logits: sum_c (fx.px)(fy.py) (softmax+norm skipped: monotone) ----------------
__global__ void k_dotphi(const float* __restrict__ fx, const float* __restrict__ fy,
                         const float* __restrict__ px, const float* __restrict__ py,
                         float* __restrict__ dps, int N, int B) {
  int gi = blockIdx.x * 256 + threadIdx.x;
  if (gi >= B * N) return;
  int b = gi / N, n = gi - b * N;
  const float* fxb = fx + (size_t)b * 192 * N + n;
  const float* fyb = fy + (size_t)b * 192 * N + n;
  const float* pxb = px + (size_t)b * 3 * N + n;
  const float* pyb = py + (size_t)b * 3 * N + n;
  float acc = 0.f;
  for (int c = 0; c < 64; ++c) {
    float ax = 0.f, ay = 0.f;
    for (int d = 0; d < 3; ++d) {
      ax = fmaf(fxb[(size_t)(c * 3 + d) * N], pxb[(size_t)d * N], ax);
      ay = fmaf(fyb[(size_t)(c * 3 + d) * N], pyb[(size_t)d * N], ay);
    }
    acc = fmaf(ax, ay, acc);
  }
  dps[gi] = acc;
}

// ---------------- top-N/2 selection: bitonic sort (desc value, asc index) ----------------
__global__ void __launch_bounds__(1024) k_topsel(const float* __restrict__ dps,
                                                 int* __restrict__ sel, int N, int Nh) {
  __shared__ float kv[2048];
  __shared__ int ki[2048];
  int b = blockIdx.x, tid = threadIdx.x;
  for (int i = tid; i < N; i += 1024) { kv[i] = dps[b * N + i]; ki[i] = i; }
  __syncthreads();
  for (int kk = 2; kk <= N; kk <<= 1) {
    for (int jj = kk >> 1; jj > 0; jj >>= 1) {
      for (int i = tid; i < N; i += 1024) {
        int ixj = i ^ jj;
        if (ixj > i) {
          float va = kv[i], vb = kv[ixj];
          int ia = ki[i], ib = ki[ixj];
          bool aFirst = (va > vb) || (va == vb && ia < ib);
          bool up = ((i & kk) == 0);
          bool doswap = up ? (!aFirst) : aFirst;
          if (doswap) { kv[i] = vb; kv[ixj] = va; ki[i] = ib; ki[ixj] = ia; }
        }
      }
      __syncthreads();
    }
  }
  for (int i = tid; i < Nh; i += 1024) sel[b * Nh + i] = ki[i];
}

// ---------------- gather selected points for both arrays ----------------
__global__ void k_gather(const float* __restrict__ sx, const float* __restrict__ sy,
                         const int* __restrict__ sel,
                         float* __restrict__ dx, float* __restrict__ dy,
                         int N, int Nh, int B) {
  int gi = blockIdx.x * 256 + threadIdx.x;
  int total = B * 192 * Nh;
  if (gi >= total) return;
  int i = gi % Nh;
  int t = gi / Nh;
  int cd = t % 192;
  int b = t / 192;
  int s = sel[b * Nh + i];
  dx[gi] = sx[((size_t)b * 192 + cd) * N + s];
  dy[gi] = sy[((size_t)b * 192 + cd) * N + s];
}

// ---------------- final head: vn_lin_lrelu(concat blocks, h_w, h_d) ----------------
__global__ void k_head(const float* __restrict__ blkX, const float* __restrict__ blkY,
                       const float* __restrict__ hw, const float* __restrict__ hd,
                       float* __restrict__ Fx, float* __restrict__ Fy) {
  __shared__ float f[3][128];
  __shared__ float xl[3][32];
  __shared__ float dv[3][32];
  int which = blockIdx.x, b = blockIdx.y, tid = threadIdx.x;
  const float* blk = which ? blkY : blkX;
  float* F = which ? Fy : Fx;
  int o = tid & 31, dd = tid >> 5;
  for (int i = tid; i < 384; i += 96) f[i % 3][i / 3] = blk[(size_t)b * 384 + i];
  __syncthreads();
  float s = 0.f;
  for (int c = 0; c < 128; ++c) s = fmaf(hw[o * 128 + c], f[dd][c], s);
  xl[dd][o] = s;
  __syncthreads();
  float s2 = 0.f;
  for (int p = 0; p < 32; ++p) s2 = fmaf(hd[o * 32 + p], xl[dd][p], s2);
  dv[dd][o] = s2;
  __syncthreads();
  float dot = xl[0][o] * dv[0][o] + xl[1][o] * dv[1][o] + xl[2][o] * dv[2][o];
  float dsq = dv[0][o] * dv[0][o] + dv[1][o] * dv[1][o] + dv[2][o] * dv[2][o];
  F[((size_t)b * 32 + o) * 3 + dd] = lrelu_combine(xl[dd][o], dv[dd][o], dot, dsq);
}

// ================== LAPACK-faithful 3x3 SVD (dgesdd path: dgebrd + dbdsqr) ==================
#define DEPS 2.220446049250313e-16
#define DUNFL 2.2250738585072014e-308

static __device__ void dlartg_(double f, double g, double* cs, double* sn, double* r) {
  if (g == 0.0) { *cs = 1.0; *sn = 0.0; *r = f; }
  else if (f == 0.0) { *cs = 0.0; *sn = copysign(1.0, g); *r = fabs(g); }
  else {
    double d = sqrt(f * f + g * g);
    double c = fabs(f) / d;
    double rr = copysign(d, f);
    *cs = c; *r = rr; *sn = g / rr;
  }
}

static __device__ void dlas2_(double f, double g, double h, double* ssmin, double* ssmax) {
  double fa = fabs(f), ga = fabs(g), ha = fabs(h);
  double fhmn = fmin(fa, ha), fhmx = fmax(fa, ha);
  if (fhmn == 0.0) {
    *ssmin = 0.0;
    if (fhmx == 0.0) *ssmax = ga;
    else { double mx = fmax(fhmx, ga), mn = fmin(fhmx, ga); double q = mn / mx; *ssmax = mx * sqrt(1.0 + q * q); }
  } else {
    if (ga < fhmx) {
      double as_ = 1.0 + fhmn / fhmx;
      double at = (fhmx - fhmn) / fhmx;
      double au = ga / fhmx; au = au * au;
      double c = 2.0 / (sqrt(as_ * as_ + au) + sqrt(at * at + au));
      *ssmin = fhmn * c; *ssmax = fhmx / c;
    } else {
      double au = fhmx / ga;
      if (au == 0.0) { *ssmin = (fhmn * fhmx) / ga; *ssmax = ga; }
      else {
        double as_ = 1.0 + fhmn / fhmx;
        double at = (fhmx - fhmn) / fhmx;
        double t1 = as_ * au, t2 = at * au;
        double c = 1.0 / (sqrt(1.0 + t1 * t1) + sqrt(1.0 + t2 * t2));
        double sm = (fhmn * c) * au; *ssmin = sm + sm;
        *ssmax = ga / (c + c);
      }
    }
  }
}

static __device__ void dlasv2_(double f, double g, double h,
                               double* ssmin, double* ssmax,
                               double* snr, double* csr, double* snl, double* csl) {
  double ft = f, fa = fabs(f), ht = h, ha = fabs(h);
  int pmax = 1;
  bool swp = (ha > fa);
  if (swp) { pmax = 3; double t = ft; ft = ht; ht = t; t = fa; fa = ha; ha = t; }
  double gt = g, ga = fabs(g);
  double clt = 0, crt = 0, slt = 0, srt = 0;
  if (ga == 0.0) {
    *ssmin = ha; *ssmax = fa; clt = 1.0; crt = 1.0; slt = 0.0; srt = 0.0;
  } else {
    bool gasmal = true;
    if (ga > fa) {
      pmax = 2;
      if ((fa / ga) < DEPS) {
        gasmal = false;
        *ssmax = ga;
        *ssmin = (ha > 1.0) ? (fa / (ga / ha)) : ((fa / ga) * ha);
        clt = 1.0; slt = ht / gt; srt = 1.0; crt = ft / gt;
      }
    }
    if (gasmal) {
      double dd = fa - ha;
      double l = (dd == fa) ? 1.0 : (dd / fa);
      double mq = gt / ft;
      double t = 2.0 - l;
      double mm = mq * mq, tt = t * t;
      double s = sqrt(tt + mm);
      double r = (l == 0.0) ? fabs(mq) : sqrt(l * l + mm);
      double a = 0.5 * (s + r);
      *ssmin = ha / a;
      *ssmax = fa * a;
      if (mm == 0.0) {
        if (l == 0.0) t = copysign(2.0, ft) * copysign(1.0, gt);
        else t = gt / copysign(dd, ft) + mq / t;
      } else {
        t = (mq / (s + t) + mq / (r + l)) * (1.0 + a);
      }
      double l2 = sqrt(t * t + 4.0);
      crt = 2.0 / l2;
      srt = t / l2;
      clt = (crt + srt * mq) / a;
      slt = (ht / ft) * srt / a;
    }
  }
  if (swp) { *csl = srt; *snl = crt; *csr = slt; *snr = clt; }
  else { *csl = clt; *snl = slt; *csr = crt; *snr = srt; }
  double tsign = 0.0;
  if (pmax == 1) tsign = copysign(1.0, *csr) * copysign(1.0, *csl) * copysign(1.0, f);
  if (pmax == 2) tsign = copysign(1.0, *snr) * copysign(1.0, *csl) * copysign(1.0, g);
  if (pmax == 3) tsign = copysign(1.0, *snr) * copysign(1.0, *snl) * copysign(1.0, h);
  *ssmax = copysign(*ssmax, tsign);
  *ssmin = copysign(*ssmin, tsign * copysign(1.0, f) * copysign(1.0, h));
}

static __device__ void dbdsqr3(double d[3], double e[2], double VT[3][3], double U[3][3]) {
  const int n = 3;
  double tolmul = fmax(10.0, fmin(100.0, pow(DEPS, -0.125)));
  double tol = tolmul * DEPS;
  double thresh;
  {
    double sminoa = fabs(d[0]);
    if (sminoa != 0.0) {
      double mu = sminoa;
      for (int i = 1; i < n; ++i) {
        mu = fabs(d[i]) * (mu / (mu + fabs(e[i - 1])));
        sminoa = fmin(sminoa, mu);
        if (sminoa == 0.0) break;
      }
    }
    sminoa = sminoa / sqrt((double)n);
    thresh = fmax(tol * sminoa, 6.0 * n * n * DUNFL);
  }
  int maxit = 6 * n * n;
  int iter = 0, oldll = -1, oldm = -1, idir = 0;
  int m = n;
  double sminl = 0.0;
  int guard = 0;
  while (true) {
    if (m <= 1) break;
    if (iter > maxit) break;
    if (++guard > 500) break;
    double smaxb = fabs(d[m - 1]);
    int ll = 0; bool found = false;
    for (int lll = 1; lll <= m - 1; ++lll) {
      int l = m - lll;
      double abss = fabs(d[l - 1]);
      double abse = fabs(e[l - 1]);
      if (abse <= thresh) { ll = l; found = true; break; }
      smaxb = fmax(smaxb, fmax(abss, abse));
    }
    if (found) {
      e[ll - 1] = 0.0;
      if (ll == m - 1) { m = m - 1; continue; }
      ll = ll + 1;
    } else ll = 1;
    if (ll == m - 1) {
      double sigmn, sigmx, sinr, cosr, sinl2, cosl2;
      dlasv2_(d[m - 2], e[m - 2], d[m - 1], &sigmn, &sigmx, &sinr, &cosr, &sinl2, &cosl2);
      d[m - 2] = sigmx; d[m - 1] = sigmn; e[m - 2] = 0.0;
      for (int j = 0; j < 3; ++j) {
        double t1 = VT[m - 2][j], t2 = VT[m - 1][j];
        VT[m - 2][j] = cosr * t1 + sinr * t2;
        VT[m - 1][j] = cosr * t2 - sinr * t1;
      }
      for (int i2 = 0; i2 < 3; ++i2) {
        double t1 = U[i2][m - 2], t2 = U[i2][m - 1];
        U[i2][m - 2] = cosl2 * t1 + sinl2 * t2;
        U[i2][m - 1] = cosl2 * t2 - sinl2 * t1;
      }
      m -= 2;
      continue;
    }
    if (ll > oldm || m < oldll)
      idir = (fabs(d[ll - 1]) >= fabs(d[m - 1])) ? 1 : 2;
    if (idir == 1) {
      if (fabs(e[m - 2]) <= tol * fabs(d[m - 1])) { e[m - 2] = 0.0; continue; }
      double mu = fabs(d[ll - 1]); sminl = mu;
      bool conv = true;
      for (int lll = ll; lll <= m - 1; ++lll) {
        if (fabs(e[lll - 1]) > tol * mu) { conv = false; break; }
        mu = fabs(d[lll]) * (mu / (mu + fabs(e[lll - 1])));
        sminl = fmin(sminl, mu);
      }
      if (conv) { e[m - 2] = 0.0; continue; }
    } else {
      if (fabs(e[ll - 1]) <= tol * fabs(d[ll - 1])) { e[ll - 1] = 0.0; continue; }
      double mu = fabs(d[m - 1]); sminl = mu;
      bool conv = true;
      for (int lll = m - 1; lll >= ll; --lll) {
        if (fabs(e[lll - 1]) > tol * mu) { conv = false; break; }
        mu = fabs(d[lll - 1]) * (mu / (mu + fabs(e[lll - 1])));
        sminl = fmin(sminl, mu);
      }
      if (conv) { e[ll - 1] = 0.0; continue; }
    }
    oldll = ll; oldm = m;
    double shift = 0.0, rr;
    if (!(n * tol * (sminl / smaxb) <= fmax(DEPS, 0.01 * tol))) {
      double sll;
      if (idir == 1) { sll = fabs(d[ll - 1]); dlas2_(d[m - 2], e[m - 2], d[m - 1], &shift, &rr); }
      else { sll = fabs(d[m - 1]); dlas2_(d[ll - 1], e[ll - 1], d[ll], &shift, &rr); }
      if (sll > 0.0) { double q = shift / sll; if (q * q < DEPS) shift = 0.0; }
    }
    iter += m - ll;
    double csv[2], snv[2], ocsv[2], osnv[2];
    int cnt = 0;
    if (shift == 0.0) {
      if (idir == 1) {
        double cs = 1.0, oldcs = 1.0, sn = 0.0, oldsn = 0.0, r;
        for (int i = ll; i <= m - 1; ++i) {
          dlartg_(d[i - 1] * cs, e[i - 1], &cs, &sn, &r);
          if (i > ll) e[i - 2] = oldsn * r;
          dlartg_(oldcs * r, d[i] * sn, &oldcs, &oldsn, &d[i - 1]);
          csv[cnt] = cs; snv[cnt] = sn; ocsv[cnt] = oldcs; osnv[cnt] = oldsn; cnt++;
        }
        double hh = d[m - 1] * cs;
        d[m - 1] = hh * oldcs;
        e[m - 2] = hh * oldsn;
        for (int k = 0; k < cnt; ++k) {
          int r0 = ll - 1 + k, r1 = r0 + 1;
          for (int j = 0; j < 3; ++j) {
            double t1 = VT[r0][j], t2 = VT[r1][j];
            VT[r0][j] = snv[k] * t2 + csv[k] * t1;
            VT[r1][j] = csv[k] * t2 - snv[k] * t1;
          }
        }
        for (int k = 0; k < cnt; ++k) {
          int c0 = ll - 1 + k, c1 = c0 + 1;
          for (int i2 = 0; i2 < 3; ++i2) {
            double t1 = U[i2][c0], t2 = U[i2][c1];
            U[i2][c0] = osnv[k] * t2 + ocsv[k] * t1;
            U[i2][c1] = ocsv[k] * t2 - osnv[k] * t1;
          }
        }
        if (fabs(e[m - 2]) <= thresh) e[m - 2] = 0.0;
      } else {
        double cs = 1.0, oldcs = 1.0, sn = 0.0, oldsn = 0.0, r;
        for (int i = m; i >= ll + 1; --i) {
          dlartg_(d[i - 1] * cs, e[i - 2], &cs, &sn, &r);
          if (i < m) e[i - 1] = oldsn * r;
          dlartg_(oldcs * r, d[i - 2] * sn, &oldcs, &oldsn, &d[i - 1]);
          int k = i - ll - 1;
          csv[k] = cs; snv[k] = -sn; ocsv[k] = oldcs; osnv[k] = -oldsn; cnt++;
        }
        double hh = d[ll - 1] * cs;
        d[ll - 1] = hh * oldcs;
        e[ll - 1] = hh * oldsn;
        for (int k = cnt - 1; k >= 0; --k) {
          int r0 = ll - 1 + k, r1 = r0 + 1;
          for (int j = 0; j < 3; ++j) {
            double t1 = VT[r0][j], t2 = VT[r1][j];
            VT[r0][j] = osnv[k] * t2 + ocsv[k] * t1;
            VT[r1][j] = ocsv[k] * t2 - osnv[k] * t1;
          }
        }
        for (int k = cnt - 1; k >= 0; --k) {
          int c0 = ll - 1 + k, c1 = c0 + 1;
          for (int i2 = 0; i2 < 3; ++i2) {
            double t1 = U[i2][c0], t2 = U[i2][c1];
            U[i2][c0] = snv[k] * t2 + csv[k] * t1;
            U[i2][c1] = csv[k] * t2 - snv[k] * t1;
          }
        }
        if (fabs(e[ll - 1]) <= thresh) e[ll - 1] = 0.0;
      }
    } else {
      if (idir == 1) {
        double f = (fabs(d[ll - 1]) - shift) * (copysign(1.0, d[ll - 1]) + shift / d[ll - 1]);
        double g = e[ll - 1];
        double cosr, sinr, cosl2, sinl2, r;
        for (int i = ll; i <= m - 1; ++i) {
          dlartg_(f, g, &cosr, &sinr, &r);
          if (i > ll) e[i - 2] = r;
          f = cosr * d[i - 1] + sinr * e[i - 1];
          e[i - 1] = cosr * e[i - 1] - sinr * d[i - 1];
          g = sinr * d[i];
          d[i] = cosr * d[i];
          dlartg_(f, g, &cosl2, &sinl2, &r);
          d[i - 1] = r;
          f = cosl2 * e[i - 1] + sinl2 * d[i];
          d[i] = cosl2 * d[i] - sinl2 * e[i - 1];
          if (i < m - 1) {
            g = sinl2 * e[i];
            e[i] = cosl2 * e[i];
          }
          csv[cnt] = cosr; snv[cnt] = sinr; ocsv[cnt] = cosl2; osnv[cnt] = sinl2; cnt++;
        }
        e[m - 2] = f;
        for (int k = 0; k < cnt; ++k) {
          int r0 = ll - 1 + k, r1 = r0 + 1;
          for (int j = 0; j < 3; ++j) {
            double t1 = VT[r0][j], t2 = VT[r1][j];
            VT[r0][j] = snv[k] * t2 + csv[k] * t1;
            VT[r1][j] = csv[k] * t2 - snv[k] * t1;
          }
        }
        for (int k = 0; k < cnt; ++k) {
          int c0 = ll - 1 + k, c1 = c0 + 1;
          for (int i2 = 0; i2 < 3; ++i2) {
            double t1 = U[i2][c0], t2 = U[i2][c1];
            U[i2][c0] = osnv[k] * t2 + ocsv[k] * t1;
            U[i2][c1] = ocsv[k] * t2 - osnv[k] * t1;
          }
        }
        if (fabs(e[m - 2]) <= thresh) e[m - 2] = 0.0;
      } else {
        double f = (fabs(d[m - 1]) - shift) * (copysign(1.0, d[m - 1]) + shift / d[m - 1]);
        double g = e[m - 2];
        for (int i = m; i >= ll + 1; --i) {
          double cosr, sinr, cosl2, sinl2, r;
          dlartg_(f, g, &cosr, &sinr, &r);
          if (i < m) e[i - 1] = r;
          f = cosr * d[i - 1] + sinr * e[i - 2];
          e[i - 2] = cosr * e[i - 2] - sinr * d[i - 1];
          g = sinr * d[i - 2];
          d[i - 2] = cosr * d[i - 2];
          dlartg_(f, g, &cosl2, &sinl2, &r);
          d[i - 1] = r;
          f = cosl2 * e[i - 2] + sinl2 * d[i - 2];
          d[i - 2] = cosl2 * d[i - 2] - sinl2 * e[i - 2];
          if (i > ll + 1) {
            g = sinl2 * e[i - 3];
            e[i - 3] = cosl2 * e[i - 3];
          }
          int k = i - ll - 1;
          ocsv[k] = cosl2; osnv[k] = -sinl2; csv[k] = cosr; snv[k] = -sinr; cnt++;
        }
        e[ll - 1] = f;
        for (int k = cnt - 1; k >= 0; --k) {
          int r0 = ll - 1 + k, r1 = r0 + 1;
          for (int j = 0; j < 3; ++j) {
            double t1 = VT[r0][j], t2 = VT[r1][j];
            VT[r0][j] = snv[k] * t2 + csv[k] * t1;
            VT[r1][j] = csv[k] * t2 - snv[k] * t1;
          }
        }
        for (int k = cnt - 1; k >= 0; --k) {
          int c0 = ll - 1 + k, c1 = c0 + 1;
          for (int i2 = 0; i2 < 3; ++i2) {
            double t1 = U[i2][c0], t2 = U[i2][c1];
            U[i2][c0] = osnv[k] * t2 + ocsv[k] * t1;
            U[i2][c1] = ocsv[k] * t2 - osnv[k] * t1;
          }
        }
        if (fabs(e[ll - 1]) <= thresh) e[ll - 1] = 0.0;
      }
    }
  }
  for (int i = 0; i < n; ++i)
    if (d[i] < 0.0) { d[i] = -d[i]; for (int j = 0; j < 3; ++j) VT[i][j] = -VT[i][j]; }
  for (int i = 1; i <= n - 1; ++i) {
    int isub = 1; double smn = d[0];
    for (int j = 2; j <= n + 1 - i; ++j)
      if (d[j - 1] <= smn) { isub = j; smn = d[j - 1]; }
    if (isub != n + 1 - i) {
      int a = isub - 1, b2 = n - i;
      double t = d[a]; d[a] = d[b2]; d[b2] = t;
      for (int j = 0; j < 3; ++j) { t = VT[a][j]; VT[a][j] = VT[b2][j]; VT[b2][j] = t; }
      for (int j = 0; j < 3; ++j) { t = U[j][a]; U[j][a] = U[j][b2]; U[j][b2] = t; }
    }
  }
}

__global__ void k_svd(const float* __restrict__ Fx, const float* __restrict__ Fy,
                      float* __restrict__ out, int B) {
  int b = blockIdx.x;
  if (threadIdx.x != 0) return;
  double A[3][3];
  for (int d = 0; d < 3; ++d)
    for (int e = 0; e < 3; ++e) {
      double s = 0.0;
      for (int c = 0; c < 32; ++c)
        s += (double)Fx[((size_t)b * 32 + c) * 3 + d] * (double)Fy[((size_t)b * 32 + c) * 3 + e];
      A[d][e] = s;
    }
  double dg[3], eg[2], tauq0, tauq1, taup0;
  double v1_1 = 0, v1_2 = 0, v2_1 = 0, w1 = 0;
  {
    double alpha = A[0][0];
    double xn = sqrt(A[1][0] * A[1][0] + A[2][0] * A[2][0]);
    if (xn == 0.0) { tauq0 = 0.0; dg[0] = alpha; }
    else {
      double beta = -copysign(sqrt(alpha * alpha + xn * xn), alpha);
      tauq0 = (beta - alpha) / beta;
      double scal = 1.0 / (alpha - beta);
      v1_1 = A[1][0] * scal; v1_2 = A[2][0] * scal;
      dg[0] = beta;
    }
    for (int j = 1; j < 3; ++j) {
      double w = A[0][j] + v1_1 * A[1][j] + v1_2 * A[2][j];
      w *= tauq0;
      A[0][j] -= w; A[1][j] -= w * v1_1; A[2][j] -= w * v1_2;
    }
  }
  {
    double alpha = A[0][1];
    double xn = fabs(A[0][2]);
    if (xn == 0.0) { taup0 = 0.0; eg[0] = alpha; }
    else {
      double beta = -copysign(sqrt(alpha * alpha + xn * xn), alpha);
      taup0 = (beta - alpha) / beta;
      w1 = A[0][2] / (alpha - beta);
      eg[0] = beta;
    }
    for (int i = 1; i < 3; ++i) {
      double t = A[i][1] + w1 * A[i][2];
      t *= taup0;
      A[i][1] -= t; A[i][2] -= t * w1;
    }
  }
  {
    double alpha = A[1][1];
    double xn = fabs(A[2][1]);
    if (xn == 0.0) { tauq1 = 0.0; dg[1] = alpha; }
    else {
      double beta = -copysign(sqrt(alpha * alpha + xn * xn), alpha);
      tauq1 = (beta - alpha) / beta;
      v2_1 = A[2][1] / (alpha - beta);
      dg[1] = beta;
    }
    double w = A[1][2] + v2_1 * A[2][2];
    w *= tauq1;
    A[1][2] -= w; A[2][2] -= w * v2_1;
  }
  eg[1] = A[1][2];
  dg[2] = A[2][2];
  double U[3][3] = {{1, 0, 0}, {0, 1, 0}, {0, 0, 1}};
  double VT[3][3] = {{1, 0, 0}, {0, 1, 0}, {0, 0, 1}};
  dbdsqr3(dg, eg, VT, U);
  for (int j = 0; j < 3; ++j) {
    double w = U[1][j] + v2_1 * U[2][j];
    w *= tauq1;
    U[1][j] -= w; U[2][j] -= w * v2_1;
  }
  for (int j = 0; j < 3; ++j) {
    double w = U[0][j] + v1_1 * U[1][j] + v1_2 * U[2][j];
    w *= tauq0;
    U[0][j] -= w; U[1][j] -= w * v1_1; U[2][j] -= w * v1_2;
  }
  for (int r = 0; r < 3; ++r) {
    double t = VT[r][1] + w1 * VT[r][2];
    t *= taup0;
    VT[r][1] -= t; VT[r][2] -= t * w1;
  }
  for (int i = 0; i < 3; ++i)
    for (int j = 0; j < 3; ++j) {
      double r = 0;
      for (int k = 0; k < 3; ++k) r += U[i][k] * VT[j][k];
      out[b * 9 + i * 3 + j] = (float)r;
    }
  for (int dd = 0; dd < 3; ++dd) {
    float sx = 0.f, sy = 0.f;
    for (int c = 0; c < 32; ++c) {
      float vx = Fx[((size_t)b * 32 + c) * 3 + dd];
      float vy = Fy[((size_t)b * 32 + c) * 3 + dd];
      sx = fmaf(vx, vx, sx);
      sy = fmaf(vy, vy, sy);
    }
    out[B * 9 + b * 3 + dd] = sqrtf(sy) / sqrtf(sx);
  }
}

extern "C" void kernel_launch(void* const* d_in, const int* in_sizes, int n_in,
                              void* d_out, int out_size, void* d_ws, size_t ws_size,
                              hipStream_t stream) {
  (void)in_sizes; (void)n_in; (void)out_size; (void)ws_size;
  const int B = 2, N0 = 2048;
  const float* W[24];
  for (int i = 0; i < 24; ++i) W[i] = (const float*)d_in[i];

  float* ws = (float*)d_ws;
  const size_t P = (size_t)B * 64 * 3 * 2048;  // 786432
  float* bufA = ws;
  float* bufB = bufA + P;
  float* bufC = bufB + P;
  float* bufD = bufC + P;
  float* bufQ = bufD + P;
  float* G1 = bufQ + P;
  float* G2 = G1 + P;
  float* G3 = G2 + P;
  float* G4 = G3 + P;
  float* logits = G4 + P;            // B*2*2048*16 = 131072
  float* att = logits + 131072;      // 131072
  float* px = att + 131072;          // B*3*2048 = 12288
  float* py = px + 12288;
  float* dps = py + 12288;           // 4096
  float* xxb = dps + 4096;           // 4096
  float* meanX = xxb + 4096;         // 384
  float* meanY = meanX + 384;
  float* cbX = meanY + 384;          // 384
  float* cbY = cbX + 384;
  float* blkX = cbY + 384;           // 768
  float* blkY = blkX + 768;
  float* Fxb = blkY + 768;           // 192
  float* Fyb = Fxb + 192;
  int* idxA = (int*)(Fyb + 192);     // 65536
  int* idxB = idxA + 65536;
  int* sel = idxB + 65536;           // 2048

  auto knn = [&](const float* x, int D, int N, int* idx) {
    dim3 g1((N + 255) / 256, B);
    k_xx<<<g1, 256, 0, stream>>>(x, xxb, D, N);
    dim3 g2(N / 4, B);
    if (D == 192) k_knn2<192><<<g2, 256, 0, stream>>>(x, xxb, idx, N);
    else          k_knn2<3><<<g2, 256, 0, stream>>>(x, xxb, idx, N);
  };
  auto lin64 = [&](const float* Wm, int wsd, int woff, int sub, const float* X,
                   const float* bias, float* out, int N) {
    dim3 g((3 * N + 255) / 256, B, 4);
    k_lin<64><<<g, 256, 0, stream>>>(Wm, wsd, woff, sub, X, bias, out, N);
  };
  auto lin1 = [&](const float* Wm, int wsd, int woff, int sub, const float* X,
                  float* out, int N) {
    dim3 g((3 * N + 255) / 256, B, 4);
    k_lin<1><<<g, 256, 0, stream>>>(Wm, wsd, woff, sub, X, nullptr, out, N);
  };

  const float* fx = W[0];
  const float* fy = W[1];
  int N = N0;
  for (int blk = 0; blk < 2; ++blk) {
    int D = (blk == 0) ? 3 : 192;
    const float* dgw = W[blk ? 12 : 2]; const float* dgd = W[blk ? 13 : 3];
    const float* qw  = W[blk ? 14 : 4]; const float* qd  = W[blk ? 15 : 5];
    const float* kw  = W[blk ? 16 : 6]; const float* kd  = W[blk ? 17 : 7];
    const float* vw  = W[blk ? 18 : 8]; const float* vd  = W[blk ? 19 : 9];
    const float* gw  = W[blk ? 20 : 10]; const float* gd = W[blk ? 21 : 11];
    int nEl = B * 64 * N;
    dim3 gE((nEl + 255) / 256);
    dim3 gW(B * N / 4);              // wave-per-point kernels
    dim3 gK(B * N * 16 / 4);         // wave-per-edge kernels
    dim3 gS((B * 2 * N + 255) / 256);

    // ---- dgcnn fx -> bufA
    knn(fx, D, N, idxA);
    if (blk == 0) { lin1(dgw, 2, 0, 0, fx, G1, N); lin1(dgw, 2, 1, 1, fx, G2, N); }
    else { lin64(dgw, 128, 0, 0, fx, nullptr, G1, N); lin64(dgw, 128, 64, 1, fx, nullptr, G2, N); }
    lin64(dgd, 64, 0, 0, G1, nullptr, G3, N);
    lin64(dgd, 64, 0, 0, G2, nullptr, G4, N);
    k_edge2<<<gE, 256, 0, stream>>>(G1, G2, G3, G4, idxA, bufA, N);
    // ---- dgcnn fy -> bufB
    knn(fy, D, N, idxB);
    if (blk == 0) { lin1(dgw, 2, 0, 0, fy, G1, N); lin1(dgw, 2, 1, 1, fy, G2, N); }
    else { lin64(dgw, 128, 0, 0, fy, nullptr, G1, N); lin64(dgw, 128, 64, 1, fy, nullptr, G2, N); }
    lin64(dgd, 64, 0, 0, G1, nullptr, G3, N);
    lin64(dgd, 64, 0, 0, G2, nullptr, G4, N);
    k_edge2<<<gE, 256, 0, stream>>>(G1, G2, G3, G4, idxB, bufB, N);

    // ---- cross_context #1: x=bufA, y=bufB -> bufC
    knn(bufB, 192, N, idxB);
    lin64(qw, 64, 0, 0, bufA, nullptr, G1, N);
    lin64(qd, 64, 0, 0, G1, nullptr, G2, N);
    k_qfin<<<gW, 256, 0, stream>>>(G1, G2, bufQ, N);
    lin64(kw, 128, 0, 0, bufB, nullptr, G1, N);
    lin64(kw, 128, 64, 1, bufB, nullptr, G2, N);
    lin64(kd, 64, 0, 0, G1, nullptr, G3, N);
    lin64(kd, 64, 0, 0, G2, nullptr, G4, N);
    k_klog2<<<gK, 256, 0, stream>>>(bufQ, G1, G2, G3, G4, idxB, logits, N);
    k_soft<<<gS, 256, 0, stream>>>(logits, att, N);
    lin64(vw, 128, 0, 0, bufB, nullptr, G1, N);
    lin64(vw, 128, 64, 1, bufB, nullptr, G2, N);
    lin64(vd, 64, 0, 0, G1, nullptr, G3, N);
    lin64(vd, 64, 0, 0, G2, nullptr, G4, N);
    k_attout2<<<gE, 256, 0, stream>>>(bufA, G1, G2, G3, G4, att, idxB, bufC, N);

    // ---- cross_context #2: x=bufB, y=bufC -> bufD
    knn(bufC, 192, N, idxA);
    lin64(qw, 64, 0, 0, bufB, nullptr, G1, N);
    lin64(qd, 64, 0, 0, G1, nullptr, G2, N);
    k_qfin<<<gW, 256, 0, stream>>>(G1, G2, bufQ, N);
    lin64(kw, 128, 0, 0, bufC, nullptr, G1, N);
    lin64(kw, 128, 64, 1, bufC, nullptr, G2, N);
    lin64(kd, 64, 0, 0, G1, nullptr, G3, N);
    lin64(kd, 64, 0, 0, G2, nullptr, G4, N);
    k_klog2<<<gK, 256, 0, stream>>>(bufQ, G1, G2, G3, G4, idxA, logits, N);
    k_soft<<<gS, 256, 0, stream>>>(logits, att, N);
    lin64(vw, 128, 0, 0, bufC, nullptr, G1, N);
    lin64(vw, 128, 64, 1, bufC, nullptr, G2, N);
    lin64(vd, 64, 0, 0, G1, nullptr, G3, N);
    lin64(vd, 64, 0, 0, G2, nullptr, G4, N);
    k_attout2<<<gE, 256, 0, stream>>>(bufB, G1, G2, G3, G4, att, idxA, bufD, N);

    // ---- global fuse
    k_cmean2<<<dim3(192, B, 2), 256, 0, stream>>>(bufC, bufD, meanX, meanY, N, 192, 0, 1.f / (float)N);
    k_gbias2<<<dim3(B, 2), 192, 0, stream>>>(gw, meanX, meanY, cbX, cbY);
    lin64(gw, 128, 0, 0, bufC, cbX, G1, N);
    lin64(gd, 64, 0, 0, G1, nullptr, G2, N);
    k_gfin<<<gE, 256, 0, stream>>>(G1, G2, bufA, N);
    lin64(gw, 128, 0, 0, bufD, cbY, G1, N);
    lin64(gd, 64, 0, 0, G1, nullptr, G2, N);
    k_gfin<<<gE, 256, 0, stream>>>(G1, G2, bufB, N);

    // ---- score + top-half selection
    int Nh = N / 2;
    k_parmean<<<dim3((B * 3 * N + 255) / 256), 256, 0, stream>>>(bufA, bufB, px, py, N, B);
    k_dotphi<<<dim3((B * N + 255) / 256), 256, 0, stream>>>(bufA, bufB, px, py, dps, N, B);
    k_topsel<<<dim3(B), 1024, 0, stream>>>(dps, sel, N, Nh);
    k_gather<<<dim3((B * 192 * Nh + 255) / 256), 256, 0, stream>>>(bufA, bufB, sel, bufC, bufD, N, Nh, B);
    k_cmean2<<<dim3(192, B, 2), 256, 0, stream>>>(bufC, bufD, blkX, blkY, Nh, 384, blk * 192, 1.f / (float)Nh);
    fx = bufC; fy = bufD;
    N = Nh;
  }
  k_head<<<dim3(2, B), 96, 0, stream>>>(blkX, blkY, W[22], W[23], Fxb, Fyb);
  k_svd<<<dim3(B), 64, 0, stream>>>(Fxb, Fyb, (float*)d_out, B);
}

// Round 6
// 2127.360 us; speedup vs baseline: 3.5035x; 1.2344x over previous
//
#include <hip/hip_runtime.h>
#include <math.h>

#define SLOPE 0.2f
#define EPSV 1e-12f
#define NEGINF (-3.0e38f)

static __device__ __forceinline__ float lrelu_combine(float xv, float dvv, float dot, float dsq) {
  float xneg = xv - dot / (dsq + EPSV) * dvv;
  float w = (dot >= 0.f) ? xv : xneg;
  return SLOPE * xv + (1.f - SLOPE) * w;
}

// ---------------- squared norms per point ----------------
__global__ void k_xx(const float* __restrict__ x, float* __restrict__ xx, int D, int N) {
  int b = blockIdx.y;
  int m = blockIdx.x * 256 + threadIdx.x;
  if (m >= N) return;
  const float* xp = x + (size_t)b * D * N + m;
  float s = 0.f;
  for (int d = 0; d < D; ++d) { float v = xp[(size_t)d * N]; s = fmaf(v, v, s); }
  xx[b * N + m] = s;
}

// ---------------- knn top-16, 4 queries per block (exact lax.top_k order & ties) ----------------
template <int D>
__global__ void __launch_bounds__(256) k_knn2(const float* __restrict__ x,
                                              const float* __restrict__ xx,
                                              int* __restrict__ idx, int N) {
  __shared__ float qt[D * 4];        // qt[d*4+qi]
  __shared__ float dist[4][2048];
  __shared__ float xxq[4];
  int b = blockIdx.y, tid = threadIdx.x;
  int q0 = blockIdx.x * 4;
  const float* xb = x + (size_t)b * D * N;
  for (int i = tid; i < D * 4; i += 256) qt[i] = xb[(size_t)(i >> 2) * N + q0 + (i & 3)];
  if (tid < 4) xxq[tid] = xx[b * N + q0 + tid];
  __syncthreads();
  int kmax = N >> 8;
  for (int k = 0; k < kmax; ++k) {
    int m = tid + 256 * k;
    float a0 = 0.f, a1 = 0.f, a2 = 0.f, a3 = 0.f;
#pragma unroll 8
    for (int d = 0; d < D; ++d) {
      float xv = xb[(size_t)d * N + m];
      const float4 q4 = *(const float4*)&qt[d * 4];
      a0 = fmaf(q4.x, xv, a0);
      a1 = fmaf(q4.y, xv, a1);
      a2 = fmaf(q4.z, xv, a2);
      a3 = fmaf(q4.w, xv, a3);
    }
    float xxm = xx[b * N + m];
    dist[0][m] = 2.f * a0 - xxq[0] - xxm;
    dist[1][m] = 2.f * a1 - xxq[1] - xxm;
    dist[2][m] = 2.f * a2 - xxq[2] - xxm;
    dist[3][m] = 2.f * a3 - xxq[3] - xxm;
  }
  __syncthreads();
  int g = tid >> 6, lane = tid & 63;
  float* dr = dist[g];
  int n = q0 + g;
  int imax = N >> 8;
  int* op = idx + ((size_t)b * N + n) * 16;
  for (int r = 0; r < 16; ++r) {
    float bv = NEGINF;
    int bi = N;
    for (int i = 0; i < imax; ++i) {
      int mb = i * 256 + lane * 4;
      float4 v = *(const float4*)&dr[mb];
      if (v.x > bv) { bv = v.x; bi = mb; }
      if (v.y > bv) { bv = v.y; bi = mb + 1; }
      if (v.z > bv) { bv = v.z; bi = mb + 2; }
      if (v.w > bv) { bv = v.w; bi = mb + 3; }
    }
#pragma unroll
    for (int s = 1; s < 64; s <<= 1) {
      float ov = __shfl_xor(bv, s, 64);
      int oi = __shfl_xor(bi, s, 64);
      if (ov > bv || (ov == bv && oi < bi)) { bv = ov; bi = oi; }
    }
    if (lane == 0) { op[r] = bi; dr[bi] = NEGINF; }
  }
}

// ---------------- generic 64-out linear, dual-layout output ----------------
// cm: out[b][o][d][n] (coalesced along n). pm: out_pm[((b*N+n)*3+d)*64+o] (16 consecutive per thread).
// Wl[o][k] = W[o*ws + woff + k] - (sub ? W[o*ws + k] : 0). Accumulation ascending k (bit-stable).
template <int KT>
__global__ void __launch_bounds__(256) k_lin(const float* __restrict__ W, int ws, int woff, int sub,
                                             const float* __restrict__ X,
                                             const float* __restrict__ bias,
                                             float* __restrict__ out, float* __restrict__ out_pm,
                                             int N) {
  __shared__ float wl[64 * ((KT + 3) & ~3)];
  const int KP = (KT + 3) & ~3;
  int tid = threadIdx.x;
  for (int i = tid; i < 64 * KT; i += 256) {
    int o = i / KT, k = i - o * KT;
    float v = W[o * ws + woff + k];
    if (sub) v -= W[o * ws + k];
    wl[o * KP + k] = v;
  }
  __syncthreads();
  int b = blockIdx.y;
  int oc = blockIdx.z * 16;
  int j = blockIdx.x * 256 + tid;  // column in [0, 3N)
  int M3 = 3 * N;
  if (j >= M3) return;
  const float* Xb = X + (size_t)b * KT * M3;
  float xv[KT];
#pragma unroll
  for (int k = 0; k < KT; ++k) xv[k] = Xb[(size_t)k * M3 + j];
  int d = j / N;
  float acc[16];
  if (bias) {
#pragma unroll
    for (int oo = 0; oo < 16; ++oo) acc[oo] = bias[b * 192 + (oc + oo) * 3 + d];
  } else {
#pragma unroll
    for (int oo = 0; oo < 16; ++oo) acc[oo] = 0.f;
  }
#pragma unroll
  for (int oo = 0; oo < 16; ++oo) {
    const float* wr = &wl[(oc + oo) * KP];
    float s = acc[oo];
#pragma unroll
    for (int k = 0; k < KT; ++k) s = fmaf(wr[k], xv[k], s);
    acc[oo] = s;
  }
  if (out) {
    float* ob = out + (size_t)b * 64 * M3;
#pragma unroll
    for (int oo = 0; oo < 16; ++oo) ob[(size_t)(oc + oo) * M3 + j] = acc[oo];
  }
  if (out_pm) {
    int n = j - d * N;
    float4* pp = (float4*)(out_pm + ((size_t)((b * N + n) * 3 + d)) * 64 + oc);
    pp[0] = make_float4(acc[0], acc[1], acc[2], acc[3]);
    pp[1] = make_float4(acc[4], acc[5], acc[6], acc[7]);
    pp[2] = make_float4(acc[8], acc[9], acc[10], acc[11]);
    pp[3] = make_float4(acc[12], acc[13], acc[14], acc[15]);
  }
}

// ---------------- edge conv, wave per point, lane = channel (pm inputs, cm output) ----------------
__global__ void __launch_bounds__(256) k_edge2(const float* __restrict__ P1, const float* __restrict__ P2,
                                               const float* __restrict__ D1, const float* __restrict__ D2,
                                               const int* __restrict__ idx,
                                               float* __restrict__ out, int N) {
  int tid = threadIdx.x;
  int p = blockIdx.x * 4 + (tid >> 6);
  int c = tid & 63;
  int b = p / N, n = p - b * N;
  size_t bn = ((size_t)(b * N + n) * 3) * 64 + c;
  float p2[3], d2[3];
#pragma unroll
  for (int d = 0; d < 3; ++d) { p2[d] = P2[bn + d * 64]; d2[d] = D2[bn + d * 64]; }
  const int* ip = idx + ((size_t)b * N + n) * 16;
  float acc0 = 0.f, acc1 = 0.f, acc2 = 0.f;
  for (int j = 0; j < 16; ++j) {
    int m = ip[j];
    size_t bm = ((size_t)(b * N + m) * 3) * 64 + c;
    float xl[3], dv[3];
#pragma unroll
    for (int d = 0; d < 3; ++d) {
      xl[d] = P1[bm + d * 64] + p2[d];
      dv[d] = D1[bm + d * 64] + d2[d];
    }
    float dot = xl[0] * dv[0] + xl[1] * dv[1] + xl[2] * dv[2];
    float dsq = dv[0] * dv[0] + dv[1] * dv[1] + dv[2] * dv[2];
    acc0 += lrelu_combine(xl[0], dv[0], dot, dsq);
    acc1 += lrelu_combine(xl[1], dv[1], dot, dsq);
    acc2 += lrelu_combine(xl[2], dv[2], dot, dsq);
  }
  size_t r0 = (size_t)((b * 64 + c) * 3) * N;
  out[r0 + n] = acc0 * (1.f / 16.f);
  out[r0 + N + n] = acc1 * (1.f / 16.f);
  out[r0 + 2 * (size_t)N + n] = acc2 * (1.f / 16.f);
}

// ---------------- Qx finisher: lrelu + chnorm (pm in, pm out) ----------------
__global__ void __launch_bounds__(256) k_qfin(const float* __restrict__ XL, const float* __restrict__ DV,
                                              float* __restrict__ outpm, int N) {
  int tid = threadIdx.x;
  int p = blockIdx.x * 4 + (tid >> 6);
  int c = tid & 63;
  int b = p / N, n = p - b * N;
  size_t bn = ((size_t)(b * N + n) * 3) * 64 + c;
  float xl[3], dv[3];
#pragma unroll
  for (int d = 0; d < 3; ++d) { xl[d] = XL[bn + d * 64]; dv[d] = DV[bn + d * 64]; }
  float dot = xl[0] * dv[0] + xl[1] * dv[1] + xl[2] * dv[2];
  float dsq = dv[0] * dv[0] + dv[1] * dv[1] + dv[2] * dv[2];
  float z[3];
#pragma unroll
  for (int d = 0; d < 3; ++d) z[d] = lrelu_combine(xl[d], dv[d], dot, dsq);
  float n2 = z[0] * z[0] + z[1] * z[1] + z[2] * z[2];
  float cn2 = n2;
#pragma unroll
  for (int s = 1; s < 64; s <<= 1) cn2 += __shfl_xor(cn2, s, 64);
  float n_o = sqrtf(n2), cn = sqrtf(cn2);
  float scl = (n_o / fmaxf(cn, EPSV)) / fmaxf(n_o, EPSV);
#pragma unroll
  for (int d = 0; d < 3; ++d) outpm[bn + d * 64] = z[d] * scl;
}

// ---------------- K path: wave per point, loop 16 edges -> logits (pm inputs) ----------------
__global__ void __launch_bounds__(256) k_klog2(const float* __restrict__ qxpm,
                                               const float* __restrict__ P1, const float* __restrict__ P2,
                                               const float* __restrict__ D1, const float* __restrict__ D2,
                                               const int* __restrict__ idx,
                                               float* __restrict__ logits, int N) {
  int tid = threadIdx.x;
  int p = blockIdx.x * 4 + (tid >> 6);
  int c = tid & 63;
  int b = p / N, n = p - b * N;
  size_t bn = ((size_t)(b * N + n) * 3) * 64 + c;
  float qv[3], p2[3], d2[3];
#pragma unroll
  for (int d = 0; d < 3; ++d) {
    qv[d] = qxpm[bn + d * 64];
    p2[d] = P2[bn + d * 64];
    d2[d] = D2[bn + d * 64];
  }
  const int* ip = idx + ((size_t)b * N + n) * 16;
  int h = c >> 5;
  for (int j = 0; j < 16; ++j) {
    int m = ip[j];
    size_t bm = ((size_t)(b * N + m) * 3) * 64 + c;
    float xl[3], dv[3];
#pragma unroll
    for (int d = 0; d < 3; ++d) {
      xl[d] = P1[bm + d * 64] + p2[d];
      dv[d] = D1[bm + d * 64] + d2[d];
    }
    float dot = xl[0] * dv[0] + xl[1] * dv[1] + xl[2] * dv[2];
    float dsq = dv[0] * dv[0] + dv[1] * dv[1] + dv[2] * dv[2];
    float z[3];
#pragma unroll
    for (int d = 0; d < 3; ++d) z[d] = lrelu_combine(xl[d], dv[d], dot, dsq);
    float n2 = z[0] * z[0] + z[1] * z[1] + z[2] * z[2];
    float cn2 = n2;
#pragma unroll
    for (int s = 1; s < 64; s <<= 1) cn2 += __shfl_xor(cn2, s, 64);
    float n_o = sqrtf(n2), cn = sqrtf(cn2);
    float scl = (n_o / fmaxf(cn, EPSV)) / fmaxf(n_o, EPSV);
    float part = (z[0] * qv[0] + z[1] * qv[1] + z[2] * qv[2]) * scl;
#pragma unroll
    for (int s = 1; s < 32; s <<= 1) part += __shfl_xor(part, s, 32);
    if ((c & 31) == 0)
      logits[(((size_t)b * 2 + h) * N + n) * 16 + j] = part * 0.102062072615966f; // 1/sqrt(96)
  }
}

// ---------------- softmax over 16 neighbors ----------------
__global__ void k_soft(const float* __restrict__ logits, float* __restrict__ att, int N) {
  int gi = blockIdx.x * 256 + threadIdx.x;
  if (gi >= 2 * 2 * N) return;
  const float* lp = logits + (size_t)gi * 16;
  float* ap = att + (size_t)gi * 16;
  float mx = lp[0];
  for (int j = 1; j < 16; ++j) mx = fmaxf(mx, lp[j]);
  float e[16]; float sum = 0.f;
  for (int j = 0; j < 16; ++j) { e[j] = expf(lp[j] - mx); sum += e[j]; }
  float inv = 1.f / sum;
  for (int j = 0; j < 16; ++j) ap[j] = e[j] * inv;
}

// ---------------- V path + attention + residual: wave per point (pm inputs, cm output) ----------------
__global__ void __launch_bounds__(256) k_attout2(const float* __restrict__ xres,
                                                 const float* __restrict__ P1, const float* __restrict__ P2,
                                                 const float* __restrict__ D1, const float* __restrict__ D2,
                                                 const float* __restrict__ att,
                                                 const int* __restrict__ idx,
                                                 float* __restrict__ out, int N) {
  int tid = threadIdx.x;
  int p = blockIdx.x * 4 + (tid >> 6);
  int c = tid & 63;
  int b = p / N, n = p - b * N;
  int h = c >> 5;
  size_t bn = ((size_t)(b * N + n) * 3) * 64 + c;
  float p2[3], d2[3];
#pragma unroll
  for (int d = 0; d < 3; ++d) { p2[d] = P2[bn + d * 64]; d2[d] = D2[bn + d * 64]; }
  const int* ip = idx + ((size_t)b * N + n) * 16;
  const float* ap = att + (((size_t)b * 2 + h) * N + n) * 16;
  float acc0 = 0.f, acc1 = 0.f, acc2 = 0.f;
  for (int j = 0; j < 16; ++j) {
    int m = ip[j];
    float av = ap[j];
    size_t bm = ((size_t)(b * N + m) * 3) * 64 + c;
    float xl[3], dv[3];
#pragma unroll
    for (int d = 0; d < 3; ++d) {
      xl[d] = P1[bm + d * 64] + p2[d];
      dv[d] = D1[bm + d * 64] + d2[d];
    }
    float dot = xl[0] * dv[0] + xl[1] * dv[1] + xl[2] * dv[2];
    float dsq = dv[0] * dv[0] + dv[1] * dv[1] + dv[2] * dv[2];
    acc0 = fmaf(av, lrelu_combine(xl[0], dv[0], dot, dsq), acc0);
    acc1 = fmaf(av, lrelu_combine(xl[1], dv[1], dot, dsq), acc1);
    acc2 = fmaf(av, lrelu_combine(xl[2], dv[2], dot, dsq), acc2);
  }
  size_t r0 = (size_t)((b * 64 + c) * 3) * N;
  out[r0 + n] = xres[r0 + n] + acc0;
  out[r0 + N + n] = xres[r0 + N + n] + acc1;
  out[r0 + 2 * (size_t)N + n] = xres[r0 + 2 * (size_t)N + n] + acc2;
}

// ---------------- g-fuse finisher: wave per point (pm in, cm+pm out) ----------------
__global__ void __launch_bounds__(256) k_gfin(const float* __restrict__ XL, const float* __restrict__ DV,
                                              float* __restrict__ out, float* __restrict__ outpm, int N) {
  int tid = threadIdx.x;
  int p = blockIdx.x * 4 + (tid >> 6);
  int c = tid & 63;
  int b = p / N, n = p - b * N;
  size_t bn = ((size_t)(b * N + n) * 3) * 64 + c;
  float xl[3], dv[3];
#pragma unroll
  for (int d = 0; d < 3; ++d) { xl[d] = XL[bn + d * 64]; dv[d] = DV[bn + d * 64]; }
  float dot = xl[0] * dv[0] + xl[1] * dv[1] + xl[2] * dv[2];
  float dsq = dv[0] * dv[0] + dv[1] * dv[1] + dv[2] * dv[2];
  size_t r0 = (size_t)((b * 64 + c) * 3) * N;
#pragma unroll
  for (int d = 0; d < 3; ++d) {
    float z = lrelu_combine(xl[d], dv[d], dot, dsq);
    out[r0 + (size_t)d * N + n] = z;
    outpm[bn + d * 64] = z;
  }
}

// ---------------- bias for g-fuse, both sides in one launch ----------------
__global__ void k_gbias2(const float* __restrict__ gw, const float* __restrict__ meanX,
                         const float* __restrict__ meanY,
                         float* __restrict__ cbX, float* __restrict__ cbY) {
  int b = blockIdx.x, which = blockIdx.y, tid = threadIdx.x;  // 192 threads
  int o = tid / 3, d = tid - o * 3;
  const float* mb = (which ? meanY : meanX) + b * 192;
  float* cb = (which ? cbY : cbX);
  float s = 0.f;
  for (int c = 0; c < 64; ++c) s = fmaf(gw[o * 128 + 64 + c], mb[c * 3 + d], s);
  cb[b * 192 + tid] = s;
}

// ---------------- column mean over N for both arrays in one launch ----------------
__global__ void k_cmean2(const float* __restrict__ x1, const float* __restrict__ x2,
                         float* __restrict__ o1, float* __restrict__ o2,
                         int N, int ostride, int obase, float inv) {
  __shared__ float red[256];
  int b = blockIdx.y, cd = blockIdx.x, which = blockIdx.z, tid = threadIdx.x;
  const float* x = which ? x2 : x1;
  float* out = which ? o2 : o1;
  const float* p = x + ((size_t)b * 192 + cd) * N;
  float s = 0.f;
  for (int i = tid; i < N; i += 256) s += p[i];
  red[tid] = s;
  __syncthreads();
  for (int st = 128; st > 0; st >>= 1) {
    if (tid < st) red[tid] += red[tid + st];
    __syncthreads();
  }
  if (tid == 0) out[(size_t)b * ostride + obase + cd] = red[0] * inv;
}

// ---------------- channel-mean (fx_par pre-normalization) for both arrays ----------------
__global__ void k_parmean(const float* __restrict__ fx, const float* __restrict__ fy,
                          float* __restrict__ px, float* __restrict__ py, int N, int B) {
  int gi = blockIdx.x * 256 + threadIdx.x;
  int total = B * 3 * N;
  if (gi >= total) return;
  int b = gi / (3 * N);
  int r = gi - b * 3 * N;
  const float* fxb = fx + (size_t)b * 192 * N + r;
  const float* fyb = fy + (size_t)b * 192 * N + r;
  float sx = 0.f, sy = 0.f;
  for (int c = 0; c < 64; ++c) { sx += fxb[(size_t)c * 3 * N]; sy += fyb[(size_t)c * 3 * N]; }
  px[gi] = sx * (1.f / 64.f);
  py[gi] = sy * (1.f / 64.f);
}

// ---------------- score logits: sum_c (fx.px)(fy.py) (softmax+norm skipped: monotone) ----------------
__global__ void k_dotphi(const float* __restrict__ fx, const float* __restrict__ fy,
                         const float* __restrict__ px, const float* __restrict__ py,
                         float* __restrict__ dps, int N, int B) {
  int gi = blockIdx.x * 256 + threadIdx.x;
  if (gi >= B * N) return;
  int b = gi / N, n = gi - b * N;
  const float* fxb = fx + (size_t)b * 192 * N + n;
  const float* fyb = fy + (size_t)b * 192 * N + n;
  const float* pxb = px + (size_t)b * 3 * N + n;
  const float* pyb = py + (size_t)b * 3 * N + n;
  float acc = 0.f;
  for (int c = 0; c < 64; ++c) {
    float ax = 0.f, ay = 0.f;
    for (int d = 0; d < 3; ++d) {
      ax = fmaf(fxb[(size_t)(c * 3 + d) * N], pxb[(size_t)d * N], ax);
      ay = fmaf(fyb[(size_t)(c * 3 + d) * N], pyb[(size_t)d * N], ay);
    }
    acc = fmaf(ax, ay, acc);
  }
  dps[gi] = acc;
}

// ---------------- top-N/2 selection: bitonic sort (desc value, asc index) ----------------
__global__ void __launch_bounds__(1024) k_topsel(const float* __restrict__ dps,
                                                 int* __restrict__ sel, int N, int Nh) {
  __shared__ float kv[2048];
  __shared__ int ki[2048];
  int b = blockIdx.x, tid = threadIdx.x;
  for (int i = tid; i < N; i += 1024) { kv[i] = dps[b * N + i]; ki[i] = i; }
  __syncthreads();
  for (int kk = 2; kk <= N; kk <<= 1) {
    for (int jj = kk >> 1; jj > 0; jj >>= 1) {
      for (int i = tid; i < N; i += 1024) {
        int ixj = i ^ jj;
        if (ixj > i) {
          float va = kv[i], vb = kv[ixj];
          int ia = ki[i], ib = ki[ixj];
          bool aFirst = (va > vb) || (va == vb && ia < ib);
          bool up = ((i & kk) == 0);
          bool doswap = up ? (!aFirst) : aFirst;
          if (doswap) { kv[i] = vb; kv[ixj] = va; ki[i] = ib; ki[ixj] = ia; }
        }
      }
      __syncthreads();
    }
  }
  for (int i = tid; i < Nh; i += 1024) sel[b * Nh + i] = ki[i];
}

// ---------------- gather selected points (pm source, cm dest), wave per point ----------------
__global__ void __launch_bounds__(256) k_gather(const float* __restrict__ sxpm, const float* __restrict__ sypm,
                                                const int* __restrict__ sel,
                                                float* __restrict__ dx, float* __restrict__ dy,
                                                int N, int Nh) {
  int tid = threadIdx.x;
  int p = blockIdx.x * 4 + (tid >> 6);
  int c = tid & 63;
  int b = p / Nh, i = p - b * Nh;
  int s = sel[b * Nh + i];
  size_t bs = ((size_t)(b * N + s) * 3) * 64 + c;
  size_t r0 = (size_t)((b * 64 + c) * 3) * Nh;
#pragma unroll
  for (int d = 0; d < 3; ++d) {
    dx[r0 + (size_t)d * Nh + i] = sxpm[bs + d * 64];
    dy[r0 + (size_t)d * Nh + i] = sypm[bs + d * 64];
  }
}

// ---------------- final head: vn_lin_lrelu(concat blocks, h_w, h_d) ----------------
__global__ void k_head(const float* __restrict__ blkX, const float* __restrict__ blkY,
                       const float* __restrict__ hw, const float* __restrict__ hd,
                       float* __restrict__ Fx, float* __restrict__ Fy) {
  __shared__ float f[3][128];
  __shared__ float xl[3][32];
  __shared__ float dv[3][32];
  int which = blockIdx.x, b = blockIdx.y, tid = threadIdx.x;
  const float* blk = which ? blkY : blkX;
  float* F = which ? Fy : Fx;
  int o = tid & 31, dd = tid >> 5;
  for (int i = tid; i < 384; i += 96) f[i % 3][i / 3] = blk[(size_t)b * 384 + i];
  __syncthreads();
  float s = 0.f;
  for (int c = 0; c < 128; ++c) s = fmaf(hw[o * 128 + c], f[dd][c], s);
  xl[dd][o] = s;
  __syncthreads();
  float s2 = 0.f;
  for (int p = 0; p < 32; ++p) s2 = fmaf(hd[o * 32 + p], xl[dd][p], s2);
  dv[dd][o] = s2;
  __syncthreads();
  float dot = xl[0][o] * dv[0][o] + xl[1][o] * dv[1][o] + xl[2][o] * dv[2][o];
  float dsq = dv[0][o] * dv[0][o] + dv[1][o] * dv[1][o] + dv[2][o] * dv[2][o];
  F[((size_t)b * 32 + o) * 3 + dd] = lrelu_combine(xl[dd][o], dv[dd][o], dot, dsq);
}

// ================== LAPACK-faithful 3x3 SVD (dgesdd path: dgebrd + dbdsqr) ==================
#define DEPS 2.220446049250313e-16
#define DUNFL 2.2250738585072014e-308

static __device__ void dlartg_(double f, double g, double* cs, double* sn, double* r) {
  if (g == 0.0) { *cs = 1.0; *sn = 0.0; *r = f; }
  else if (f == 0.0) { *cs = 0.0; *sn = copysign(1.0, g); *r = fabs(g); }
  else {
    double d = sqrt(f * f + g * g);
    double c = fabs(f) / d;
    double rr = copysign(d, f);
    *cs = c; *r = rr; *sn = g / rr;
  }
}

static __device__ void dlas2_(double f, double g, double h, double* ssmin, double* ssmax) {
  double fa = fabs(f), ga = fabs(g), ha = fabs(h);
  double fhmn = fmin(fa, ha), fhmx = fmax(fa, ha);
  if (fhmn == 0.0) {
    *ssmin = 0.0;
    if (fhmx == 0.0) *ssmax = ga;
    else { double mx = fmax(fhmx, ga), mn = fmin(fhmx, ga); double q = mn / mx; *ssmax = mx * sqrt(1.0 + q * q); }
  } else {
    if (ga < fhmx) {
      double as_ = 1.0 + fhmn / fhmx;
      double at = (fhmx - fhmn) / fhmx;
      double au = ga / fhmx; au = au * au;
      double c = 2.0 / (sqrt(as_ * as_ + au) + sqrt(at * at + au));
      *ssmin = fhmn * c; *ssmax = fhmx / c;
    } else {
      double au = fhmx / ga;
      if (au == 0.0) { *ssmin = (fhmn * fhmx) / ga; *ssmax = ga; }
      else {
        double as_ = 1.0 + fhmn / fhmx;
        double at = (fhmx - fhmn) / fhmx;
        double t1 = as_ * au, t2 = at * au;
        double c = 1.0 / (sqrt(1.0 + t1 * t1) + sqrt(1.0 + t2 * t2));
        double sm = (fhmn * c) * au; *ssmin = sm + sm;
        *ssmax = ga / (c + c);
      }
    }
  }
}

static __device__ void dlasv2_(double f, double g, double h,
                               double* ssmin, double* ssmax,
                               double* snr, double* csr, double* snl, double* csl) {
  double ft = f, fa = fabs(f), ht = h, ha = fabs(h);
  int pmax = 1;
  bool swp = (ha > fa);
  if (swp) { pmax = 3; double t = ft; ft = ht; ht = t; t = fa; fa = ha; ha = t; }
  double gt = g, ga = fabs(g);
  double clt = 0, crt = 0, slt = 0, srt = 0;
  if (ga == 0.0) {
    *ssmin = ha; *ssmax = fa; clt = 1.0; crt = 1.0; slt = 0.0; srt = 0.0;
  } else {
    bool gasmal = true;
    if (ga > fa) {
      pmax = 2;
      if ((fa / ga) < DEPS) {
        gasmal = false;
        *ssmax = ga;
        *ssmin = (ha > 1.0) ? (fa / (ga / ha)) : ((fa / ga) * ha);
        clt = 1.0; slt = ht / gt; srt = 1.0; crt = ft / gt;
      }
    }
    if (gasmal) {
      double dd = fa - ha;
      double l = (dd == fa) ? 1.0 : (dd / fa);
      double mq = gt / ft;
      double t = 2.0 - l;
      double mm = mq * mq, tt = t * t;
      double s = sqrt(tt + mm);
      double r = (l == 0.0) ? fabs(mq) : sqrt(l * l + mm);
      double a = 0.5 * (s + r);
      *ssmin = ha / a;
      *ssmax = fa * a;
      if (mm == 0.0) {
        if (l == 0.0) t = copysign(2.0, ft) * copysign(1.0, gt);
        else t = gt / copysign(dd, ft) + mq / t;
      } else {
        t = (mq / (s + t) + mq / (r + l)) * (1.0 + a);
      }
      double l2 = sqrt(t * t + 4.0);
      crt = 2.0 / l2;
      srt = t / l2;
      clt = (crt + srt * mq) / a;
      slt = (ht / ft) * srt / a;
    }
  }
  if (swp) { *csl = srt; *snl = crt; *csr = slt; *snr = clt; }
  else { *csl = clt; *snl = slt; *csr = crt; *snr = srt; }
  double tsign = 0.0;
  if (pmax == 1) tsign = copysign(1.0, *csr) * copysign(1.0, *csl) * copysign(1.0, f);
  if (pmax == 2) tsign = copysign(1.0, *snr) * copysign(1.0, *csl) * copysign(1.0, g);
  if (pmax == 3) tsign = copysign(1.0, *snr) * copysign(1.0, *snl) * copysign(1.0, h);
  *ssmax = copysign(*ssmax, tsign);
  *ssmin = copysign(*ssmin, tsign * copysign(1.0, f) * copysign(1.0, h));
}

static __device__ void dbdsqr3(double d[3], double e[2], double VT[3][3], double U[3][3]) {
  const int n = 3;
  double tolmul = fmax(10.0, fmin(100.0, pow(DEPS, -0.125)));
  double tol = tolmul * DEPS;
  double thresh;
  {
    double sminoa = fabs(d[0]);
    if (sminoa != 0.0) {
      double mu = sminoa;
      for (int i = 1; i < n; ++i) {
        mu = fabs(d[i]) * (mu / (mu + fabs(e[i - 1])));
        sminoa = fmin(sminoa, mu);
        if (sminoa == 0.0) break;
      }
    }
    sminoa = sminoa / sqrt((double)n);
    thresh = fmax(tol * sminoa, 6.0 * n * n * DUNFL);
  }
  int maxit = 6 * n * n;
  int iter = 0, oldll = -1, oldm = -1, idir = 0;
  int m = n;
  double sminl = 0.0;
  int guard = 0;
  while (true) {
    if (m <= 1) break;
    if (iter > maxit) break;
    if (++guard > 500) break;
    double smaxb = fabs(d[m - 1]);
    int ll = 0; bool found = false;
    for (int lll = 1; lll <= m - 1; ++lll) {
      int l = m - lll;
      double abss = fabs(d[l - 1]);
      double abse = fabs(e[l - 1]);
      if (abse <= thresh) { ll = l; found = true; break; }
      smaxb = fmax(smaxb, fmax(abss, abse));
    }
    if (found) {
      e[ll - 1] = 0.0;
      if (ll == m - 1) { m = m - 1; continue; }
      ll = ll + 1;
    } else ll = 1;
    if (ll == m - 1) {
      double sigmn, sigmx, sinr, cosr, sinl2, cosl2;
      dlasv2_(d[m - 2], e[m - 2], d[m - 1], &sigmn, &sigmx, &sinr, &cosr, &sinl2, &cosl2);
      d[m - 2] = sigmx; d[m - 1] = sigmn; e[m - 2] = 0.0;
      for (int j = 0; j < 3; ++j) {
        double t1 = VT[m - 2][j], t2 = VT[m - 1][j];
        VT[m - 2][j] = cosr * t1 + sinr * t2;
        VT[m - 1][j] = cosr * t2 - sinr * t1;
      }
      for (int i2 = 0; i2 < 3; ++i2) {
        double t1 = U[i2][m - 2], t2 = U[i2][m - 1];
        U[i2][m - 2] = cosl2 * t1 + sinl2 * t2;
        U[i2][m - 1] = cosl2 * t2 - sinl2 * t1;
      }
      m -= 2;
      continue;
    }
    if (ll > oldm || m < oldll)
      idir = (fabs(d[ll - 1]) >= fabs(d[m - 1])) ? 1 : 2;
    if (idir == 1) {
      if (fabs(e[m - 2]) <= tol * fabs(d[m - 1])) { e[m - 2] = 0.0; continue; }
      double mu = fabs(d[ll - 1]); sminl = mu;
      bool conv = true;
      for (int lll = ll; lll <= m - 1; ++lll) {
        if (fabs(e[lll - 1]) > tol * mu) { conv = false; break; }
        mu = fabs(d[lll]) * (mu / (mu + fabs(e[lll - 1])));
        sminl = fmin(sminl, mu);
      }
      if (conv) { e[m - 2] = 0.0; continue; }
    } else {
      if (fabs(e[ll - 1]) <= tol * fabs(d[ll - 1])) { e[ll - 1] = 0.0; continue; }
      double mu = fabs(d[m - 1]); sminl = mu;
      bool conv = true;
      for (int lll = m - 1; lll >= ll; --lll) {
        if (fabs(e[lll - 1]) > tol * mu) { conv = false; break; }
        mu = fabs(d[lll - 1]) * (mu / (mu + fabs(e[lll - 1])));
        sminl = fmin(sminl, mu);
      }
      if (conv) { e[ll - 1] = 0.0; continue; }
    }
    oldll = ll; oldm = m;
    double shift = 0.0, rr;
    if (!(n * tol * (sminl / smaxb) <= fmax(DEPS, 0.01 * tol))) {
      double sll;
      if (idir == 1) { sll = fabs(d[ll - 1]); dlas2_(d[m - 2], e[m - 2], d[m - 1], &shift, &rr); }
      else { sll = fabs(d[m - 1]); dlas2_(d[ll - 1], e[ll - 1], d[ll], &shift, &rr); }
      if (sll > 0.0) { double q = shift / sll; if (q * q < DEPS) shift = 0.0; }
    }
    iter += m - ll;
    double csv[2], snv[2], ocsv[2], osnv[2];
    int cnt = 0;
    if (shift == 0.0) {
      if (idir == 1) {
        double cs = 1.0, oldcs = 1.0, sn = 0.0, oldsn = 0.0, r;
        for (int i = ll; i <= m - 1; ++i) {
          dlartg_(d[i - 1] * cs, e[i - 1], &cs, &sn, &r);
          if (i > ll) e[i - 2] = oldsn * r;
          dlartg_(oldcs * r, d[i] * sn, &oldcs, &oldsn, &d[i - 1]);
          csv[cnt] = cs; snv[cnt] = sn; ocsv[cnt] = oldcs; osnv[cnt] = oldsn; cnt++;
        }
        double hh = d[m - 1] * cs;
        d[m - 1] = hh * oldcs;
        e[m - 2] = hh * oldsn;
        for (int k = 0; k < cnt; ++k) {
          int r0 = ll - 1 + k, r1 = r0 + 1;
          for (int j = 0; j < 3; ++j) {
            double t1 = VT[r0][j], t2 = VT[r1][j];
            VT[r0][j] = snv[k] * t2 + csv[k] * t1;
            VT[r1][j] = csv[k] * t2 - snv[k] * t1;
          }
        }
        for (int k = 0; k < cnt; ++k) {
          int c0 = ll - 1 + k, c1 = c0 + 1;
          for (int i2 = 0; i2 < 3; ++i2) {
            double t1 = U[i2][c0], t2 = U[i2][c1];
            U[i2][c0] = osnv[k] * t2 + ocsv[k] * t1;
            U[i2][c1] = ocsv[k] * t2 - osnv[k] * t1;
          }
        }
        if (fabs(e[m - 2]) <= thresh) e[m - 2] = 0.0;
      } else {
        double cs = 1.0, oldcs = 1.0, sn = 0.0, oldsn = 0.0, r;
        for (int i = m; i >= ll + 1; --i) {
          dlartg_(d[i - 1] * cs, e[i - 2], &cs, &sn, &r);
          if (i < m) e[i - 1] = oldsn * r;
          dlartg_(oldcs * r, d[i - 2] * sn, &oldcs, &oldsn, &d[i - 1]);
          int k = i - ll - 1;
          csv[k] = cs; snv[k] = -sn; ocsv[k] = oldcs; osnv[k] = -oldsn; cnt++;
        }
        double hh = d[ll - 1] * cs;
        d[ll - 1] = hh * oldcs;
        e[ll - 1] = hh * oldsn;
        for (int k = cnt - 1; k >= 0; --k) {
          int r0 = ll - 1 + k, r1 = r0 + 1;
          for (int j = 0; j < 3; ++j) {
            double t1 = VT[r0][j], t2 = VT[r1][j];
            VT[r0][j] = osnv[k] * t2 + ocsv[k] * t1;
            VT[r1][j] = ocsv[k] * t2 - osnv[k] * t1;
          }
        }
        for (int k = cnt - 1; k >= 0; --k) {
          int c0 = ll - 1 + k, c1 = c0 + 1;
          for (int i2 = 0; i2 < 3; ++i2) {
            double t1 = U[i2][c0], t2 = U[i2][c1];
            U[i2][c0] = snv[k] * t2 + csv[k] * t1;
            U[i2][c1] = csv[k] * t2 - snv[k] * t1;
          }
        }
        if (fabs(e[ll - 1]) <= thresh) e[ll - 1] = 0.0;
      }
    } else {
      if (idir == 1) {
        double f = (fabs(d[ll - 1]) - shift) * (copysign(1.0, d[ll - 1]) + shift / d[ll - 1]);
        double g = e[ll - 1];
        double cosr, sinr, cosl2, sinl2, r;
        for (int i = ll; i <= m - 1; ++i) {
          dlartg_(f, g, &cosr, &sinr, &r);
          if (i > ll) e[i - 2] = r;
          f = cosr * d[i - 1] + sinr * e[i - 1];
          e[i - 1] = cosr * e[i - 1] - sinr * d[i - 1];
          g = sinr * d[i];
          d[i] = cosr * d[i];
          dlartg_(f, g, &cosl2, &sinl2, &r);
          d[i - 1] = r;
          f = cosl2 * e[i - 1] + sinl2 * d[i];
          d[i] = cosl2 * d[i] - sinl2 * e[i - 1];
          if (i < m - 1) {
            g = sinl2 * e[i];
            e[i] = cosl2 * e[i];
          }
          csv[cnt] = cosr; snv[cnt] = sinr; ocsv[cnt] = cosl2; osnv[cnt] = sinl2; cnt++;
        }
        e[m - 2] = f;
        for (int k = 0; k < cnt; ++k) {
          int r0 = ll - 1 + k, r1 = r0 + 1;
          for (int j = 0; j < 3; ++j) {
            double t1 = VT[r0][j], t2 = VT[r1][j];
            VT[r0][j] = snv[k] * t2 + csv[k] * t1;
            VT[r1][j] = csv[k] * t2 - snv[k] * t1;
          }
        }
        for (int k = 0; k < cnt; ++k) {
          int c0 = ll - 1 + k, c1 = c0 + 1;
          for (int i2 = 0; i2 < 3; ++i2) {
            double t1 = U[i2][c0], t2 = U[i2][c1];
            U[i2][c0] = osnv[k] * t2 + ocsv[k] * t1;
            U[i2][c1] = ocsv[k] * t2 - osnv[k] * t1;
          }
        }
        if (fabs(e[m - 2]) <= thresh) e[m - 2] = 0.0;
      } else {
        double f = (fabs(d[m - 1]) - shift) * (copysign(1.0, d[m - 1]) + shift / d[m - 1]);
        double g = e[m - 2];
        for (int i = m; i >= ll + 1; --i) {
          double cosr, sinr, cosl2, sinl2, r;
          dlartg_(f, g, &cosr, &sinr, &r);
          if (i < m) e[i - 1] = r;
          f = cosr * d[i - 1] + sinr * e[i - 2];
          e[i - 2] = cosr * e[i - 2] - sinr * d[i - 1];
          g = sinr * d[i - 2];
          d[i - 2] = cosr * d[i - 2];
          dlartg_(f, g, &cosl2, &sinl2, &r);
          d[i - 1] = r;
          f = cosl2 * e[i - 2] + sinl2 * d[i - 2];
          d[i - 2] = cosl2 * d[i - 2] - sinl2 * e[i - 2];
          if (i > ll + 1) {
            g = sinl2 * e[i - 3];
            e[i - 3] = cosl2 * e[i - 3];
          }
          int k = i - ll - 1;
          ocsv[k] = cosl2; osnv[k] = -sinl2; csv[k] = cosr; snv[k] = -sinr; cnt++;
        }
        e[ll - 1] = f;
        for (int k = cnt - 1; k >= 0; --k) {
          int r0 = ll - 1 + k, r1 = r0 + 1;
          for (int j = 0; j < 3; ++j) {
            double t1 = VT[r0][j], t2 = VT[r1][j];
            VT[r0][j] = snv[k] * t2 + csv[k] * t1;
            VT[r1][j] = csv[k] * t2 - snv[k] * t1;
          }
        }
        for (int k = cnt - 1; k >= 0; --k) {
          int c0 = ll - 1 + k, c1 = c0 + 1;
          for (int i2 = 0; i2 < 3; ++i2) {
            double t1 = U[i2][c0], t2 = U[i2][c1];
            U[i2][c0] = osnv[k] * t2 + ocsv[k] * t1;
            U[i2][c1] = ocsv[k] * t2 - osnv[k] * t1;
          }
        }
        if (fabs(e[ll - 1]) <= thresh) e[ll - 1] = 0.0;
      }
    }
  }
  for (int i = 0; i < n; ++i)
    if (d[i] < 0.0) { d[i] = -d[i]; for (int j = 0; j < 3; ++j) VT[i][j] = -VT[i][j]; }
  for (int i = 1; i <= n - 1; ++i) {
    int isub = 1; double smn = d[0];
    for (int j = 2; j <= n + 1 - i; ++j)
      if (d[j - 1] <= smn) { isub = j; smn = d[j - 1]; }
    if (isub != n + 1 - i) {
      int a = isub - 1, b2 = n - i;
      double t = d[a]; d[a] = d[b2]; d[b2] = t;
      for (int j = 0; j < 3; ++j) { t = VT[a][j]; VT[a][j] = VT[b2][j]; VT[b2][j] = t; }
      for (int j = 0; j < 3; ++j) { t = U[j][a]; U[j][a] = U[j][b2]; U[j][b2] = t; }
    }
  }
}

__global__ void k_svd(const float* __restrict__ Fx, const float* __restrict__ Fy,
                      float* __restrict__ out, int B) {
  int b = blockIdx.x;
  if (threadIdx.x != 0) return;
  double A[3][3];
  for (int d = 0; d < 3; ++d)
    for (int e = 0; e < 3; ++e) {
      double s = 0.0;
      for (int c = 0; c < 32; ++c)
        s += (double)Fx[((size_t)b * 32 + c) * 3 + d] * (double)Fy[((size_t)b * 32 + c) * 3 + e];
      A[d][e] = s;
    }
  double dg[3], eg[2], tauq0, tauq1, taup0;
  double v1_1 = 0, v1_2 = 0, v2_1 = 0, w1 = 0;
  {
    double alpha = A[0][0];
    double xn = sqrt(A[1][0] * A[1][0] + A[2][0] * A[2][0]);
    if (xn == 0.0) { tauq0 = 0.0; dg[0] = alpha; }
    else {
      double beta = -copysign(sqrt(alpha * alpha + xn * xn), alpha);
      tauq0 = (beta - alpha) / beta;
      double scal = 1.0 / (alpha - beta);
      v1_1 = A[1][0] * scal; v1_2 = A[2][0] * scal;
      dg[0] = beta;
    }
    for (int j = 1; j < 3; ++j) {
      double w = A[0][j] + v1_1 * A[1][j] + v1_2 * A[2][j];
      w *= tauq0;
      A[0][j] -= w; A[1][j] -= w * v1_1; A[2][j] -= w * v1_2;
    }
  }
  {
    double alpha = A[0][1];
    double xn = fabs(A[0][2]);
    if (xn == 0.0) { taup0 = 0.0; eg[0] = alpha; }
    else {
      double beta = -copysign(sqrt(alpha * alpha + xn * xn), alpha);
      taup0 = (beta - alpha) / beta;
      w1 = A[0][2] / (alpha - beta);
      eg[0] = beta;
    }
    for (int i = 1; i < 3; ++i) {
      double t = A[i][1] + w1 * A[i][2];
      t *= taup0;
      A[i][1] -= t; A[i][2] -= t * w1;
    }
  }
  {
    double alpha = A[1][1];
    double xn = fabs(A[2][1]);
    if (xn == 0.0) { tauq1 = 0.0; dg[1] = alpha; }
    else {
      double beta = -copysign(sqrt(alpha * alpha + xn * xn), alpha);
      tauq1 = (beta - alpha) / beta;
      v2_1 = A[2][1] / (alpha - beta);
      dg[1] = beta;
    }
    double w = A[1][2] + v2_1 * A[2][2];
    w *= tauq1;
    A[1][2] -= w; A[2][2] -= w * v2_1;
  }
  eg[1] = A[1][2];
  dg[2] = A[2][2];
  double U[3][3] = {{1, 0, 0}, {0, 1, 0}, {0, 0, 1}};
  double VT[3][3] = {{1, 0, 0}, {0, 1, 0}, {0, 0, 1}};
  dbdsqr3(dg, eg, VT, U);
  for (int j = 0; j < 3; ++j) {
    double w = U[1][j] + v2_1 * U[2][j];
    w *= tauq1;
    U[1][j] -= w; U[2][j] -= w * v2_1;
  }
  for (int j = 0; j < 3; ++j) {
    double w = U[0][j] + v1_1 * U[1][j] + v1_2 * U[2][j];
    w *= tauq0;
    U[0][j] -= w; U[1][j] -= w * v1_1; U[2][j] -= w * v1_2;
  }
  for (int r = 0; r < 3; ++r) {
    double t = VT[r][1] + w1 * VT[r][2];
    t *= taup0;
    VT[r][1] -= t; VT[r][2] -= t * w1;
  }
  for (int i = 0; i < 3; ++i)
    for (int j = 0; j < 3; ++j) {
      double r = 0;
      for (int k = 0; k < 3; ++k) r += U[i][k] * VT[j][k];
      out[b * 9 + i * 3 + j] = (float)r;
    }
  for (int dd = 0; dd < 3; ++dd) {
    float sx = 0.f, sy = 0.f;
    for (int c = 0; c < 32; ++c) {
      float vx = Fx[((size_t)b * 32 + c) * 3 + dd];
      float vy = Fy[((size_t)b * 32 + c) * 3 + dd];
      sx = fmaf(vx, vx, sx);
      sy = fmaf(vy, vy, sy);
    }
    out[B * 9 + b * 3 + dd] = sqrtf(sy) / sqrtf(sx);
  }
}

extern "C" void kernel_launch(void* const* d_in, const int* in_sizes, int n_in,
                              void* d_out, int out_size, void* d_ws, size_t ws_size,
                              hipStream_t stream) {
  (void)in_sizes; (void)n_in; (void)out_size; (void)ws_size;
  const int B = 2, N0 = 2048;
  const float* W[24];
  for (int i = 0; i < 24; ++i) W[i] = (const float*)d_in[i];

  float* ws = (float*)d_ws;
  const size_t P = (size_t)B * 64 * 3 * 2048;  // 786432
  float* bufA = ws;
  float* bufB = bufA + P;
  float* bufC = bufB + P;
  float* bufD = bufC + P;
  float* G1 = bufD + P;
  float* G2 = G1 + P;
  float* G1pm = G2 + P;
  float* G2pm = G1pm + P;
  float* G3pm = G2pm + P;
  float* G4pm = G3pm + P;
  float* qxpm = G4pm + P;
  float* bufApm = qxpm + P;
  float* bufBpm = bufApm + P;
  float* logits = bufBpm + P;        // B*2*2048*16 = 131072
  float* att = logits + 131072;      // 131072
  float* px = att + 131072;          // B*3*2048 = 12288
  float* py = px + 12288;
  float* dps = py + 12288;           // 4096
  float* xxb = dps + 4096;           // 4096
  float* meanX = xxb + 4096;         // 384
  float* meanY = meanX + 384;
  float* cbX = meanY + 384;          // 384
  float* cbY = cbX + 384;
  float* blkX = cbY + 384;           // 768
  float* blkY = blkX + 768;
  float* Fxb = blkY + 768;           // 192
  float* Fyb = Fxb + 192;
  int* idxA = (int*)(Fyb + 192);     // 65536
  int* idxB = idxA + 65536;
  int* sel = idxB + 65536;           // 2048

  auto knn = [&](const float* x, int D, int N, int* idx) {
    dim3 g1((N + 255) / 256, B);
    k_xx<<<g1, 256, 0, stream>>>(x, xxb, D, N);
    dim3 g2(N / 4, B);
    if (D == 192) k_knn2<192><<<g2, 256, 0, stream>>>(x, xxb, idx, N);
    else          k_knn2<3><<<g2, 256, 0, stream>>>(x, xxb, idx, N);
  };
  auto lin64 = [&](const float* Wm, int wsd, int woff, int sub, const float* X,
                   const float* bias, float* cm, float* pm, int N) {
    dim3 g((3 * N + 255) / 256, B, 4);
    k_lin<64><<<g, 256, 0, stream>>>(Wm, wsd, woff, sub, X, bias, cm, pm, N);
  };
  auto lin1 = [&](const float* Wm, int wsd, int woff, int sub, const float* X,
                  float* cm, float* pm, int N) {
    dim3 g((3 * N + 255) / 256, B, 4);
    k_lin<1><<<g, 256, 0, stream>>>(Wm, wsd, woff, sub, X, nullptr, cm, pm, N);
  };

  const float* fx = W[0];
  const float* fy = W[1];
  int N = N0;
  for (int blk = 0; blk < 2; ++blk) {
    int D = (blk == 0) ? 3 : 192;
    const float* dgw = W[blk ? 12 : 2]; const float* dgd = W[blk ? 13 : 3];
    const float* qw  = W[blk ? 14 : 4]; const float* qd  = W[blk ? 15 : 5];
    const float* kw  = W[blk ? 16 : 6]; const float* kd  = W[blk ? 17 : 7];
    const float* vw  = W[blk ? 18 : 8]; const float* vd  = W[blk ? 19 : 9];
    const float* gw  = W[blk ? 20 : 10]; const float* gd = W[blk ? 21 : 11];
    dim3 gP(B * N / 4);              // wave-per-point kernels (4 waves/block)
    dim3 gS((B * 2 * N + 255) / 256);

    // ---- dgcnn fx -> bufA
    knn(fx, D, N, idxA);
    if (blk == 0) { lin1(dgw, 2, 0, 0, fx, G1, G1pm, N); lin1(dgw, 2, 1, 1, fx, G2, G2pm, N); }
    else { lin64(dgw, 128, 0, 0, fx, nullptr, G1, G1pm, N); lin64(dgw, 128, 64, 1, fx, nullptr, G2, G2pm, N); }
    lin64(dgd, 64, 0, 0, G1, nullptr, nullptr, G3pm, N);
    lin64(dgd, 64, 0, 0, G2, nullptr, nullptr, G4pm, N);
    k_edge2<<<gP, 256, 0, stream>>>(G1pm, G2pm, G3pm, G4pm, idxA, bufA, N);
    // ---- dgcnn fy -> bufB
    knn(fy, D, N, idxB);
    if (blk == 0) { lin1(dgw, 2, 0, 0, fy, G1, G1pm, N); lin1(dgw, 2, 1, 1, fy, G2, G2pm, N); }
    else { lin64(dgw, 128, 0, 0, fy, nullptr, G1, G1pm, N); lin64(dgw, 128, 64, 1, fy, nullptr, G2, G2pm, N); }
    lin64(dgd, 64, 0, 0, G1, nullptr, nullptr, G3pm, N);
    lin64(dgd, 64, 0, 0, G2, nullptr, nullptr, G4pm, N);
    k_edge2<<<gP, 256, 0, stream>>>(G1pm, G2pm, G3pm, G4pm, idxB, bufB, N);

    // ---- cross_context #1: x=bufA, y=bufB -> bufC
    knn(bufB, 192, N, idxB);
    lin64(qw, 64, 0, 0, bufA, nullptr, G1, G1pm, N);
    lin64(qd, 64, 0, 0, G1, nullptr, nullptr, G2pm, N);
    k_qfin<<<gP, 256, 0, stream>>>(G1pm, G2pm, qxpm, N);
    lin64(kw, 128, 0, 0, bufB, nullptr, G1, G1pm, N);
    lin64(kw, 128, 64, 1, bufB, nullptr, G2, G2pm, N);
    lin64(kd, 64, 0, 0, G1, nullptr, nullptr, G3pm, N);
    lin64(kd, 64, 0, 0, G2, nullptr, nullptr, G4pm, N);
    k_klog2<<<gP, 256, 0, stream>>>(qxpm, G1pm, G2pm, G3pm, G4pm, idxB, logits, N);
    k_soft<<<gS, 256, 0, stream>>>(logits, att, N);
    lin64(vw, 128, 0, 0, bufB, nullptr, G1, G1pm, N);
    lin64(vw, 128, 64, 1, bufB, nullptr, G2, G2pm, N);
    lin64(vd, 64, 0, 0, G1, nullptr, nullptr, G3pm, N);
    lin64(vd, 64, 0, 0, G2, nullptr, nullptr, G4pm, N);
    k_attout2<<<gP, 256, 0, stream>>>(bufA, G1pm, G2pm, G3pm, G4pm, att, idxB, bufC, N);

    // ---- cross_context #2: x=bufB, y=bufC -> bufD
    knn(bufC, 192, N, idxA);
    lin64(qw, 64, 0, 0, bufB, nullptr, G1, G1pm, N);
    lin64(qd, 64, 0, 0, G1, nullptr, nullptr, G2pm, N);
    k_qfin<<<gP, 256, 0, stream>>>(G1pm, G2pm, qxpm, N);
    lin64(kw, 128, 0, 0, bufC, nullptr, G1, G1pm, N);
    lin64(kw, 128, 64, 1, bufC, nullptr, G2, G2pm, N);
    lin64(kd, 64, 0, 0, G1, nullptr, nullptr, G3pm, N);
    lin64(kd, 64, 0, 0, G2, nullptr, nullptr, G4pm, N);
    k_klog2<<<gP, 256, 0, stream>>>(qxpm, G1pm, G2pm, G3pm, G4pm, idxA, logits, N);
    k_soft<<<gS, 256, 0, stream>>>(logits, att, N);
    lin64(vw, 128, 0, 0, bufC, nullptr, G1, G1pm, N);
    lin64(vw, 128, 64, 1, bufC, nullptr, G2, G2pm, N);
    lin64(vd, 64, 0, 0, G1, nullptr, nullptr, G3pm, N);
    lin64(vd, 64, 0, 0, G2, nullptr, nullptr, G4pm, N);
    k_attout2<<<gP, 256, 0, stream>>>(bufB, G1pm, G2pm, G3pm, G4pm, att, idxA, bufD, N);

    // ---- global fuse
    k_cmean2<<<dim3(192, B, 2), 256, 0, stream>>>(bufC, bufD, meanX, meanY, N, 192, 0, 1.f / (float)N);
    k_gbias2<<<dim3(B, 2), 192, 0, stream>>>(gw, meanX, meanY, cbX, cbY);
    lin64(gw, 128, 0, 0, bufC, cbX, G1, G1pm, N);
    lin64(gd, 64, 0, 0, G1, nullptr, nullptr, G2pm, N);
    k_gfin<<<gP, 256, 0, stream>>>(G1pm, G2pm, bufA, bufApm, N);
    lin64(gw, 128, 0, 0, bufD, cbY, G1, G1pm, N);
    lin64(gd, 64, 0, 0, G1, nullptr, nullptr, G2pm, N);
    k_gfin<<<gP, 256, 0, stream>>>(G1pm, G2pm, bufB, bufBpm, N);

    // ---- score + top-half selection
    int Nh = N / 2;
    k_parmean<<<dim3((B * 3 * N + 255) / 256), 256, 0, stream>>>(bufA, bufB, px, py, N, B);
    k_dotphi<<<dim3((B * N + 255) / 256), 256, 0, stream>>>(bufA, bufB, px, py, dps, N, B);
    k_topsel<<<dim3(B), 1024, 0, stream>>>(dps, sel, N, Nh);
    k_gather<<<dim3(B * Nh / 4), 256, 0, stream>>>(bufApm, bufBpm, sel, bufC, bufD, N, Nh);
    k_cmean2<<<dim3(192, B, 2), 256, 0, stream>>>(bufC, bufD, blkX, blkY, Nh, 384, blk * 192, 1.f / (float)Nh);
    fx = bufC; fy = bufD;
    N = Nh;
  }
  k_head<<<dim3(2, B), 96, 0, stream>>>(blkX, blkY, W[22], W[23], Fxb, Fyb);
  k_svd<<<dim3(B), 64, 0, stream>>>(Fxb, Fyb, (float*)d_out, B);
}

// Round 7
// 1380.216 us; speedup vs baseline: 5.4000x; 1.5413x over previous
//
#include <hip/hip_runtime.h>
#include <math.h>

#define SLOPE 0.2f
#define EPSV 1e-12f
#define NEGINF (-3.0e38f)

static __device__ __forceinline__ float lrelu_combine(float xv, float dvv, float dot, float dsq) {
  float xneg = xv - dot / (dsq + EPSV) * dvv;
  float w = (dot >= 0.f) ? xv : xneg;
  return SLOPE * xv + (1.f - SLOPE) * w;
}

// ---------------- squared norms per point, up to 2 inputs (side = blockIdx.z) ----------------
__global__ void k_xx2(const float* __restrict__ x0, const float* __restrict__ x1,
                      float* __restrict__ xxA, float* __restrict__ xxB, int D, int N) {
  int side = blockIdx.z;
  const float* x = side ? x1 : x0;
  float* xx = side ? xxB : xxA;
  int b = blockIdx.y;
  int m = blockIdx.x * 256 + threadIdx.x;
  if (m >= N) return;
  const float* xp = x + (size_t)b * D * N + m;
  float s = 0.f;
  for (int d = 0; d < D; ++d) { float v = xp[(size_t)d * N]; s = fmaf(v, v, s); }
  xx[b * N + m] = s;
}

// ---------------- knn top-16: 4 queries/block, 4 m-points/thread, side=blockIdx.z ----------------
// distance chain per (q,m): ascending-d fmaf, 2*dot - xxn - xxm  (bit-identical to prior rounds)
template <int D>
__global__ void __launch_bounds__(256) k_knn2(const float* __restrict__ x0, const float* __restrict__ x1,
                                              const float* __restrict__ xxA, const float* __restrict__ xxB,
                                              int* __restrict__ idx0, int* __restrict__ idx1, int N) {
  int side = blockIdx.z;
  const float* x = side ? x1 : x0;
  const float* xx = side ? xxB : xxA;
  int* idx = side ? idx1 : idx0;
  __shared__ float qt[D * 4];
  __shared__ float dist[4][2048];
  __shared__ float xxq[4];
  int b = blockIdx.y, tid = threadIdx.x;
  int q0 = blockIdx.x * 4;
  const float* xb = x + (size_t)b * D * N;
  for (int i = tid; i < D * 4; i += 256) qt[i] = xb[(size_t)(i >> 2) * N + q0 + (i & 3)];
  if (tid < 4) xxq[tid] = xx[b * N + q0 + tid];
  __syncthreads();
  int kouter = N >> 10;
  for (int k = 0; k < kouter; ++k) {
    int m0 = tid + (k << 10);
    float4 a0 = {0, 0, 0, 0}, a1 = {0, 0, 0, 0}, a2 = {0, 0, 0, 0}, a3 = {0, 0, 0, 0};
#pragma unroll 4
    for (int d = 0; d < D; ++d) {
      const float4 q4 = *(const float4*)&qt[d * 4];
      const float* xr = xb + (size_t)d * N + m0;
      float v0 = xr[0], v1 = xr[256], v2 = xr[512], v3 = xr[768];
      a0.x = fmaf(q4.x, v0, a0.x); a0.y = fmaf(q4.y, v0, a0.y);
      a0.z = fmaf(q4.z, v0, a0.z); a0.w = fmaf(q4.w, v0, a0.w);
      a1.x = fmaf(q4.x, v1, a1.x); a1.y = fmaf(q4.y, v1, a1.y);
      a1.z = fmaf(q4.z, v1, a1.z); a1.w = fmaf(q4.w, v1, a1.w);
      a2.x = fmaf(q4.x, v2, a2.x); a2.y = fmaf(q4.y, v2, a2.y);
      a2.z = fmaf(q4.z, v2, a2.z); a2.w = fmaf(q4.w, v2, a2.w);
      a3.x = fmaf(q4.x, v3, a3.x); a3.y = fmaf(q4.y, v3, a3.y);
      a3.z = fmaf(q4.z, v3, a3.z); a3.w = fmaf(q4.w, v3, a3.w);
    }
    const float* xxb2 = xx + b * N + m0;
    float x0v = xxb2[0], x1v = xxb2[256], x2v = xxb2[512], x3v = xxb2[768];
    dist[0][m0]       = 2.f * a0.x - xxq[0] - x0v;
    dist[1][m0]       = 2.f * a0.y - xxq[1] - x0v;
    dist[2][m0]       = 2.f * a0.z - xxq[2] - x0v;
    dist[3][m0]       = 2.f * a0.w - xxq[3] - x0v;
    dist[0][m0 + 256] = 2.f * a1.x - xxq[0] - x1v;
    dist[1][m0 + 256] = 2.f * a1.y - xxq[1] - x1v;
    dist[2][m0 + 256] = 2.f * a1.z - xxq[2] - x1v;
    dist[3][m0 + 256] = 2.f * a1.w - xxq[3] - x1v;
    dist[0][m0 + 512] = 2.f * a2.x - xxq[0] - x2v;
    dist[1][m0 + 512] = 2.f * a2.y - xxq[1] - x2v;
    dist[2][m0 + 512] = 2.f * a2.z - xxq[2] - x2v;
    dist[3][m0 + 512] = 2.f * a2.w - xxq[3] - x2v;
    dist[0][m0 + 768] = 2.f * a3.x - xxq[0] - x3v;
    dist[1][m0 + 768] = 2.f * a3.y - xxq[1] - x3v;
    dist[2][m0 + 768] = 2.f * a3.z - xxq[2] - x3v;
    dist[3][m0 + 768] = 2.f * a3.w - xxq[3] - x3v;
  }
  __syncthreads();
  int g = tid >> 6, lane = tid & 63;
  float* dr = dist[g];
  int n = q0 + g;
  int imax = N >> 8;
  int* op = idx + ((size_t)b * N + n) * 16;
  for (int r = 0; r < 16; ++r) {
    float bv = NEGINF;
    int bi = N;
    for (int i = 0; i < imax; ++i) {
      int mb = i * 256 + lane * 4;
      float4 v = *(const float4*)&dr[mb];
      if (v.x > bv) { bv = v.x; bi = mb; }
      if (v.y > bv) { bv = v.y; bi = mb + 1; }
      if (v.z > bv) { bv = v.z; bi = mb + 2; }
      if (v.w > bv) { bv = v.w; bi = mb + 3; }
    }
#pragma unroll
    for (int s = 1; s < 64; s <<= 1) {
      float ov = __shfl_xor(bv, s, 64);
      int oi = __shfl_xor(bi, s, 64);
      if (ov > bv || (ov == bv && oi < bi)) { bv = ov; bi = oi; }
    }
    if (lane == 0) { op[r] = bi; dr[bi] = NEGINF; }
  }
}

// ---------------- multi-slot 64-out linear (slot = blockIdx.z>>2), dual-layout output ----------------
// Per-block body identical to the proven k_lin (xv[64]+acc[16], no spill). Ascending-k chains.
struct LinSlots {
  const float* W[5]; const float* X[5]; const float* bias[5];
  float* cm[5]; float* pm[5];
  int ws[5]; int woff[5]; int sub[5];
};

template <int KT>
__global__ void __launch_bounds__(256) k_linm(LinSlots S, int N) {
  __shared__ float wl[64 * ((KT + 3) & ~3)];
  const int KP = (KT + 3) & ~3;
  int slot = blockIdx.z >> 2;
  int oc = (blockIdx.z & 3) * 16;
  const float* W = S.W[slot];
  int ws = S.ws[slot], woff = S.woff[slot], sub = S.sub[slot];
  int tid = threadIdx.x;
  for (int i = tid; i < 64 * KT; i += 256) {
    int o = i / KT, k = i - o * KT;
    float v = W[o * ws + woff + k];
    if (sub) v -= W[o * ws + k];
    wl[o * KP + k] = v;
  }
  __syncthreads();
  int b = blockIdx.y;
  int j = blockIdx.x * 256 + tid;
  int M3 = 3 * N;
  if (j >= M3) return;
  const float* Xb = S.X[slot] + (size_t)b * KT * M3;
  float xv[KT];
#pragma unroll
  for (int k = 0; k < KT; ++k) xv[k] = Xb[(size_t)k * M3 + j];
  int d = j / N;
  const float* bias = S.bias[slot];
  float acc[16];
  if (bias) {
#pragma unroll
    for (int oo = 0; oo < 16; ++oo) acc[oo] = bias[b * 192 + (oc + oo) * 3 + d];
  } else {
#pragma unroll
    for (int oo = 0; oo < 16; ++oo) acc[oo] = 0.f;
  }
#pragma unroll
  for (int oo = 0; oo < 16; ++oo) {
    const float* wr = &wl[(oc + oo) * KP];
    float s = acc[oo];
#pragma unroll
    for (int k = 0; k < KT; ++k) s = fmaf(wr[k], xv[k], s);
    acc[oo] = s;
  }
  if (S.cm[slot]) {
    float* ob = S.cm[slot] + (size_t)b * 64 * M3;
#pragma unroll
    for (int oo = 0; oo < 16; ++oo) ob[(size_t)(oc + oo) * M3 + j] = acc[oo];
  }
  if (S.pm[slot]) {
    int n = j - d * N;
    float4* pp = (float4*)(S.pm[slot] + ((size_t)((b * N + n) * 3 + d)) * 64 + oc);
    pp[0] = make_float4(acc[0], acc[1], acc[2], acc[3]);
    pp[1] = make_float4(acc[4], acc[5], acc[6], acc[7]);
    pp[2] = make_float4(acc[8], acc[9], acc[10], acc[11]);
    pp[3] = make_float4(acc[12], acc[13], acc[14], acc[15]);
  }
}

// ---------------- edge conv, wave per point, side = blockIdx.y ----------------
__global__ void __launch_bounds__(256) k_edge2(const float* __restrict__ P1a, const float* __restrict__ P2a,
                                               const float* __restrict__ D1a, const float* __restrict__ D2a,
                                               const float* __restrict__ P1b, const float* __restrict__ P2b,
                                               const float* __restrict__ D1b, const float* __restrict__ D2b,
                                               const int* __restrict__ idxA, const int* __restrict__ idxB,
                                               float* __restrict__ outA, float* __restrict__ outB, int N) {
  int side = blockIdx.y;
  const float* P1 = side ? P1b : P1a;
  const float* P2 = side ? P2b : P2a;
  const float* D1 = side ? D1b : D1a;
  const float* D2 = side ? D2b : D2a;
  const int* idx = side ? idxB : idxA;
  float* out = side ? outB : outA;
  int tid = threadIdx.x;
  int p = blockIdx.x * 4 + (tid >> 6);
  int c = tid & 63;
  int b = p / N, n = p - b * N;
  size_t bn = ((size_t)(b * N + n) * 3) * 64 + c;
  float p2[3], d2[3];
#pragma unroll
  for (int d = 0; d < 3; ++d) { p2[d] = P2[bn + d * 64]; d2[d] = D2[bn + d * 64]; }
  const int* ip = idx + ((size_t)b * N + n) * 16;
  float acc0 = 0.f, acc1 = 0.f, acc2 = 0.f;
  for (int j = 0; j < 16; ++j) {
    int m = ip[j];
    size_t bm = ((size_t)(b * N + m) * 3) * 64 + c;
    float xl[3], dv[3];
#pragma unroll
    for (int d = 0; d < 3; ++d) {
      xl[d] = P1[bm + d * 64] + p2[d];
      dv[d] = D1[bm + d * 64] + d2[d];
    }
    float dot = xl[0] * dv[0] + xl[1] * dv[1] + xl[2] * dv[2];
    float dsq = dv[0] * dv[0] + dv[1] * dv[1] + dv[2] * dv[2];
    acc0 += lrelu_combine(xl[0], dv[0], dot, dsq);
    acc1 += lrelu_combine(xl[1], dv[1], dot, dsq);
    acc2 += lrelu_combine(xl[2], dv[2], dot, dsq);
  }
  size_t r0 = (size_t)((b * 64 + c) * 3) * N;
  out[r0 + n] = acc0 * (1.f / 16.f);
  out[r0 + N + n] = acc1 * (1.f / 16.f);
  out[r0 + 2 * (size_t)N + n] = acc2 * (1.f / 16.f);
}

// ---------------- Qx finisher: lrelu + chnorm (pm in, pm out) ----------------
__global__ void __launch_bounds__(256) k_qfin(const float* __restrict__ XL, const float* __restrict__ DV,
                                              float* __restrict__ outpm, int N) {
  int tid = threadIdx.x;
  int p = blockIdx.x * 4 + (tid >> 6);
  int c = tid & 63;
  int b = p / N, n = p - b * N;
  size_t bn = ((size_t)(b * N + n) * 3) * 64 + c;
  float xl[3], dv[3];
#pragma unroll
  for (int d = 0; d < 3; ++d) { xl[d] = XL[bn + d * 64]; dv[d] = DV[bn + d * 64]; }
  float dot = xl[0] * dv[0] + xl[1] * dv[1] + xl[2] * dv[2];
  float dsq = dv[0] * dv[0] + dv[1] * dv[1] + dv[2] * dv[2];
  float z[3];
#pragma unroll
  for (int d = 0; d < 3; ++d) z[d] = lrelu_combine(xl[d], dv[d], dot, dsq);
  float n2 = z[0] * z[0] + z[1] * z[1] + z[2] * z[2];
  float cn2 = n2;
#pragma unroll
  for (int s = 1; s < 64; s <<= 1) cn2 += __shfl_xor(cn2, s, 64);
  float n_o = sqrtf(n2), cn = sqrtf(cn2);
  float scl = (n_o / fmaxf(cn, EPSV)) / fmaxf(n_o, EPSV);
#pragma unroll
  for (int d = 0; d < 3; ++d) outpm[bn + d * 64] = z[d] * scl;
}

// ---------------- fused K-logits + softmax + V-attention + residual (wave per point) ----------------
// Logit values bit-identical to prior klog2 (lane-0 butterfly result broadcast); softmax = k_soft's
// exact sequence; V loop = attout2's exact sequence.
__global__ void __launch_bounds__(256) k_att(const float* __restrict__ xres,
                                             const float* __restrict__ qxpm,
                                             const float* __restrict__ KP1, const float* __restrict__ KP2,
                                             const float* __restrict__ KD1, const float* __restrict__ KD2,
                                             const float* __restrict__ VP1, const float* __restrict__ VP2,
                                             const float* __restrict__ VD1, const float* __restrict__ VD2,
                                             const int* __restrict__ idx,
                                             float* __restrict__ out, int N) {
  int tid = threadIdx.x;
  int p = blockIdx.x * 4 + (tid >> 6);
  int c = tid & 63;
  int b = p / N, n = p - b * N;
  size_t bn = ((size_t)(b * N + n) * 3) * 64 + c;
  float qv[3], kp2[3], kd2[3], vp2[3], vd2[3];
#pragma unroll
  for (int d = 0; d < 3; ++d) {
    qv[d] = qxpm[bn + d * 64];
    kp2[d] = KP2[bn + d * 64];
    kd2[d] = KD2[bn + d * 64];
    vp2[d] = VP2[bn + d * 64];
    vd2[d] = VD2[bn + d * 64];
  }
  const int* ip = idx + ((size_t)b * N + n) * 16;
  float l[16];
#pragma unroll
  for (int j = 0; j < 16; ++j) {
    int m = ip[j];
    size_t bm = ((size_t)(b * N + m) * 3) * 64 + c;
    float xl[3], dv[3];
#pragma unroll
    for (int d = 0; d < 3; ++d) {
      xl[d] = KP1[bm + d * 64] + kp2[d];
      dv[d] = KD1[bm + d * 64] + kd2[d];
    }
    float dot = xl[0] * dv[0] + xl[1] * dv[1] + xl[2] * dv[2];
    float dsq = dv[0] * dv[0] + dv[1] * dv[1] + dv[2] * dv[2];
    float z[3];
#pragma unroll
    for (int d = 0; d < 3; ++d) z[d] = lrelu_combine(xl[d], dv[d], dot, dsq);
    float n2 = z[0] * z[0] + z[1] * z[1] + z[2] * z[2];
    float cn2 = n2;
#pragma unroll
    for (int s = 1; s < 64; s <<= 1) cn2 += __shfl_xor(cn2, s, 64);
    float n_o = sqrtf(n2), cn = sqrtf(cn2);
    float scl = (n_o / fmaxf(cn, EPSV)) / fmaxf(n_o, EPSV);
    float part = (z[0] * qv[0] + z[1] * qv[1] + z[2] * qv[2]) * scl;
#pragma unroll
    for (int s = 1; s < 32; s <<= 1) part += __shfl_xor(part, s, 32);
    part = __shfl(part, 0, 32);  // broadcast lane-0 (lane-32) value: bit-identical to prior logits
    l[j] = part * 0.102062072615966f;  // 1/sqrt(96)
  }
  // softmax (k_soft's exact arithmetic)
  float mx = l[0];
#pragma unroll
  for (int j = 1; j < 16; ++j) mx = fmaxf(mx, l[j]);
  float sum = 0.f;
#pragma unroll
  for (int j = 0; j < 16; ++j) { l[j] = expf(l[j] - mx); sum += l[j]; }
  float inv = 1.f / sum;
#pragma unroll
  for (int j = 0; j < 16; ++j) l[j] *= inv;
  // V path
  float acc0 = 0.f, acc1 = 0.f, acc2 = 0.f;
#pragma unroll
  for (int j = 0; j < 16; ++j) {
    int m = ip[j];
    float av = l[j];
    size_t bm = ((size_t)(b * N + m) * 3) * 64 + c;
    float xl[3], dv[3];
#pragma unroll
    for (int d = 0; d < 3; ++d) {
      xl[d] = VP1[bm + d * 64] + vp2[d];
      dv[d] = VD1[bm + d * 64] + vd2[d];
    }
    float dot = xl[0] * dv[0] + xl[1] * dv[1] + xl[2] * dv[2];
    float dsq = dv[0] * dv[0] + dv[1] * dv[1] + dv[2] * dv[2];
    acc0 = fmaf(av, lrelu_combine(xl[0], dv[0], dot, dsq), acc0);
    acc1 = fmaf(av, lrelu_combine(xl[1], dv[1], dot, dsq), acc1);
    acc2 = fmaf(av, lrelu_combine(xl[2], dv[2], dot, dsq), acc2);
  }
  size_t r0 = (size_t)((b * 64 + c) * 3) * N;
  out[r0 + n] = xres[r0 + n] + acc0;
  out[r0 + N + n] = xres[r0 + N + n] + acc1;
  out[r0 + 2 * (size_t)N + n] = xres[r0 + 2 * (size_t)N + n] + acc2;
}

// ---------------- g-fuse finisher: wave per point, side = blockIdx.y ----------------
__global__ void __launch_bounds__(256) k_gfin(const float* __restrict__ XLa, const float* __restrict__ DVa,
                                              const float* __restrict__ XLb, const float* __restrict__ DVb,
                                              float* __restrict__ outa, float* __restrict__ outpa,
                                              float* __restrict__ outb, float* __restrict__ outpb, int N) {
  int side = blockIdx.y;
  const float* XL = side ? XLb : XLa;
  const float* DV = side ? DVb : DVa;
  float* out = side ? outb : outa;
  float* outpm = side ? outpb : outpa;
  int tid = threadIdx.x;
  int p = blockIdx.x * 4 + (tid >> 6);
  int c = tid & 63;
  int b = p / N, n = p - b * N;
  size_t bn = ((size_t)(b * N + n) * 3) * 64 + c;
  float xl[3], dv[3];
#pragma unroll
  for (int d = 0; d < 3; ++d) { xl[d] = XL[bn + d * 64]; dv[d] = DV[bn + d * 64]; }
  float dot = xl[0] * dv[0] + xl[1] * dv[1] + xl[2] * dv[2];
  float dsq = dv[0] * dv[0] + dv[1] * dv[1] + dv[2] * dv[2];
  size_t r0 = (size_t)((b * 64 + c) * 3) * N;
#pragma unroll
  for (int d = 0; d < 3; ++d) {
    float z = lrelu_combine(xl[d], dv[d], dot, dsq);
    out[r0 + (size_t)d * N + n] = z;
    outpm[bn + d * 64] = z;
  }
}

// ---------------- bias for g-fuse, both sides in one launch ----------------
__global__ void k_gbias2(const float* __restrict__ gw, const float* __restrict__ meanX,
                         const float* __restrict__ meanY,
                         float* __restrict__ cbX, float* __restrict__ cbY) {
  int b = blockIdx.x, which = blockIdx.y, tid = threadIdx.x;  // 192 threads
  int o = tid / 3, d = tid - o * 3;
  const float* mb = (which ? meanY : meanX) + b * 192;
  float* cb = (which ? cbY : cbX);
  float s = 0.f;
  for (int c = 0; c < 64; ++c) s = fmaf(gw[o * 128 + 64 + c], mb[c * 3 + d], s);
  cb[b * 192 + tid] = s;
}

// ---------------- column mean over N for both arrays in one launch ----------------
__global__ void k_cmean2(const float* __restrict__ x1, const float* __restrict__ x2,
                         float* __restrict__ o1, float* __restrict__ o2,
                         int N, int ostride, int obase, float inv) {
  __shared__ float red[256];
  int b = blockIdx.y, cd = blockIdx.x, which = blockIdx.z, tid = threadIdx.x;
  const float* x = which ? x2 : x1;
  float* out = which ? o2 : o1;
  const float* p = x + ((size_t)b * 192 + cd) * N;
  float s = 0.f;
  for (int i = tid; i < N; i += 256) s += p[i];
  red[tid] = s;
  __syncthreads();
  for (int st = 128; st > 0; st >>= 1) {
    if (tid < st) red[tid] += red[tid + st];
    __syncthreads();
  }
  if (tid == 0) out[(size_t)b * ostride + obase + cd] = red[0] * inv;
}

// ---------------- channel-mean (fx_par pre-normalization) for both arrays ----------------
__global__ void k_parmean(const float* __restrict__ fx, const float* __restrict__ fy,
                          float* __restrict__ px, float* __restrict__ py, int N, int B) {
  int gi = blockIdx.x * 256 + threadIdx.x;
  int total = B * 3 * N;
  if (gi >= total) return;
  int b = gi / (3 * N);
  int r = gi - b * 3 * N;
  const float* fxb = fx + (size_t)b * 192 * N + r;
  const float* fyb = fy + (size_t)b * 192 * N + r;
  float sx = 0.f, sy = 0.f;
  for (int c = 0; c < 64; ++c) { sx += fxb[(size_t)c * 3 * N]; sy += fyb[(size_t)c * 3 * N]; }
  px[gi] = sx * (1.f / 64.f);
  py[gi] = sy * (1.f / 64.f);
}

// ---------------- score logits: sum_c (fx.px)(fy.py) (softmax+norm skipped: monotone) ----------------
__global__ void k_dotphi(const float* __restrict__ fx, const float* __restrict__ fy,
                         const float* __restrict__ px, const float* __restrict__ py,
                         float* __restrict__ dps, int N, int B) {
  int gi = blockIdx.x * 256 + threadIdx.x;
  if (gi >= B * N) return;
  int b = gi / N, n = gi - b * N;
  const float* fxb = fx + (size_t)b * 192 * N + n;
  const float* fyb = fy + (size_t)b * 192 * N + n;
  const float* pxb = px + (size_t)b * 3 * N + n;
  const float* pyb = py + (size_t)b * 3 * N + n;
  float acc = 0.f;
  for (int c = 0; c < 64; ++c) {
    float ax = 0.f, ay = 0.f;
    for (int d = 0; d < 3; ++d) {
      ax = fmaf(fxb[(size_t)(c * 3 + d) * N], pxb[(size_t)d * N], ax);
      ay = fmaf(fyb[(size_t)(c * 3 + d) * N], pyb[(size_t)d * N], ay);
    }
    acc = fmaf(ax, ay, acc);
  }
  dps[gi] = acc;
}

// ---------------- top-N/2 selection: bitonic sort (desc value, asc index) ----------------
__global__ void __launch_bounds__(1024) k_topsel(const float* __restrict__ dps,
                                                 int* __restrict__ sel, int N, int Nh) {
  __shared__ float kv[2048];
  __shared__ int ki[2048];
  int b = blockIdx.x, tid = threadIdx.x;
  for (int i = tid; i < N; i += 1024) { kv[i] = dps[b * N + i]; ki[i] = i; }
  __syncthreads();
  for (int kk = 2; kk <= N; kk <<= 1) {
    for (int jj = kk >> 1; jj > 0; jj >>= 1) {
      for (int i = tid; i < N; i += 1024) {
        int ixj = i ^ jj;
        if (ixj > i) {
          float va = kv[i], vb = kv[ixj];
          int ia = ki[i], ib = ki[ixj];
          bool aFirst = (va > vb) || (va == vb && ia < ib);
          bool up = ((i & kk) == 0);
          bool doswap = up ? (!aFirst) : aFirst;
          if (doswap) { kv[i] = vb; kv[ixj] = va; ki[i] = ib; ki[ixj] = ia; }
        }
      }
      __syncthreads();
    }
  }
  for (int i = tid; i < Nh; i += 1024) sel[b * Nh + i] = ki[i];
}

// ---------------- gather selected points (pm source, cm dest), wave per point ----------------
__global__ void __launch_bounds__(256) k_gather(const float* __restrict__ sxpm, const float* __restrict__ sypm,
                                                const int* __restrict__ sel,
                                                float* __restrict__ dx, float* __restrict__ dy,
                                                int N, int Nh) {
  int tid = threadIdx.x;
  int p = blockIdx.x * 4 + (tid >> 6);
  int c = tid & 63;
  int b = p / Nh, i = p - b * Nh;
  int s = sel[b * Nh + i];
  size_t bs = ((size_t)(b * N + s) * 3) * 64 + c;
  size_t r0 = (size_t)((b * 64 + c) * 3) * Nh;
#pragma unroll
  for (int d = 0; d < 3; ++d) {
    dx[r0 + (size_t)d * Nh + i] = sxpm[bs + d * 64];
    dy[r0 + (size_t)d * Nh + i] = sypm[bs + d * 64];
  }
}

// ---------------- final head: vn_lin_lrelu(concat blocks, h_w, h_d) ----------------
__global__ void k_head(const float* __restrict__ blkX, const float* __restrict__ blkY,
                       const float* __restrict__ hw, const float* __restrict__ hd,
                       float* __restrict__ Fx, float* __restrict__ Fy) {
  __shared__ float f[3][128];
  __shared__ float xl[3][32];
  __shared__ float dv[3][32];
  int which = blockIdx.x, b = blockIdx.y, tid = threadIdx.x;
  const float* blk = which ? blkY : blkX;
  float* F = which ? Fy : Fx;
  int o = tid & 31, dd = tid >> 5;
  for (int i = tid; i < 384; i += 96) f[i % 3][i / 3] = blk[(size_t)b * 384 + i];
  __syncthreads();
  float s = 0.f;
  for (int c = 0; c < 128; ++c) s = fmaf(hw[o * 128 + c], f[dd][c], s);
  xl[dd][o] = s;
  __syncthreads();
  float s2 = 0.f;
  for (int p = 0; p < 32; ++p) s2 = fmaf(hd[o * 32 + p], xl[dd][p], s2);
  dv[dd][o] = s2;
  __syncthreads();
  float dot = xl[0][o] * dv[0][o] + xl[1][o] * dv[1][o] + xl[2][o] * dv[2][o];
  float dsq = dv[0][o] * dv[0][o] + dv[1][o] * dv[1][o] + dv[2][o] * dv[2][o];
  F[((size_t)b * 32 + o) * 3 + dd] = lrelu_combine(xl[dd][o], dv[dd][o], dot, dsq);
}

// ================== LAPACK-faithful 3x3 SVD (dgesdd path: dgebrd + dbdsqr) ==================
#define DEPS 2.220446049250313e-16
#define DUNFL 2.2250738585072014e-308

static __device__ void dlartg_(double f, double g, double* cs, double* sn, double* r) {
  if (g == 0.0) { *cs = 1.0; *sn = 0.0; *r = f; }
  else if (f == 0.0) { *cs = 0.0; *sn = copysign(1.0, g); *r = fabs(g); }
  else {
    double d = sqrt(f * f + g * g);
    double c = fabs(f) / d;
    double rr = copysign(d, f);
    *cs = c; *r = rr; *sn = g / rr;
  }
}

static __device__ void dlas2_(double f, double g, double h, double* ssmin, double* ssmax) {
  double fa = fabs(f), ga = fabs(g), ha = fabs(h);
  double fhmn = fmin(fa, ha), fhmx = fmax(fa, ha);
  if (fhmn == 0.0) {
    *ssmin = 0.0;
    if (fhmx == 0.0) *ssmax = ga;
    else { double mx = fmax(fhmx, ga), mn = fmin(fhmx, ga); double q = mn / mx; *ssmax = mx * sqrt(1.0 + q * q); }
  } else {
    if (ga < fhmx) {
      double as_ = 1.0 + fhmn / fhmx;
      double at = (fhmx - fhmn) / fhmx;
      double au = ga / fhmx; au = au * au;
      double c = 2.0 / (sqrt(as_ * as_ + au) + sqrt(at * at + au));
      *ssmin = fhmn * c; *ssmax = fhmx / c;
    } else {
      double au = fhmx / ga;
      if (au == 0.0) { *ssmin = (fhmn * fhmx) / ga; *ssmax = ga; }
      else {
        double as_ = 1.0 + fhmn / fhmx;
        double at = (fhmx - fhmn) / fhmx;
        double t1 = as_ * au, t2 = at * au;
        double c = 1.0 / (sqrt(1.0 + t1 * t1) + sqrt(1.0 + t2 * t2));
        double sm = (fhmn * c) * au; *ssmin = sm + sm;
        *ssmax = ga / (c + c);
      }
    }
  }
}

static __device__ void dlasv2_(double f, double g, double h,
                               double* ssmin, double* ssmax,
                               double* snr, double* csr, double* snl, double* csl) {
  double ft = f, fa = fabs(f), ht = h, ha = fabs(h);
  int pmax = 1;
  bool swp = (ha > fa);
  if (swp) { pmax = 3; double t = ft; ft = ht; ht = t; t = fa; fa = ha; ha = t; }
  double gt = g, ga = fabs(g);
  double clt = 0, crt = 0, slt = 0, srt = 0;
  if (ga == 0.0) {
    *ssmin = ha; *ssmax = fa; clt = 1.0; crt = 1.0; slt = 0.0; srt = 0.0;
  } else {
    bool gasmal = true;
    if (ga > fa) {
      pmax = 2;
      if ((fa / ga) < DEPS) {
        gasmal = false;
        *ssmax = ga;
        *ssmin = (ha > 1.0) ? (fa / (ga / ha)) : ((fa / ga) * ha);
        clt = 1.0; slt = ht / gt; srt = 1.0; crt = ft / gt;
      }
    }
    if (gasmal) {
      double dd = fa - ha;
      double l = (dd == fa) ? 1.0 : (dd / fa);
      double mq = gt / ft;
      double t = 2.0 - l;
      double mm = mq * mq, tt = t * t;
      double s = sqrt(tt + mm);
      double r = (l == 0.0) ? fabs(mq) : sqrt(l * l + mm);
      double a = 0.5 * (s + r);
      *ssmin = ha / a;
      *ssmax = fa * a;
      if (mm == 0.0) {
        if (l == 0.0) t = copysign(2.0, ft) * copysign(1.0, gt);
        else t = gt / copysign(dd, ft) + mq / t;
      } else {
        t = (mq / (s + t) + mq / (r + l)) * (1.0 + a);
      }
      double l2 = sqrt(t * t + 4.0);
      crt = 2.0 / l2;
      srt = t / l2;
      clt = (crt + srt * mq) / a;
      slt = (ht / ft) * srt / a;
    }
  }
  if (swp) { *csl = srt; *snl = crt; *csr = slt; *snr = clt; }
  else { *csl = clt; *snl = slt; *csr = crt; *snr = srt; }
  double tsign = 0.0;
  if (pmax == 1) tsign = copysign(1.0, *csr) * copysign(1.0, *csl) * copysign(1.0, f);
  if (pmax == 2) tsign = copysign(1.0, *snr) * copysign(1.0, *csl) * copysign(1.0, g);
  if (pmax == 3) tsign = copysign(1.0, *snr) * copysign(1.0, *snl) * copysign(1.0, h);
  *ssmax = copysign(*ssmax, tsign);
  *ssmin = copysign(*ssmin, tsign * copysign(1.0, f) * copysign(1.0, h));
}

static __device__ void dbdsqr3(double d[3], double e[2], double VT[3][3], double U[3][3]) {
  const int n = 3;
  double tolmul = fmax(10.0, fmin(100.0, pow(DEPS, -0.125)));
  double tol = tolmul * DEPS;
  double thresh;
  {
    double sminoa = fabs(d[0]);
    if (sminoa != 0.0) {
      double mu = sminoa;
      for (int i = 1; i < n; ++i) {
        mu = fabs(d[i]) * (mu / (mu + fabs(e[i - 1])));
        sminoa = fmin(sminoa, mu);
        if (sminoa == 0.0) break;
      }
    }
    sminoa = sminoa / sqrt((double)n);
    thresh = fmax(tol * sminoa, 6.0 * n * n * DUNFL);
  }
  int maxit = 6 * n * n;
  int iter = 0, oldll = -1, oldm = -1, idir = 0;
  int m = n;
  double sminl = 0.0;
  int guard = 0;
  while (true) {
    if (m <= 1) break;
    if (iter > maxit) break;
    if (++guard > 500) break;
    double smaxb = fabs(d[m - 1]);
    int ll = 0; bool found = false;
    for (int lll = 1; lll <= m - 1; ++lll) {
      int l = m - lll;
      double abss = fabs(d[l - 1]);
      double abse = fabs(e[l - 1]);
      if (abse <= thresh) { ll = l; found = true; break; }
      smaxb = fmax(smaxb, fmax(abss, abse));
    }
    if (found) {
      e[ll - 1] = 0.0;
      if (ll == m - 1) { m = m - 1; continue; }
      ll = ll + 1;
    } else ll = 1;
    if (ll == m - 1) {
      double sigmn, sigmx, sinr, cosr, sinl2, cosl2;
      dlasv2_(d[m - 2], e[m - 2], d[m - 1], &sigmn, &sigmx, &sinr, &cosr, &sinl2, &cosl2);
      d[m - 2] = sigmx; d[m - 1] = sigmn; e[m - 2] = 0.0;
      for (int j = 0; j < 3; ++j) {
        double t1 = VT[m - 2][j], t2 = VT[m - 1][j];
        VT[m - 2][j] = cosr * t1 + sinr * t2;
        VT[m - 1][j] = cosr * t2 - sinr * t1;
      }
      for (int i2 = 0; i2 < 3; ++i2) {
        double t1 = U[i2][m - 2], t2 = U[i2][m - 1];
        U[i2][m - 2] = cosl2 * t1 + sinl2 * t2;
        U[i2][m - 1] = cosl2 * t2 - sinl2 * t1;
      }
      m -= 2;
      continue;
    }
    if (ll > oldm || m < oldll)
      idir = (fabs(d[ll - 1]) >= fabs(d[m - 1])) ? 1 : 2;
    if (idir == 1) {
      if (fabs(e[m - 2]) <= tol * fabs(d[m - 1])) { e[m - 2] = 0.0; continue; }
      double mu = fabs(d[ll - 1]); sminl = mu;
      bool conv = true;
      for (int lll = ll; lll <= m - 1; ++lll) {
        if (fabs(e[lll - 1]) > tol * mu) { conv = false; break; }
        mu = fabs(d[lll]) * (mu / (mu + fabs(e[lll - 1])));
        sminl = fmin(sminl, mu);
      }
      if (conv) { e[m - 2] = 0.0; continue; }
    } else {
      if (fabs(e[ll - 1]) <= tol * fabs(d[ll - 1])) { e[ll - 1] = 0.0; continue; }
      double mu = fabs(d[m - 1]); sminl = mu;
      bool conv = true;
      for (int lll = m - 1; lll >= ll; --lll) {
        if (fabs(e[lll - 1]) > tol * mu) { conv = false; break; }
        mu = fabs(d[lll - 1]) * (mu / (mu + fabs(e[lll - 1])));
        sminl = fmin(sminl, mu);
      }
      if (conv) { e[ll - 1] = 0.0; continue; }
    }
    oldll = ll; oldm = m;
    double shift = 0.0, rr;
    if (!(n * tol * (sminl / smaxb) <= fmax(DEPS, 0.01 * tol))) {
      double sll;
      if (idir == 1) { sll = fabs(d[ll - 1]); dlas2_(d[m - 2], e[m - 2], d[m - 1], &shift, &rr); }
      else { sll = fabs(d[m - 1]); dlas2_(d[ll - 1], e[ll - 1], d[ll], &shift, &rr); }
      if (sll > 0.0) { double q = shift / sll; if (q * q < DEPS) shift = 0.0; }
    }
    iter += m - ll;
    double csv[2], snv[2], ocsv[2], osnv[2];
    int cnt = 0;
    if (shift == 0.0) {
      if (idir == 1) {
        double cs = 1.0, oldcs = 1.0, sn = 0.0, oldsn = 0.0, r;
        for (int i = ll; i <= m - 1; ++i) {
          dlartg_(d[i - 1] * cs, e[i - 1], &cs, &sn, &r);
          if (i > ll) e[i - 2] = oldsn * r;
          dlartg_(oldcs * r, d[i] * sn, &oldcs, &oldsn, &d[i - 1]);
          csv[cnt] = cs; snv[cnt] = sn; ocsv[cnt] = oldcs; osnv[cnt] = oldsn; cnt++;
        }
        double hh = d[m - 1] * cs;
        d[m - 1] = hh * oldcs;
        e[m - 2] = hh * oldsn;
        for (int k = 0; k < cnt; ++k) {
          int r0 = ll - 1 + k, r1 = r0 + 1;
          for (int j = 0; j < 3; ++j) {
            double t1 = VT[r0][j], t2 = VT[r1][j];
            VT[r0][j] = snv[k] * t2 + csv[k] * t1;
            VT[r1][j] = csv[k] * t2 - snv[k] * t1;
          }
        }
        for (int k = 0; k < cnt; ++k) {
          int c0 = ll - 1 + k, c1 = c0 + 1;
          for (int i2 = 0; i2 < 3; ++i2) {
            double t1 = U[i2][c0], t2 = U[i2][c1];
            U[i2][c0] = osnv[k] * t2 + ocsv[k] * t1;
            U[i2][c1] = ocsv[k] * t2 - osnv[k] * t1;
          }
        }
        if (fabs(e[m - 2]) <= thresh) e[m - 2] = 0.0;
      } else {
        double cs = 1.0, oldcs = 1.0, sn = 0.0, oldsn = 0.0, r;
        for (int i = m; i >= ll + 1; --i) {
          dlartg_(d[i - 1] * cs, e[i - 2], &cs, &sn, &r);
          if (i < m) e[i - 1] = oldsn * r;
          dlartg_(oldcs * r, d[i - 2] * sn, &oldcs, &oldsn, &d[i - 1]);
          int k = i - ll - 1;
          csv[k] = cs; snv[k] = -sn; ocsv[k] = oldcs; osnv[k] = -oldsn; cnt++;
        }
        double hh = d[ll - 1] * cs;
        d[ll - 1] = hh * oldcs;
        e[ll - 1] = hh * oldsn;
        for (int k = cnt - 1; k >= 0; --k) {
          int r0 = ll - 1 + k, r1 = r0 + 1;
          for (int j = 0; j < 3; ++j) {
            double t1 = VT[r0][j], t2 = VT[r1][j];
            VT[r0][j] = osnv[k] * t2 + ocsv[k] * t1;
            VT[r1][j] = ocsv[k] * t2 - osnv[k] * t1;
          }
        }
        for (int k = cnt - 1; k >= 0; --k) {
          int c0 = ll - 1 + k, c1 = c0 + 1;
          for (int i2 = 0; i2 < 3; ++i2) {
            double t1 = U[i2][c0], t2 = U[i2][c1];
            U[i2][c0] = snv[k] * t2 + csv[k] * t1;
            U[i2][c1] = csv[k] * t2 - snv[k] * t1;
          }
        }
        if (fabs(e[ll - 1]) <= thresh) e[ll - 1] = 0.0;
      }
    } else {
      if (idir == 1) {
        double f = (fabs(d[ll - 1]) - shift) * (copysign(1.0, d[ll - 1]) + shift / d[ll - 1]);
        double g = e[ll - 1];
        double cosr, sinr, cosl2, sinl2, r;
        for (int i = ll; i <= m - 1; ++i) {
          dlartg_(f, g, &cosr, &sinr, &r);
          if (i > ll) e[i - 2] = r;
          f = cosr * d[i - 1] + sinr * e[i - 1];
          e[i - 1] = cosr * e[i - 1] - sinr * d[i - 1];
          g = sinr * d[i];
          d[i] = cosr * d[i];
          dlartg_(f, g, &cosl2, &sinl2, &r);
          d[i - 1] = r;
          f = cosl2 * e[i - 1] + sinl2 * d[i];
          d[i] = cosl2 * d[i] - sinl2 * e[i - 1];
          if (i < m - 1) {
            g = sinl2 * e[i];
            e[i] = cosl2 * e[i];
          }
          csv[cnt] = cosr; snv[cnt] = sinr; ocsv[cnt] = cosl2; osnv[cnt] = sinl2; cnt++;
        }
        e[m - 2] = f;
        for (int k = 0; k < cnt; ++k) {
          int r0 = ll - 1 + k, r1 = r0 + 1;
          for (int j = 0; j < 3; ++j) {
            double t1 = VT[r0][j], t2 = VT[r1][j];
            VT[r0][j] = snv[k] * t2 + csv[k] * t1;
            VT[r1][j] = csv[k] * t2 - snv[k] * t1;
          }
        }
        for (int k = 0; k < cnt; ++k) {
          int c0 = ll - 1 + k, c1 = c0 + 1;
          for (int i2 = 0; i2 < 3; ++i2) {
            double t1 = U[i2][c0], t2 = U[i2][c1];
            U[i2][c0] = osnv[k] * t2 + ocsv[k] * t1;
            U[i2][c1] = ocsv[k] * t2 - osnv[k] * t1;
          }
        }
        if (fabs(e[m - 2]) <= thresh) e[m - 2] = 0.0;
      } else {
        double f = (fabs(d[m - 1]) - shift) * (copysign(1.0, d[m - 1]) + shift / d[m - 1]);
        double g = e[m - 2];
        for (int i = m; i >= ll + 1; --i) {
          double cosr, sinr, cosl2, sinl2, r;
          dlartg_(f, g, &cosr, &sinr, &r);
          if (i < m) e[i - 1] = r;
          f = cosr * d[i - 1] + sinr * e[i - 2];
          e[i - 2] = cosr * e[i - 2] - sinr * d[i - 1];
          g = sinr * d[i - 2];
          d[i - 2] = cosr * d[i - 2];
          dlartg_(f, g, &cosl2, &sinl2, &r);
          d[i - 1] = r;
          f = cosl2 * e[i - 2] + sinl2 * d[i - 2];
          d[i - 2] = cosl2 * d[i - 2] - sinl2 * e[i - 2];
          if (i > ll + 1) {
            g = sinl2 * e[i - 3];
            e[i - 3] = cosl2 * e[i - 3];
          }
          int k = i - ll - 1;
          ocsv[k] = cosl2; osnv[k] = -sinl2; csv[k] = cosr; snv[k] = -sinr; cnt++;
        }
        e[ll - 1] = f;
        for (int k = cnt - 1; k >= 0; --k) {
          int r0 = ll - 1 + k, r1 = r0 + 1;
          for (int j = 0; j < 3; ++j) {
            double t1 = VT[r0][j], t2 = VT[r1][j];
            VT[r0][j] = snv[k] * t2 + csv[k] * t1;
            VT[r1][j] = csv[k] * t2 - snv[k] * t1;
          }
        }
        for (int k = cnt - 1; k >= 0; --k) {
          int c0 = ll - 1 + k, c1 = c0 + 1;
          for (int i2 = 0; i2 < 3; ++i2) {
            double t1 = U[i2][c0], t2 = U[i2][c1];
            U[i2][c0] = osnv[k] * t2 + ocsv[k] * t1;
            U[i2][c1] = ocsv[k] * t2 - osnv[k] * t1;
          }
        }
        if (fabs(e[ll - 1]) <= thresh) e[ll - 1] = 0.0;
      }
    }
  }
  for (int i = 0; i < n; ++i)
    if (d[i] < 0.0) { d[i] = -d[i]; for (int j = 0; j < 3; ++j) VT[i][j] = -VT[i][j]; }
  for (int i = 1; i <= n - 1; ++i) {
    int isub = 1; double smn = d[0];
    for (int j = 2; j <= n + 1 - i; ++j)
      if (d[j - 1] <= smn) { isub = j; smn = d[j - 1]; }
    if (isub != n + 1 - i) {
      int a = isub - 1, b2 = n - i;
      double t = d[a]; d[a] = d[b2]; d[b2] = t;
      for (int j = 0; j < 3; ++j) { t = VT[a][j]; VT[a][j] = VT[b2][j]; VT[b2][j] = t; }
      for (int j = 0; j < 3; ++j) { t = U[j][a]; U[j][a] = U[j][b2]; U[j][b2] = t; }
    }
  }
}

__global__ void k_svd(const float* __restrict__ Fx, const float* __restrict__ Fy,
                      float* __restrict__ out, int B) {
  int b = blockIdx.x;
  if (threadIdx.x != 0) return;
  double A[3][3];
  for (int d = 0; d < 3; ++d)
    for (int e = 0; e < 3; ++e) {
      double s = 0.0;
      for (int c = 0; c < 32; ++c)
        s += (double)Fx[((size_t)b * 32 + c) * 3 + d] * (double)Fy[((size_t)b * 32 + c) * 3 + e];
      A[d][e] = s;
    }
  double dg[3], eg[2], tauq0, tauq1, taup0;
  double v1_1 = 0, v1_2 = 0, v2_1 = 0, w1 = 0;
  {
    double alpha = A[0][0];
    double xn = sqrt(A[1][0] * A[1][0] + A[2][0] * A[2][0]);
    if (xn == 0.0) { tauq0 = 0.0; dg[0] = alpha; }
    else {
      double beta = -copysign(sqrt(alpha * alpha + xn * xn), alpha);
      tauq0 = (beta - alpha) / beta;
      double scal = 1.0 / (alpha - beta);
      v1_1 = A[1][0] * scal; v1_2 = A[2][0] * scal;
      dg[0] = beta;
    }
    for (int j = 1; j < 3; ++j) {
      double w = A[0][j] + v1_1 * A[1][j] + v1_2 * A[2][j];
      w *= tauq0;
      A[0][j] -= w; A[1][j] -= w * v1_1; A[2][j] -= w * v1_2;
    }
  }
  {
    double alpha = A[0][1];
    double xn = fabs(A[0][2]);
    if (xn == 0.0) { taup0 = 0.0; eg[0] = alpha; }
    else {
      double beta = -copysign(sqrt(alpha * alpha + xn * xn), alpha);
      taup0 = (beta - alpha) / beta;
      w1 = A[0][2] / (alpha - beta);
      eg[0] = beta;
    }
    for (int i = 1; i < 3; ++i) {
      double t = A[i][1] + w1 * A[i][2];
      t *= taup0;
      A[i][1] -= t; A[i][2] -= t * w1;
    }
  }
  {
    double alpha = A[1][1];
    double xn = fabs(A[2][1]);
    if (xn == 0.0) { tauq1 = 0.0; dg[1] = alpha; }
    else {
      double beta = -copysign(sqrt(alpha * alpha + xn * xn), alpha);
      tauq1 = (beta - alpha) / beta;
      v2_1 = A[2][1] / (alpha - beta);
      dg[1] = beta;
    }
    double w = A[1][2] + v2_1 * A[2][2];
    w *= tauq1;
    A[1][2] -= w; A[2][2] -= w * v2_1;
  }
  eg[1] = A[1][2];
  dg[2] = A[2][2];
  double U[3][3] = {{1, 0, 0}, {0, 1, 0}, {0, 0, 1}};
  double VT[3][3] = {{1, 0, 0}, {0, 1, 0}, {0, 0, 1}};
  dbdsqr3(dg, eg, VT, U);
  for (int j = 0; j < 3; ++j) {
    double w = U[1][j] + v2_1 * U[2][j];
    w *= tauq1;
    U[1][j] -= w; U[2][j] -= w * v2_1;
  }
  for (int j = 0; j < 3; ++j) {
    double w = U[0][j] + v1_1 * U[1][j] + v1_2 * U[2][j];
    w *= tauq0;
    U[0][j] -= w; U[1][j] -= w * v1_1; U[2][j] -= w * v1_2;
  }
  for (int r = 0; r < 3; ++r) {
    double t = VT[r][1] + w1 * VT[r][2];
    t *= taup0;
    VT[r][1] -= t; VT[r][2] -= t * w1;
  }
  for (int i = 0; i < 3; ++i)
    for (int j = 0; j < 3; ++j) {
      double r = 0;
      for (int k = 0; k < 3; ++k) r += U[i][k] * VT[j][k];
      out[b * 9 + i * 3 + j] = (float)r;
    }
  for (int dd = 0; dd < 3; ++dd) {
    float sx = 0.f, sy = 0.f;
    for (int c = 0; c < 32; ++c) {
      float vx = Fx[((size_t)b * 32 + c) * 3 + dd];
      float vy = Fy[((size_t)b * 32 + c) * 3 + dd];
      sx = fmaf(vx, vx, sx);
      sy = fmaf(vy, vy, sy);
    }
    out[B * 9 + b * 3 + dd] = sqrtf(sy) / sqrtf(sx);
  }
}

extern "C" void kernel_launch(void* const* d_in, const int* in_sizes, int n_in,
                              void* d_out, int out_size, void* d_ws, size_t ws_size,
                              hipStream_t stream) {
  (void)in_sizes; (void)n_in; (void)out_size; (void)ws_size;
  const int B = 2, N0 = 2048;
  const float* W[24];
  for (int i = 0; i < 24; ++i) W[i] = (const float*)d_in[i];

  float* ws = (float*)d_ws;
  const size_t P = (size_t)B * 64 * 3 * 2048;  // 786432 floats
  float* bufA = ws;
  float* bufB = bufA + P;
  float* bufC = bufB + P;
  float* bufD = bufC + P;
  float* bufApm = bufD + P;
  float* bufBpm = bufApm + P;
  float* qxpm = bufBpm + P;
  float* C1 = qxpm + P;
  float* C2 = C1 + P;
  float* C3 = C2 + P;
  float* C4 = C3 + P;
  float* C5 = C4 + P;
  float* M1 = C5 + P;
  float* M2 = M1 + P;
  float* M3 = M2 + P;
  float* M4 = M3 + P;
  float* M5 = M4 + P;
  float* M6 = M5 + P;
  float* M7 = M6 + P;
  float* M8 = M7 + P;
  float* M9 = M8 + P;
  float* M10 = M9 + P;
  float* px = M10 + P;               // B*3*2048 = 12288
  float* py = px + 12288;
  float* dps = py + 12288;           // 4096
  float* xx0 = dps + 4096;           // 4096
  float* xx1 = xx0 + 4096;           // 4096
  float* meanX = xx1 + 4096;         // 384
  float* meanY = meanX + 384;
  float* cbX = meanY + 384;
  float* cbY = cbX + 384;
  float* blkX = cbY + 384;           // 768
  float* blkY = blkX + 768;
  float* Fxb = blkY + 768;           // 192
  float* Fyb = Fxb + 192;
  int* idxA = (int*)(Fyb + 192);     // 65536
  int* idxB = idxA + 65536;
  int* sel = idxB + 65536;           // 2048

  auto knn2s = [&](const float* xa, const float* xb2, int D, int N, int* ia, int* ib, int ns) {
    k_xx2<<<dim3((N + 255) / 256, B, ns), 256, 0, stream>>>(xa, xb2, xx0, xx1, D, N);
    dim3 g2(N / 4, B, ns);
    if (D == 192) k_knn2<192><<<g2, 256, 0, stream>>>(xa, xb2, xx0, xx1, ia, ib, N);
    else          k_knn2<3><<<g2, 256, 0, stream>>>(xa, xb2, xx0, xx1, ia, ib, N);
  };

  const float* fx = W[0];
  const float* fy = W[1];
  int N = N0;
  for (int blk = 0; blk < 2; ++blk) {
    int D = (blk == 0) ? 3 : 192;
    const float* dgw = W[blk ? 12 : 2]; const float* dgd = W[blk ? 13 : 3];
    const float* qw  = W[blk ? 14 : 4]; const float* qd  = W[blk ? 15 : 5];
    const float* kw  = W[blk ? 16 : 6]; const float* kd  = W[blk ? 17 : 7];
    const float* vw  = W[blk ? 18 : 8]; const float* vd  = W[blk ? 19 : 9];
    const float* gw  = W[blk ? 20 : 10]; const float* gd = W[blk ? 21 : 11];
    dim3 gP(B * N / 4);
    dim3 gL((3 * N + 255) / 256, B, 1);  // z set per launch

    // ======== dgcnn, both sides in merged launches ========
    knn2s(fx, fy, D, N, idxA, idxB, 2);
    {
      LinSlots s{};  // stage1: W1*x, (W2-W1)*x for fx and fy
      int wsd = (blk == 0) ? 2 : 128;
      int off2 = (blk == 0) ? 1 : 64;
      const float* Xs[4] = {fx, fx, fy, fy};
      float* cms[4] = {C1, C2, C3, C4};
      float* pms[4] = {M1, M2, M3, M4};
      for (int i = 0; i < 4; ++i) {
        s.W[i] = dgw; s.X[i] = Xs[i]; s.bias[i] = nullptr;
        s.cm[i] = cms[i]; s.pm[i] = pms[i];
        s.ws[i] = wsd; s.woff[i] = (i & 1) ? off2 : 0; s.sub[i] = (i & 1);
      }
      gL.z = 16;
      if (blk == 0) k_linm<1><<<gL, 256, 0, stream>>>(s, N);
      else          k_linm<64><<<gL, 256, 0, stream>>>(s, N);
    }
    {
      LinSlots s{};  // stage2: Wd * each
      const float* Xs[4] = {C1, C2, C3, C4};
      float* pms[4] = {M5, M6, M7, M8};
      for (int i = 0; i < 4; ++i) {
        s.W[i] = dgd; s.X[i] = Xs[i]; s.bias[i] = nullptr;
        s.cm[i] = nullptr; s.pm[i] = pms[i];
        s.ws[i] = 64; s.woff[i] = 0; s.sub[i] = 0;
      }
      gL.z = 16;
      k_linm<64><<<gL, 256, 0, stream>>>(s, N);
    }
    k_edge2<<<dim3(B * N / 4, 2), 256, 0, stream>>>(M1, M2, M5, M6, M3, M4, M7, M8,
                                                    idxA, idxB, bufA, bufB, N);

    // ======== cross_context #1: x=bufA, y=bufB -> bufC ========
    knn2s(bufB, bufB, 192, N, idxB, idxB, 1);
    {
      LinSlots s{};  // stage1: q,k1,k2,v1,v2
      const float* Wm[5] = {qw, kw, kw, vw, vw};
      const float* Xs[5] = {bufA, bufB, bufB, bufB, bufB};
      float* cms[5] = {C1, C2, C3, C4, C5};
      float* pms[5] = {M1, M3, M4, M5, M6};
      int wss[5] = {64, 128, 128, 128, 128};
      int offs[5] = {0, 0, 64, 0, 64};
      int subs[5] = {0, 0, 1, 0, 1};
      for (int i = 0; i < 5; ++i) {
        s.W[i] = Wm[i]; s.X[i] = Xs[i]; s.bias[i] = nullptr;
        s.cm[i] = cms[i]; s.pm[i] = pms[i];
        s.ws[i] = wss[i]; s.woff[i] = offs[i]; s.sub[i] = subs[i];
      }
      gL.z = 20;
      k_linm<64><<<gL, 256, 0, stream>>>(s, N);
    }
    {
      LinSlots s{};  // stage2: qd,kd,kd,vd,vd
      const float* Wm[5] = {qd, kd, kd, vd, vd};
      const float* Xs[5] = {C1, C2, C3, C4, C5};
      float* pms[5] = {M2, M7, M8, M9, M10};
      for (int i = 0; i < 5; ++i) {
        s.W[i] = Wm[i]; s.X[i] = Xs[i]; s.bias[i] = nullptr;
        s.cm[i] = nullptr; s.pm[i] = pms[i];
        s.ws[i] = 64; s.woff[i] = 0; s.sub[i] = 0;
      }
      gL.z = 20;
      k_linm<64><<<gL, 256, 0, stream>>>(s, N);
    }
    k_qfin<<<gP, 256, 0, stream>>>(M1, M2, qxpm, N);
    k_att<<<gP, 256, 0, stream>>>(bufA, qxpm, M3, M4, M7, M8, M5, M6, M9, M10, idxB, bufC, N);

    // ======== cross_context #2: x=bufB, y=bufC -> bufD ========
    knn2s(bufC, bufC, 192, N, idxA, idxA, 1);
    {
      LinSlots s{};
      const float* Wm[5] = {qw, kw, kw, vw, vw};
      const float* Xs[5] = {bufB, bufC, bufC, bufC, bufC};
      float* cms[5] = {C1, C2, C3, C4, C5};
      float* pms[5] = {M1, M3, M4, M5, M6};
      int wss[5] = {64, 128, 128, 128, 128};
      int offs[5] = {0, 0, 64, 0, 64};
      int subs[5] = {0, 0, 1, 0, 1};
      for (int i = 0; i < 5; ++i) {
        s.W[i] = Wm[i]; s.X[i] = Xs[i]; s.bias[i] = nullptr;
        s.cm[i] = cms[i]; s.pm[i] = pms[i];
        s.ws[i] = wss[i]; s.woff[i] = offs[i]; s.sub[i] = subs[i];
      }
      gL.z = 20;
      k_linm<64><<<gL, 256, 0, stream>>>(s, N);
    }
    {
      LinSlots s{};
      const float* Wm[5] = {qd, kd, kd, vd, vd};
      const float* Xs[5] = {C1, C2, C3, C4, C5};
      float* pms[5] = {M2, M7, M8, M9, M10};
      for (int i = 0; i < 5; ++i) {
        s.W[i] = Wm[i]; s.X[i] = Xs[i]; s.bias[i] = nullptr;
        s.cm[i] = nullptr; s.pm[i] = pms[i];
        s.ws[i] = 64; s.woff[i] = 0; s.sub[i] = 0;
      }
      gL.z = 20;
      k_linm<64><<<gL, 256, 0, stream>>>(s, N);
    }
    k_qfin<<<gP, 256, 0, stream>>>(M1, M2, qxpm, N);
    k_att<<<gP, 256, 0, stream>>>(bufB, qxpm, M3, M4, M7, M8, M5, M6, M9, M10, idxA, bufD, N);

    // ======== global fuse ========
    k_cmean2<<<dim3(192, B, 2), 256, 0, stream>>>(bufC, bufD, meanX, meanY, N, 192, 0, 1.f / (float)N);
    k_gbias2<<<dim3(B, 2), 192, 0, stream>>>(gw, meanX, meanY, cbX, cbY);
    {
      LinSlots s{};  // gw on both sides (with bias)
      const float* Xs[2] = {bufC, bufD};
      const float* bs[2] = {cbX, cbY};
      float* cms[2] = {C1, C2};
      float* pms[2] = {M1, M2};
      for (int i = 0; i < 2; ++i) {
        s.W[i] = gw; s.X[i] = Xs[i]; s.bias[i] = bs[i];
        s.cm[i] = cms[i]; s.pm[i] = pms[i];
        s.ws[i] = 128; s.woff[i] = 0; s.sub[i] = 0;
      }
      gL.z = 8;
      k_linm<64><<<gL, 256, 0, stream>>>(s, N);
    }
    {
      LinSlots s{};  // gd on both sides
      const float* Xs[2] = {C1, C2};
      float* pms[2] = {M3, M4};
      for (int i = 0; i < 2; ++i) {
        s.W[i] = gd; s.X[i] = Xs[i]; s.bias[i] = nullptr;
        s.cm[i] = nullptr; s.pm[i] = pms[i];
        s.ws[i] = 64; s.woff[i] = 0; s.sub[i] = 0;
      }
      gL.z = 8;
      k_linm<64><<<gL, 256, 0, stream>>>(s, N);
    }
    k_gfin<<<dim3(B * N / 4, 2), 256, 0, stream>>>(M1, M3, M2, M4, bufA, bufApm, bufB, bufBpm, N);

    // ======== score + top-half selection ========
    int Nh = N / 2;
    k_parmean<<<dim3((B * 3 * N + 255) / 256), 256, 0, stream>>>(bufA, bufB, px, py, N, B);
    k_dotphi<<<dim3((B * N + 255) / 256), 256, 0, stream>>>(bufA, bufB, px, py, dps, N, B);
    k_topsel<<<dim3(B), 1024, 0, stream>>>(dps, sel, N, Nh);
    k_gather<<<dim3(B * Nh / 4), 256, 0, stream>>>(bufApm, bufBpm, sel, bufC, bufD, N, Nh);
    k_cmean2<<<dim3(192, B, 2), 256, 0, stream>>>(bufC, bufD, blkX, blkY, Nh, 384, blk * 192, 1.f / (float)Nh);
    fx = bufC; fy = bufD;
    N = Nh;
  }
  k_head<<<dim3(2, B), 96, 0, stream>>>(blkX, blkY, W[22], W[23], Fxb, Fyb);
  k_svd<<<dim3(B), 64, 0, stream>>>(Fxb, Fyb, (float*)d_out, B);
}